// Round 4
// baseline (188.033 us; speedup 1.0000x reference)
//
#include <hip/hip_runtime.h>
#include <hip/hip_bf16.h>

// Problem: B=2, T=2048, D=1024, H=16, DH=64
#define BB 2
#define TT 2048
#define DD 1024
#define HH 16
#define MM (BB*TT)        // 4096
#define N3 (3*DD)         // 3072

typedef __attribute__((ext_vector_type(8))) short short8;
typedef __attribute__((ext_vector_type(4))) float f32x4;
typedef __attribute__((ext_vector_type(16))) float f32x16;

#define ZERO16 (f32x16){0,0,0,0,0,0,0,0,0,0,0,0,0,0,0,0}

#define GLDS16(g, l) __builtin_amdgcn_global_load_lds( \
    (const __attribute__((address_space(1))) void*)(g), \
    (__attribute__((address_space(3))) void*)(l), 16, 0, 0)

__device__ __forceinline__ unsigned short f2bf(float f) {
    union { float f; unsigned u; } v; v.f = f;
    unsigned r = v.u + 0x7FFFu + ((v.u >> 16) & 1u);
    return (unsigned short)(r >> 16);
}

__device__ __forceinline__ unsigned cvt_pk_bf16(float lo, float hi) {
    unsigned r;
    asm("v_cvt_pk_bf16_f32 %0, %1, %2" : "=v"(r) : "v"(lo), "v"(hi));
    return r;
}

// ---------------- cast fp32 -> bf16, vectorized ----------------
__global__ void cast_bf16_kernel(const float* __restrict__ src,
                                 unsigned short* __restrict__ dst, int n8) {
    int i = blockIdx.x * blockDim.x + threadIdx.x;
    int stride = gridDim.x * blockDim.x;
    for (; i < n8; i += stride) {
        const float4* s = reinterpret_cast<const float4*>(src) + (size_t)i * 2;
        float4 a = s[0], b = s[1];
        unsigned short r[8] = {f2bf(a.x), f2bf(a.y), f2bf(a.z), f2bf(a.w),
                               f2bf(b.x), f2bf(b.y), f2bf(b.z), f2bf(b.w)};
        *reinterpret_cast<uint4*>(dst + (size_t)i * 8) = *reinterpret_cast<uint4*>(r);
    }
}

// ---------------- transpose + cast: src[rows][cols] f32 -> dst[cols][rows] bf16 ----------------
__global__ void transpose_cast_kernel(const float* __restrict__ src,
                                      unsigned short* __restrict__ dst,
                                      int rows, int cols) {
    __shared__ float tile[32][33];
    int c0 = blockIdx.x * 32, r0 = blockIdx.y * 32;
    int tx = threadIdx.x, ty = threadIdx.y;   // block (32,8)
#pragma unroll
    for (int i = 0; i < 4; i++) {
        int r = ty + i * 8;
        tile[r][tx] = src[(size_t)(r0 + r) * cols + c0 + tx];
    }
    __syncthreads();
#pragma unroll
    for (int i = 0; i < 4; i++) {
        int r = ty + i * 8;
        dst[(size_t)(c0 + r) * rows + r0 + tx] = f2bf(tile[tx][r]);
    }
}

// ---------------- GEMM (m97 structure): C[M][N] = A[M][K] * Bt[N][K]^T ----------------
template<int WRITE_BF16>
__global__ __launch_bounds__(256)
void gemm_kernel(const unsigned short* __restrict__ A,
                 const unsigned short* __restrict__ Bt,
                 void* __restrict__ Cout, int M, int N, int K) {
    __shared__ unsigned short As[128][64];
    __shared__ unsigned short Bs[128][64];
    const int tm = blockIdx.y * 128, tn = blockIdx.x * 128;
    const int t = threadIdx.x;
    const int w = t >> 6, lane = t & 63, lo = lane & 15, hi = lane >> 4;
    const int wr = w >> 1, wc = w & 1;

    f32x4 acc[4][4];
#pragma unroll
    for (int i = 0; i < 4; i++)
#pragma unroll
        for (int j = 0; j < 4; j++) acc[i][j] = (f32x4){0.f, 0.f, 0.f, 0.f};

    const int srow = w * 32 + (lane >> 3);
    const int scol = (lane & 7) * 8;
    const unsigned short* ga = &A[(size_t)(tm + srow) * K + scol];
    const unsigned short* gb = &Bt[(size_t)(tn + srow) * K + scol];

    for (int k0 = 0; k0 < K; k0 += 64) {
        __syncthreads();
#pragma unroll
        for (int i = 0; i < 4; i++) {
            GLDS16(ga + (size_t)(i * 8) * K + k0, &As[w * 32 + i * 8][0]);
            GLDS16(gb + (size_t)(i * 8) * K + k0, &Bs[w * 32 + i * 8][0]);
        }
        __syncthreads();

        short8 af[4][2], bf[4][2];
#pragma unroll
        for (int i = 0; i < 4; i++)
#pragma unroll
            for (int ks = 0; ks < 2; ks++) {
                af[i][ks] = *reinterpret_cast<const short8*>(&As[wr * 64 + i * 16 + lo][ks * 32 + hi * 8]);
                bf[i][ks] = *reinterpret_cast<const short8*>(&Bs[wc * 64 + i * 16 + lo][ks * 32 + hi * 8]);
            }
#pragma unroll
        for (int ks = 0; ks < 2; ks++)
#pragma unroll
            for (int i = 0; i < 4; i++)
#pragma unroll
                for (int j = 0; j < 4; j++)
                    acc[i][j] = __builtin_amdgcn_mfma_f32_16x16x32_bf16(af[i][ks], bf[j][ks], acc[i][j], 0, 0, 0);
    }
#pragma unroll
    for (int i = 0; i < 4; i++)
#pragma unroll
        for (int j = 0; j < 4; j++)
#pragma unroll
            for (int r = 0; r < 4; r++) {
                int row = tm + wr * 64 + i * 16 + hi * 4 + r;
                int col = tn + wc * 64 + j * 16 + lo;
                float v = acc[i][j][r];
                if (WRITE_BF16)
                    ((unsigned short*)Cout)[(size_t)row * N + col] = f2bf(v);
                else
                    ((float*)Cout)[(size_t)row * N + col] = v;
            }
}

// ---------------- Flash attention, swapped-QK^T 32x32x16, XOR-swizzled LDS ----------------
// grid (H, T/128, B), 256 threads = 4 waves; wave w owns q rows [qc*128 + w*32, +32)
// LDS layout: linear 128B rows, byte ^= ((row&7)<<4) swizzle (T2).
// K staged via global_load_lds with pre-swizzled SOURCE (rule #21); V reg-staged packed.
__global__ __launch_bounds__(256)
void attn_kernel(const unsigned short* __restrict__ qkv,
                 unsigned short* __restrict__ outp) {
    __shared__ unsigned short Ks[2][64][64];   // K[kv][dh], swizzled
    __shared__ unsigned short Vt[2][64][64];   // V^T[dh][kv], swizzled

    const int b = blockIdx.z, h = blockIdx.x;
    const int qc = (TT / 128 - 1) - blockIdx.y;   // heavy blocks first
    const int t = threadIdx.x;
    const int w = t >> 6, l = t & 63, ql = l & 31, hi8 = l >> 5;
    const int q0 = qc * 128 + w * 32;
    const unsigned short* base = qkv + (size_t)b * TT * N3;

    // Q B-fragments (loop-invariant): lane l -> Q[q0+ql][dh = ks*16 + hi8*8 + j]
    short8 bq[4];
#pragma unroll
    for (int ks = 0; ks < 4; ks++)
        bq[ks] = *reinterpret_cast<const short8*>(
            &base[(size_t)(q0 + ql) * N3 + h * 64 + ks * 16 + hi8 * 8]);

    f32x16 o0 = ZERO16, o1 = ZERO16;
    float m_r = -1e30f, l_r = 0.f;
    const float sc = 0.125f * 1.44269504088896f;   // 1/sqrt(64) * log2(e)

    // K staging (GLDS, pre-swizzled source): lane covers row w*8+(l>>3) (+0/+32), col group (l&7)^(row&7)
    const int krow = l >> 3;
    const int kc8 = (l & 7) ^ (krow & 7);
    // V staging: thread owns kv pair (kv0,kv0+1) x 8 dh
    const int kv0 = 2 * (t & 31);
    const int dh0 = 8 * (t >> 5);
    uint4 v0, v1;

#define STAGE_K(KVB, BUF) { \
    GLDS16(&base[(size_t)((KVB) + w * 8 + krow) * N3 + DD + h * 64 + kc8 * 8], &Ks[BUF][w * 8][0]); \
    GLDS16(&base[(size_t)((KVB) + 32 + w * 8 + krow) * N3 + DD + h * 64 + kc8 * 8], &Ks[BUF][32 + w * 8][0]); }

#define STAGE_V_LOAD(KVB) { \
    const unsigned short* gv = &base[(size_t)((KVB) + kv0) * N3 + 2 * DD + h * 64 + dh0]; \
    v0 = *reinterpret_cast<const uint4*>(gv); \
    v1 = *reinterpret_cast<const uint4*>(gv + N3); }

#define STAGE_V_WRITE(BUF) { \
    const unsigned short* e0 = (const unsigned short*)&v0; \
    const unsigned short* e1 = (const unsigned short*)&v1; \
    char* vb = (char*)&Vt[BUF][0][0]; \
    _Pragma("unroll") \
    for (int j = 0; j < 8; j++) { \
        unsigned pk = (unsigned)e0[j] | ((unsigned)e1[j] << 16); \
        *reinterpret_cast<unsigned*>(vb + (dh0 + j) * 128 + ((4 * (t & 31)) ^ (j << 4))) = pk; \
    } }

    const int kvEnd = qc * 128 + 128;
    STAGE_K(0, 0);
    STAGE_V_LOAD(0);
    STAGE_V_WRITE(0);
    __syncthreads();   // drains GLDS vmcnt + ds writes; buf0 ready

    int it = 0;
    for (int kvb = 0; kvb < kvEnd; kvb += 64, it ^= 1) {
        const bool more = (kvb + 64) < kvEnd;
        if (more) { STAGE_K(kvb + 64, it ^ 1); STAGE_V_LOAD(kvb + 64); }

        if (kvb <= q0 + 31) {          // wave-uniform causal skip
            const bool diag = (kvb + 63 > q0);
            const int qg = q0 + ql;
            const char* kbase = (const char*)&Ks[it][0][0];
            const char* vbase = (const char*)&Vt[it][0][0];
#pragma unroll
            for (int sub = 0; sub < 2; sub++) {
                // K A-frags (swizzled read): row = sub*32+ql, group (2ks+hi8)^(ql&7)
                const int rb = (sub * 32 + ql) * 128;
                const int sw = (ql & 7);
                short8 ak0 = *reinterpret_cast<const short8*>(kbase + rb + (((0 + hi8) ^ sw) << 4));
                short8 ak1 = *reinterpret_cast<const short8*>(kbase + rb + (((2 + hi8) ^ sw) << 4));
                short8 ak2 = *reinterpret_cast<const short8*>(kbase + rb + (((4 + hi8) ^ sw) << 4));
                short8 ak3 = *reinterpret_cast<const short8*>(kbase + rb + (((6 + hi8) ^ sw) << 4));
                __builtin_amdgcn_s_setprio(1);
                f32x16 sa = ZERO16;
                sa = __builtin_amdgcn_mfma_f32_32x32x16_bf16(ak0, bq[0], sa, 0, 0, 0);
                sa = __builtin_amdgcn_mfma_f32_32x32x16_bf16(ak1, bq[1], sa, 0, 0, 0);
                sa = __builtin_amdgcn_mfma_f32_32x32x16_bf16(ak2, bq[2], sa, 0, 0, 0);
                sa = __builtin_amdgcn_mfma_f32_32x32x16_bf16(ak3, bq[3], sa, 0, 0, 0);
                __builtin_amdgcn_s_setprio(0);

                // scale + mask; lane holds S[q=ql][kv = kvb + sub*32 + crow(r,hi8)]
                float p[16];
#pragma unroll
                for (int r = 0; r < 16; r++) {
                    float v = sa[r] * sc;
                    if (diag) {
                        int kvg = kvb + sub * 32 + ((r & 3) + 8 * (r >> 2) + 4 * hi8);
                        if (kvg > qg) v = -1e30f;
                    }
                    p[r] = v;
                }
                float pmax = fmaxf(
                    fmaxf(fmaxf(fmaxf(p[0], p[1]), fmaxf(p[2], p[3])),
                          fmaxf(fmaxf(p[4], p[5]), fmaxf(p[6], p[7]))),
                    fmaxf(fmaxf(fmaxf(p[8], p[9]), fmaxf(p[10], p[11])),
                          fmaxf(fmaxf(p[12], p[13]), fmaxf(p[14], p[15]))));
                pmax = fmaxf(pmax, __shfl_xor(pmax, 32));

                // T13 defer-max (THR=8 in log2 units)
                if (__any(pmax > m_r + 8.0f)) {
                    float mnew = fmaxf(m_r, pmax);
                    float alpha = exp2f(m_r - mnew);
                    m_r = mnew;
                    l_r *= alpha;
#pragma unroll
                    for (int r = 0; r < 16; r++) {
                        int src = (r & 3) + 8 * (r >> 2) + 4 * hi8;
                        float av = __int_as_float(__builtin_amdgcn_ds_bpermute(
                            src << 2, __float_as_int(alpha)));
                        o0[r] *= av; o1[r] *= av;
                    }
                }
#pragma unroll
                for (int r = 0; r < 16; r++) p[r] = exp2f(p[r] - m_r);
                float ps = (((p[0] + p[1]) + (p[2] + p[3])) + ((p[4] + p[5]) + (p[6] + p[7])))
                         + (((p[8] + p[9]) + (p[10] + p[11])) + ((p[12] + p[13]) + (p[14] + p[15])));
                ps += __shfl_xor(ps, 32);
                l_r += ps;

                // T12: P -> A-frags via cvt_pk + permlane32_swap
                unsigned c01 = cvt_pk_bf16(p[0], p[1]);
                unsigned c23 = cvt_pk_bf16(p[2], p[3]);
                unsigned c45 = cvt_pk_bf16(p[4], p[5]);
                unsigned c67 = cvt_pk_bf16(p[6], p[7]);
                asm("v_permlane32_swap_b32 %0, %1" : "+v"(c01), "+v"(c45));
                asm("v_permlane32_swap_b32 %0, %1" : "+v"(c23), "+v"(c67));
                unsigned d01 = cvt_pk_bf16(p[8], p[9]);
                unsigned d23 = cvt_pk_bf16(p[10], p[11]);
                unsigned d45 = cvt_pk_bf16(p[12], p[13]);
                unsigned d67 = cvt_pk_bf16(p[14], p[15]);
                asm("v_permlane32_swap_b32 %0, %1" : "+v"(d01), "+v"(d45));
                asm("v_permlane32_swap_b32 %0, %1" : "+v"(d23), "+v"(d67));
                union { unsigned u[4]; short8 s; } f0, f1;
                f0.u[0] = c01; f0.u[1] = c23; f0.u[2] = c45; f0.u[3] = c67;
                f1.u[0] = d01; f1.u[1] = d23; f1.u[2] = d45; f1.u[3] = d67;

                // PV B-frags (swizzled read): row = ql / 32+ql, group (sub*4+ks*2+hi8)^(ql&7)
                short8 bv00 = *reinterpret_cast<const short8*>(vbase + ql * 128 + (((sub * 4 + 0 + hi8) ^ sw) << 4));
                short8 bv01 = *reinterpret_cast<const short8*>(vbase + ql * 128 + (((sub * 4 + 2 + hi8) ^ sw) << 4));
                short8 bv10 = *reinterpret_cast<const short8*>(vbase + (32 + ql) * 128 + (((sub * 4 + 0 + hi8) ^ sw) << 4));
                short8 bv11 = *reinterpret_cast<const short8*>(vbase + (32 + ql) * 128 + (((sub * 4 + 2 + hi8) ^ sw) << 4));
                __builtin_amdgcn_s_setprio(1);
                o0 = __builtin_amdgcn_mfma_f32_32x32x16_bf16(f0.s, bv00, o0, 0, 0, 0);
                o0 = __builtin_amdgcn_mfma_f32_32x32x16_bf16(f1.s, bv01, o0, 0, 0, 0);
                o1 = __builtin_amdgcn_mfma_f32_32x32x16_bf16(f0.s, bv10, o1, 0, 0, 0);
                o1 = __builtin_amdgcn_mfma_f32_32x32x16_bf16(f1.s, bv11, o1, 0, 0, 0);
                __builtin_amdgcn_s_setprio(0);
            }
        }
        if (more) STAGE_V_WRITE(it ^ 1);
        __syncthreads();   // drains GLDS(next) + V writes; next buf ready
    }

    // normalize + write: O rows q = crow(r,hi8), cols dh = {ql, 32+ql}
#pragma unroll
    for (int r = 0; r < 16; r++) {
        int src = (r & 3) + 8 * (r >> 2) + 4 * hi8;
        float lq = __int_as_float(__builtin_amdgcn_ds_bpermute(src << 2, __float_as_int(l_r)));
        float inv = 1.0f / lq;
        size_t off = (size_t)(b * TT + q0 + src) * DD + h * 64 + ql;
        outp[off] = f2bf(o0[r] * inv);
        outp[off + 32] = f2bf(o1[r] * inv);
    }
#undef STAGE_K
#undef STAGE_V_LOAD
#undef STAGE_V_WRITE
}

extern "C" void kernel_launch(void* const* d_in, const int* in_sizes, int n_in,
                              void* d_out, int out_size, void* d_ws, size_t ws_size,
                              hipStream_t stream) {
    const float* x     = (const float*)d_in[0];   // [4096][1024]
    const float* Wqkv  = (const float*)d_in[1];   // [1024][3072]
    const float* Wproj = (const float*)d_in[2];   // [1024][1024]
    float* out = (float*)d_out;                    // [4096][1024] fp32

    unsigned short* xb     = (unsigned short*)d_ws;            // 4096*1024
    unsigned short* wqkvt  = xb + (size_t)MM * DD;             // 3072*1024
    unsigned short* wprojt = wqkvt + (size_t)N3 * DD;          // 1024*1024
    unsigned short* qkv    = wprojt + (size_t)DD * DD;         // 4096*3072
    unsigned short* attout = qkv + (size_t)MM * N3;            // 4096*1024
    size_t need = ((size_t)MM * DD + (size_t)N3 * DD + (size_t)DD * DD +
                   (size_t)MM * N3 + (size_t)MM * DD) * 2;
    if (ws_size < need) return;

    cast_bf16_kernel<<<1024, 256, 0, stream>>>(x, xb, MM * DD / 8);
    transpose_cast_kernel<<<dim3(N3 / 32, DD / 32), dim3(32, 8), 0, stream>>>(Wqkv, wqkvt, DD, N3);
    transpose_cast_kernel<<<dim3(DD / 32, DD / 32), dim3(32, 8), 0, stream>>>(Wproj, wprojt, DD, DD);

    gemm_kernel<1><<<dim3(N3 / 128, MM / 128), 256, 0, stream>>>(xb, wqkvt, qkv, MM, N3, DD);

    attn_kernel<<<dim3(HH, TT / 128, BB), 256, 0, stream>>>(qkv, attout);

    gemm_kernel<0><<<dim3(DD / 128, MM / 128), 256, 0, stream>>>(attout, wprojt, out, MM, DD, DD);
}

// Round 5
// 179.191 us; speedup vs baseline: 1.0493x; 1.0493x over previous
//
#include <hip/hip_runtime.h>
#include <hip/hip_bf16.h>

// Problem: B=2, T=2048, D=1024, H=16, DH=64
#define BB 2
#define TT 2048
#define DD 1024
#define HH 16
#define MM (BB*TT)        // 4096
#define N3 (3*DD)         // 3072

typedef __attribute__((ext_vector_type(8))) short short8;
typedef __attribute__((ext_vector_type(4))) float f32x4;
typedef __attribute__((ext_vector_type(16))) float f32x16;

#define ZERO16 (f32x16){0,0,0,0,0,0,0,0,0,0,0,0,0,0,0,0}

#define GLDS16(g, l) __builtin_amdgcn_global_load_lds( \
    (const __attribute__((address_space(1))) void*)(g), \
    (__attribute__((address_space(3))) void*)(l), 16, 0, 0)

__device__ __forceinline__ unsigned short f2bf(float f) {
    union { float f; unsigned u; } v; v.f = f;
    unsigned r = v.u + 0x7FFFu + ((v.u >> 16) & 1u);
    return (unsigned short)(r >> 16);
}

__device__ __forceinline__ unsigned cvt_pk_bf16(float lo, float hi) {
    unsigned r;
    asm("v_cvt_pk_bf16_f32 %0, %1, %2" : "=v"(r) : "v"(lo), "v"(hi));
    return r;
}

// ---------------- cast fp32 -> bf16, vectorized ----------------
__global__ void cast_bf16_kernel(const float* __restrict__ src,
                                 unsigned short* __restrict__ dst, int n8) {
    int i = blockIdx.x * blockDim.x + threadIdx.x;
    int stride = gridDim.x * blockDim.x;
    for (; i < n8; i += stride) {
        const float4* s = reinterpret_cast<const float4*>(src) + (size_t)i * 2;
        float4 a = s[0], b = s[1];
        unsigned short r[8] = {f2bf(a.x), f2bf(a.y), f2bf(a.z), f2bf(a.w),
                               f2bf(b.x), f2bf(b.y), f2bf(b.z), f2bf(b.w)};
        *reinterpret_cast<uint4*>(dst + (size_t)i * 8) = *reinterpret_cast<uint4*>(r);
    }
}

// ---------------- transpose + cast: src[rows][cols] f32 -> dst[cols][rows] bf16 ----------------
__global__ void transpose_cast_kernel(const float* __restrict__ src,
                                      unsigned short* __restrict__ dst,
                                      int rows, int cols) {
    __shared__ float tile[32][33];
    int c0 = blockIdx.x * 32, r0 = blockIdx.y * 32;
    int tx = threadIdx.x, ty = threadIdx.y;   // block (32,8)
#pragma unroll
    for (int i = 0; i < 4; i++) {
        int r = ty + i * 8;
        tile[r][tx] = src[(size_t)(r0 + r) * cols + c0 + tx];
    }
    __syncthreads();
#pragma unroll
    for (int i = 0; i < 4; i++) {
        int r = ty + i * 8;
        dst[(size_t)(c0 + r) * rows + r0 + tx] = f2bf(tile[tx][r]);
    }
}

// ---------------- GEMM (m97 structure): C[M][N] = A[M][K] * Bt[N][K]^T ----------------
// Optional: scale the first scale_cols output columns by `scale` (fold attn 1/sqrt(dh)*log2e into Q).
template<int WRITE_BF16>
__global__ __launch_bounds__(256)
void gemm_kernel(const unsigned short* __restrict__ A,
                 const unsigned short* __restrict__ Bt,
                 void* __restrict__ Cout, int M, int N, int K,
                 int scale_cols, float scale) {
    __shared__ unsigned short As[128][64];
    __shared__ unsigned short Bs[128][64];
    // bijective XCD swizzle (nwg % 8 == 0 for all our launches)
    const int nbx = gridDim.x;
    const int id = blockIdx.y * nbx + blockIdx.x;
    const int cpx = (nbx * gridDim.y) >> 3;
    const int swz = (id & 7) * cpx + (id >> 3);
    const int tm = (swz / nbx) * 128, tn = (swz % nbx) * 128;
    const int t = threadIdx.x;
    const int w = t >> 6, lane = t & 63, lo = lane & 15, hi = lane >> 4;
    const int wr = w >> 1, wc = w & 1;

    f32x4 acc[4][4];
#pragma unroll
    for (int i = 0; i < 4; i++)
#pragma unroll
        for (int j = 0; j < 4; j++) acc[i][j] = (f32x4){0.f, 0.f, 0.f, 0.f};

    const int srow = w * 32 + (lane >> 3);
    const int scol = (lane & 7) * 8;
    const unsigned short* ga = &A[(size_t)(tm + srow) * K + scol];
    const unsigned short* gb = &Bt[(size_t)(tn + srow) * K + scol];

    for (int k0 = 0; k0 < K; k0 += 64) {
        __syncthreads();
#pragma unroll
        for (int i = 0; i < 4; i++) {
            GLDS16(ga + (size_t)(i * 8) * K + k0, &As[w * 32 + i * 8][0]);
            GLDS16(gb + (size_t)(i * 8) * K + k0, &Bs[w * 32 + i * 8][0]);
        }
        __syncthreads();

        short8 af[4][2], bf[4][2];
#pragma unroll
        for (int i = 0; i < 4; i++)
#pragma unroll
            for (int ks = 0; ks < 2; ks++) {
                af[i][ks] = *reinterpret_cast<const short8*>(&As[wr * 64 + i * 16 + lo][ks * 32 + hi * 8]);
                bf[i][ks] = *reinterpret_cast<const short8*>(&Bs[wc * 64 + i * 16 + lo][ks * 32 + hi * 8]);
            }
#pragma unroll
        for (int ks = 0; ks < 2; ks++)
#pragma unroll
            for (int i = 0; i < 4; i++)
#pragma unroll
                for (int j = 0; j < 4; j++)
                    acc[i][j] = __builtin_amdgcn_mfma_f32_16x16x32_bf16(af[i][ks], bf[j][ks], acc[i][j], 0, 0, 0);
    }
#pragma unroll
    for (int i = 0; i < 4; i++)
#pragma unroll
        for (int j = 0; j < 4; j++)
#pragma unroll
            for (int r = 0; r < 4; r++) {
                int row = tm + wr * 64 + i * 16 + hi * 4 + r;
                int col = tn + wc * 64 + j * 16 + lo;
                float v = acc[i][j][r];
                if (col < scale_cols) v *= scale;
                if (WRITE_BF16)
                    ((unsigned short*)Cout)[(size_t)row * N + col] = f2bf(v);
                else
                    ((float*)Cout)[(size_t)row * N + col] = v;
            }
}

// ---------------- Flash attention, swapped-QK^T 32x32x16, merged-sub softmax ----------------
// grid (H, T/64, B), 128 threads = 2 waves; wave w owns q rows [qc*64 + w*32, +32)
// Every wave computes every kv tile (no skip divergence). Q pre-scaled in GEMM1.
__global__ __launch_bounds__(128)
void attn_kernel(const unsigned short* __restrict__ qkv,
                 unsigned short* __restrict__ outp) {
    __shared__ unsigned short Ks[2][64][64];   // K[kv][dh], XOR-swizzled rows
    __shared__ unsigned short Vt[2][64][64];   // V^T[dh][kv], XOR-swizzled rows

    const int b = blockIdx.z, h = blockIdx.x;
    const int qc = (TT / 64 - 1) - blockIdx.y;   // heavy blocks first
    const int t = threadIdx.x;
    const int w = t >> 6, l = t & 63, ql = l & 31, hi8 = l >> 5;
    const int q0 = qc * 64 + w * 32;
    const unsigned short* base = qkv + (size_t)b * TT * N3;

    // Q B-fragments (pre-scaled by 1/sqrt(dh)*log2e in GEMM1 epilogue)
    short8 bq[4];
#pragma unroll
    for (int ks = 0; ks < 4; ks++)
        bq[ks] = *reinterpret_cast<const short8*>(
            &base[(size_t)(q0 + ql) * N3 + h * 64 + ks * 16 + hi8 * 8]);

    f32x16 o0 = ZERO16, o1 = ZERO16;
    float m_r = -1e30f, l_r = 0.f;

    // K staging via GLDS, pre-swizzled source
    const int krow = l >> 3;              // 0..7
    const int kc8 = (l & 7) ^ krow;       // source col group
    // V staging: thread owns 4 kv x 8 dh
    const int kv0 = 4 * (t & 15);
    const int dh0 = 8 * (t >> 4);
    uint4 v0, v1, v2, v3;

#define STAGE_K(KVB, BUF) { \
    _Pragma("unroll") \
    for (int i = 0; i < 4; i++) \
        GLDS16(&base[(size_t)((KVB) + i * 16 + w * 8 + krow) * N3 + DD + h * 64 + kc8 * 8], \
               &Ks[BUF][i * 16 + w * 8][0]); }

#define STAGE_V_LOAD(KVB) { \
    const unsigned short* gv = &base[(size_t)((KVB) + kv0) * N3 + 2 * DD + h * 64 + dh0]; \
    v0 = *reinterpret_cast<const uint4*>(gv); \
    v1 = *reinterpret_cast<const uint4*>(gv + N3); \
    v2 = *reinterpret_cast<const uint4*>(gv + 2 * N3); \
    v3 = *reinterpret_cast<const uint4*>(gv + 3 * N3); }

#define STAGE_V_WRITE(BUF) { \
    const unsigned short* e0 = (const unsigned short*)&v0; \
    const unsigned short* e1 = (const unsigned short*)&v1; \
    const unsigned short* e2 = (const unsigned short*)&v2; \
    const unsigned short* e3 = (const unsigned short*)&v3; \
    char* vb = (char*)&Vt[BUF][0][0]; \
    _Pragma("unroll") \
    for (int j = 0; j < 8; j++) { \
        uint2 pk; \
        pk.x = (unsigned)e0[j] | ((unsigned)e1[j] << 16); \
        pk.y = (unsigned)e2[j] | ((unsigned)e3[j] << 16); \
        *reinterpret_cast<uint2*>(vb + (dh0 + j) * 128 + ((8 * (t & 15)) ^ (j << 4))) = pk; \
    } }

    const int kvEnd = qc * 64 + 64;
    STAGE_K(0, 0);
    STAGE_V_LOAD(0);
    STAGE_V_WRITE(0);
    __syncthreads();

    const int sw4 = (ql & 7) << 4;
    const int qg = q0 + ql;
    int it = 0;
    for (int kvb = 0; kvb < kvEnd; kvb += 64, it ^= 1) {
        const bool more = (kvb + 64) < kvEnd;
        if (more) { STAGE_K(kvb + 64, it ^ 1); STAGE_V_LOAD(kvb + 64); }

        const char* kbase = (const char*)&Ks[it][0][0];
        const char* vbase = (const char*)&Vt[it][0][0];

        // ---- K A-frags, both subs ----
        short8 ak0[4], ak1[4];
#pragma unroll
        for (int ks = 0; ks < 4; ks++) {
            ak0[ks] = *reinterpret_cast<const short8*>(kbase + ql * 128 + (((ks * 2 + hi8) << 4) ^ sw4));
            ak1[ks] = *reinterpret_cast<const short8*>(kbase + (32 + ql) * 128 + (((ks * 2 + hi8) << 4) ^ sw4));
        }
        // ---- QK^T, both subs (interleaved chains) ----
        f32x16 sa0 = ZERO16, sa1 = ZERO16;
#pragma unroll
        for (int ks = 0; ks < 4; ks++) {
            sa0 = __builtin_amdgcn_mfma_f32_32x32x16_bf16(ak0[ks], bq[ks], sa0, 0, 0, 0);
            sa1 = __builtin_amdgcn_mfma_f32_32x32x16_bf16(ak1[ks], bq[ks], sa1, 0, 0, 0);
        }
        // ---- causal mask (diag tile only) ----
        if (kvb + 63 > q0) {
#pragma unroll
            for (int r = 0; r < 16; r++) {
                int crow = (r & 3) + 8 * (r >> 2) + 4 * hi8;
                if (kvb + crow > qg) sa0[r] = -1e30f;
                if (kvb + 32 + crow > qg) sa1[r] = -1e30f;
            }
        }
        // ---- merged row max over 32 values (balanced tree) ----
        float x0 = fmaxf(fmaxf(sa0[0], sa0[1]), fmaxf(sa0[2], sa0[3]));
        float x1 = fmaxf(fmaxf(sa0[4], sa0[5]), fmaxf(sa0[6], sa0[7]));
        float x2 = fmaxf(fmaxf(sa0[8], sa0[9]), fmaxf(sa0[10], sa0[11]));
        float x3 = fmaxf(fmaxf(sa0[12], sa0[13]), fmaxf(sa0[14], sa0[15]));
        float x4 = fmaxf(fmaxf(sa1[0], sa1[1]), fmaxf(sa1[2], sa1[3]));
        float x5 = fmaxf(fmaxf(sa1[4], sa1[5]), fmaxf(sa1[6], sa1[7]));
        float x6 = fmaxf(fmaxf(sa1[8], sa1[9]), fmaxf(sa1[10], sa1[11]));
        float x7 = fmaxf(fmaxf(sa1[12], sa1[13]), fmaxf(sa1[14], sa1[15]));
        float pmax = fmaxf(fmaxf(fmaxf(x0, x1), fmaxf(x2, x3)),
                           fmaxf(fmaxf(x4, x5), fmaxf(x6, x7)));
        pmax = fmaxf(pmax, __shfl_xor(pmax, 32));

        // ---- T13 defer-max: single check per tile ----
        if (__any(pmax > m_r + 8.0f)) {
            float mnew = fmaxf(m_r, pmax);
            float alpha = exp2f(m_r - mnew);
            m_r = mnew;
            l_r *= alpha;
#pragma unroll
            for (int r = 0; r < 16; r++) {
                int src = (r & 3) + 8 * (r >> 2) + 4 * hi8;
                float av = __int_as_float(__builtin_amdgcn_ds_bpermute(
                    src << 2, __float_as_int(alpha)));
                o0[r] *= av; o1[r] *= av;
            }
        }
        // ---- P = exp2(S - m), merged sum ----
#pragma unroll
        for (int r = 0; r < 16; r++) sa0[r] = exp2f(sa0[r] - m_r);
#pragma unroll
        for (int r = 0; r < 16; r++) sa1[r] = exp2f(sa1[r] - m_r);
        float s0 = ((sa0[0] + sa0[1]) + (sa0[2] + sa0[3])) + ((sa0[4] + sa0[5]) + (sa0[6] + sa0[7]));
        float s1 = ((sa0[8] + sa0[9]) + (sa0[10] + sa0[11])) + ((sa0[12] + sa0[13]) + (sa0[14] + sa0[15]));
        float s2 = ((sa1[0] + sa1[1]) + (sa1[2] + sa1[3])) + ((sa1[4] + sa1[5]) + (sa1[6] + sa1[7]));
        float s3 = ((sa1[8] + sa1[9]) + (sa1[10] + sa1[11])) + ((sa1[12] + sa1[13]) + (sa1[14] + sa1[15]));
        float ps = (s0 + s1) + (s2 + s3);
        ps += __shfl_xor(ps, 32);
        l_r += ps;

        // ---- T12: P -> bf16 A-frags via cvt_pk + permlane32_swap ----
        unsigned a01 = cvt_pk_bf16(sa0[0], sa0[1]),  a23 = cvt_pk_bf16(sa0[2], sa0[3]);
        unsigned a45 = cvt_pk_bf16(sa0[4], sa0[5]),  a67 = cvt_pk_bf16(sa0[6], sa0[7]);
        asm("v_permlane32_swap_b32 %0, %1" : "+v"(a01), "+v"(a45));
        asm("v_permlane32_swap_b32 %0, %1" : "+v"(a23), "+v"(a67));
        unsigned b01 = cvt_pk_bf16(sa0[8], sa0[9]),  b23 = cvt_pk_bf16(sa0[10], sa0[11]);
        unsigned b45 = cvt_pk_bf16(sa0[12], sa0[13]), b67 = cvt_pk_bf16(sa0[14], sa0[15]);
        asm("v_permlane32_swap_b32 %0, %1" : "+v"(b01), "+v"(b45));
        asm("v_permlane32_swap_b32 %0, %1" : "+v"(b23), "+v"(b67));
        unsigned c01 = cvt_pk_bf16(sa1[0], sa1[1]),  c23 = cvt_pk_bf16(sa1[2], sa1[3]);
        unsigned c45 = cvt_pk_bf16(sa1[4], sa1[5]),  c67 = cvt_pk_bf16(sa1[6], sa1[7]);
        asm("v_permlane32_swap_b32 %0, %1" : "+v"(c01), "+v"(c45));
        asm("v_permlane32_swap_b32 %0, %1" : "+v"(c23), "+v"(c67));
        unsigned d01 = cvt_pk_bf16(sa1[8], sa1[9]),  d23 = cvt_pk_bf16(sa1[10], sa1[11]);
        unsigned d45 = cvt_pk_bf16(sa1[12], sa1[13]), d67 = cvt_pk_bf16(sa1[14], sa1[15]);
        asm("v_permlane32_swap_b32 %0, %1" : "+v"(d01), "+v"(d45));
        asm("v_permlane32_swap_b32 %0, %1" : "+v"(d23), "+v"(d67));
        union { unsigned u[4]; short8 s; } f0s0, f1s0, f0s1, f1s1;
        f0s0.u[0] = a01; f0s0.u[1] = a23; f0s0.u[2] = a45; f0s0.u[3] = a67;
        f1s0.u[0] = b01; f1s0.u[1] = b23; f1s0.u[2] = b45; f1s0.u[3] = b67;
        f0s1.u[0] = c01; f0s1.u[1] = c23; f0s1.u[2] = c45; f0s1.u[3] = c67;
        f1s1.u[0] = d01; f1s1.u[1] = d23; f1s1.u[2] = d45; f1s1.u[3] = d67;

        // ---- PV: 8 MFMA cluster ----
        short8 bv00 = *reinterpret_cast<const short8*>(vbase + ql * 128 + (((0 + hi8) << 4) ^ sw4));
        short8 bv01 = *reinterpret_cast<const short8*>(vbase + ql * 128 + (((2 + hi8) << 4) ^ sw4));
        short8 bv02 = *reinterpret_cast<const short8*>(vbase + ql * 128 + (((4 + hi8) << 4) ^ sw4));
        short8 bv03 = *reinterpret_cast<const short8*>(vbase + ql * 128 + (((6 + hi8) << 4) ^ sw4));
        short8 bv10 = *reinterpret_cast<const short8*>(vbase + (32 + ql) * 128 + (((0 + hi8) << 4) ^ sw4));
        short8 bv11 = *reinterpret_cast<const short8*>(vbase + (32 + ql) * 128 + (((2 + hi8) << 4) ^ sw4));
        short8 bv12 = *reinterpret_cast<const short8*>(vbase + (32 + ql) * 128 + (((4 + hi8) << 4) ^ sw4));
        short8 bv13 = *reinterpret_cast<const short8*>(vbase + (32 + ql) * 128 + (((6 + hi8) << 4) ^ sw4));
        o0 = __builtin_amdgcn_mfma_f32_32x32x16_bf16(f0s0.s, bv00, o0, 0, 0, 0);
        o1 = __builtin_amdgcn_mfma_f32_32x32x16_bf16(f0s0.s, bv10, o1, 0, 0, 0);
        o0 = __builtin_amdgcn_mfma_f32_32x32x16_bf16(f1s0.s, bv01, o0, 0, 0, 0);
        o1 = __builtin_amdgcn_mfma_f32_32x32x16_bf16(f1s0.s, bv11, o1, 0, 0, 0);
        o0 = __builtin_amdgcn_mfma_f32_32x32x16_bf16(f0s1.s, bv02, o0, 0, 0, 0);
        o1 = __builtin_amdgcn_mfma_f32_32x32x16_bf16(f0s1.s, bv12, o1, 0, 0, 0);
        o0 = __builtin_amdgcn_mfma_f32_32x32x16_bf16(f1s1.s, bv03, o0, 0, 0, 0);
        o1 = __builtin_amdgcn_mfma_f32_32x32x16_bf16(f1s1.s, bv13, o1, 0, 0, 0);

        if (more) STAGE_V_WRITE(it ^ 1);
        __syncthreads();
    }

    // ---- normalize + write (bf16, [b][t][h][dh]) ----
#pragma unroll
    for (int r = 0; r < 16; r++) {
        int src = (r & 3) + 8 * (r >> 2) + 4 * hi8;
        float lq = __int_as_float(__builtin_amdgcn_ds_bpermute(src << 2, __float_as_int(l_r)));
        float inv = 1.0f / lq;
        size_t off = (size_t)(b * TT + q0 + src) * DD + h * 64 + ql;
        outp[off] = f2bf(o0[r] * inv);
        outp[off + 32] = f2bf(o1[r] * inv);
    }
#undef STAGE_K
#undef STAGE_V_LOAD
#undef STAGE_V_WRITE
}

extern "C" void kernel_launch(void* const* d_in, const int* in_sizes, int n_in,
                              void* d_out, int out_size, void* d_ws, size_t ws_size,
                              hipStream_t stream) {
    const float* x     = (const float*)d_in[0];   // [4096][1024]
    const float* Wqkv  = (const float*)d_in[1];   // [1024][3072]
    const float* Wproj = (const float*)d_in[2];   // [1024][1024]
    float* out = (float*)d_out;                    // [4096][1024] fp32

    unsigned short* xb     = (unsigned short*)d_ws;            // 4096*1024
    unsigned short* wqkvt  = xb + (size_t)MM * DD;             // 3072*1024
    unsigned short* wprojt = wqkvt + (size_t)N3 * DD;          // 1024*1024
    unsigned short* qkv    = wprojt + (size_t)DD * DD;         // 4096*3072
    unsigned short* attout = qkv + (size_t)MM * N3;            // 4096*1024
    size_t need = ((size_t)MM * DD + (size_t)N3 * DD + (size_t)DD * DD +
                   (size_t)MM * N3 + (size_t)MM * DD) * 2;
    if (ws_size < need) return;

    const float sc = 0.125f * 1.44269504088896f;   // 1/sqrt(64) * log2(e), folded into Q

    cast_bf16_kernel<<<1024, 256, 0, stream>>>(x, xb, MM * DD / 8);
    transpose_cast_kernel<<<dim3(N3 / 32, DD / 32), dim3(32, 8), 0, stream>>>(Wqkv, wqkvt, DD, N3);
    transpose_cast_kernel<<<dim3(DD / 32, DD / 32), dim3(32, 8), 0, stream>>>(Wproj, wprojt, DD, DD);

    gemm_kernel<1><<<dim3(N3 / 128, MM / 128), 256, 0, stream>>>(xb, wqkvt, qkv, MM, N3, DD, DD, sc);

    attn_kernel<<<dim3(HH, TT / 64, BB), 128, 0, stream>>>(qkv, attout);

    gemm_kernel<0><<<dim3(DD / 128, MM / 128), 256, 0, stream>>>(attout, wprojt, out, MM, DD, DD, 0, 1.0f);
}

// Round 6
// 160.014 us; speedup vs baseline: 1.1751x; 1.1198x over previous
//
#include <hip/hip_runtime.h>
#include <hip/hip_bf16.h>

// Problem: B=2, T=2048, D=1024, H=16, DH=64
#define BB 2
#define TT 2048
#define DD 1024
#define HH 16
#define MM (BB*TT)        // 4096
#define N3 (3*DD)         // 3072

typedef __attribute__((ext_vector_type(8))) short short8;
typedef __attribute__((ext_vector_type(4))) float f32x4;
typedef __attribute__((ext_vector_type(16))) float f32x16;

#define ZERO16 (f32x16){0,0,0,0,0,0,0,0,0,0,0,0,0,0,0,0}

#define GLDS16(g, l) __builtin_amdgcn_global_load_lds( \
    (const __attribute__((address_space(1))) void*)(g), \
    (__attribute__((address_space(3))) void*)(l), 16, 0, 0)

__device__ __forceinline__ unsigned short f2bf(float f) {
    union { float f; unsigned u; } v; v.f = f;
    unsigned r = v.u + 0x7FFFu + ((v.u >> 16) & 1u);
    return (unsigned short)(r >> 16);
}

__device__ __forceinline__ unsigned cvt_pk_bf16(float lo, float hi) {
    unsigned r;
    asm("v_cvt_pk_bf16_f32 %0, %1, %2" : "=v"(r) : "v"(lo), "v"(hi));
    return r;
}

// ---------------- cast fp32 -> bf16, vectorized ----------------
__global__ void cast_bf16_kernel(const float* __restrict__ src,
                                 unsigned short* __restrict__ dst, int n8) {
    int i = blockIdx.x * blockDim.x + threadIdx.x;
    int stride = gridDim.x * blockDim.x;
    for (; i < n8; i += stride) {
        const float4* s = reinterpret_cast<const float4*>(src) + (size_t)i * 2;
        float4 a = s[0], b = s[1];
        unsigned short r[8] = {f2bf(a.x), f2bf(a.y), f2bf(a.z), f2bf(a.w),
                               f2bf(b.x), f2bf(b.y), f2bf(b.z), f2bf(b.w)};
        *reinterpret_cast<uint4*>(dst + (size_t)i * 8) = *reinterpret_cast<uint4*>(r);
    }
}

// ---------------- transpose + cast: src[rows][cols] f32 -> dst[cols][rows] bf16 ----------------
__global__ void transpose_cast_kernel(const float* __restrict__ src,
                                      unsigned short* __restrict__ dst,
                                      int rows, int cols) {
    __shared__ float tile[32][33];
    int c0 = blockIdx.x * 32, r0 = blockIdx.y * 32;
    int tx = threadIdx.x, ty = threadIdx.y;   // block (32,8)
#pragma unroll
    for (int i = 0; i < 4; i++) {
        int r = ty + i * 8;
        tile[r][tx] = src[(size_t)(r0 + r) * cols + c0 + tx];
    }
    __syncthreads();
#pragma unroll
    for (int i = 0; i < 4; i++) {
        int r = ty + i * 8;
        dst[(size_t)(c0 + r) * rows + r0 + tx] = f2bf(tile[tx][r]);
    }
}

// ---------------- GEMM (m97 structure): C[M][N] = A[M][K] * Bt[N][K]^T ----------------
template<int WRITE_BF16>
__global__ __launch_bounds__(256)
void gemm_kernel(const unsigned short* __restrict__ A,
                 const unsigned short* __restrict__ Bt,
                 void* __restrict__ Cout, int M, int N, int K,
                 int scale_cols, float scale) {
    __shared__ unsigned short As[128][64];
    __shared__ unsigned short Bs[128][64];
    const int nbx = gridDim.x;
    const int id = blockIdx.y * nbx + blockIdx.x;
    const int cpx = (nbx * gridDim.y) >> 3;
    const int swz = (id & 7) * cpx + (id >> 3);
    const int tm = (swz / nbx) * 128, tn = (swz % nbx) * 128;
    const int t = threadIdx.x;
    const int w = t >> 6, lane = t & 63, lo = lane & 15, hi = lane >> 4;
    const int wr = w >> 1, wc = w & 1;

    f32x4 acc[4][4];
#pragma unroll
    for (int i = 0; i < 4; i++)
#pragma unroll
        for (int j = 0; j < 4; j++) acc[i][j] = (f32x4){0.f, 0.f, 0.f, 0.f};

    const int srow = w * 32 + (lane >> 3);
    const int scol = (lane & 7) * 8;
    const unsigned short* ga = &A[(size_t)(tm + srow) * K + scol];
    const unsigned short* gb = &Bt[(size_t)(tn + srow) * K + scol];

    for (int k0 = 0; k0 < K; k0 += 64) {
        __syncthreads();
#pragma unroll
        for (int i = 0; i < 4; i++) {
            GLDS16(ga + (size_t)(i * 8) * K + k0, &As[w * 32 + i * 8][0]);
            GLDS16(gb + (size_t)(i * 8) * K + k0, &Bs[w * 32 + i * 8][0]);
        }
        __syncthreads();

        short8 af[4][2], bf[4][2];
#pragma unroll
        for (int i = 0; i < 4; i++)
#pragma unroll
            for (int ks = 0; ks < 2; ks++) {
                af[i][ks] = *reinterpret_cast<const short8*>(&As[wr * 64 + i * 16 + lo][ks * 32 + hi * 8]);
                bf[i][ks] = *reinterpret_cast<const short8*>(&Bs[wc * 64 + i * 16 + lo][ks * 32 + hi * 8]);
            }
#pragma unroll
        for (int ks = 0; ks < 2; ks++)
#pragma unroll
            for (int i = 0; i < 4; i++)
#pragma unroll
                for (int j = 0; j < 4; j++)
                    acc[i][j] = __builtin_amdgcn_mfma_f32_16x16x32_bf16(af[i][ks], bf[j][ks], acc[i][j], 0, 0, 0);
    }
#pragma unroll
    for (int i = 0; i < 4; i++)
#pragma unroll
        for (int j = 0; j < 4; j++)
#pragma unroll
            for (int r = 0; r < 4; r++) {
                int row = tm + wr * 64 + i * 16 + hi * 4 + r;
                int col = tn + wc * 64 + j * 16 + lo;
                float v = acc[i][j][r];
                if (col < scale_cols) v *= scale;
                if (WRITE_BF16)
                    ((unsigned short*)Cout)[(size_t)row * N + col] = f2bf(v);
                else
                    ((float*)Cout)[(size_t)row * N + col] = v;
            }
}

// ---------------- Flash attention: fixed-m softmax, balanced pair + kv-split ----------------
// grid (H, 16 pairs, B), 256 threads = 4 waves.
// Pair p: light q-tile qcl=p (64 rows), heavy q-tile qch=31-p. L=p+1 tiles, Hn=32-p tiles.
// Phase 1 (kvt<L): wave-pair 0 -> heavy full tile, pair 1 -> light full tile.
// Phase 2 (kvt>=L): pair 0 -> heavy kv rows 0-31, pair 1 -> heavy kv rows 32-63 (fixed-m => order-free).
// End: pair-1 heavy partials merged into pair 0 via LDS; pair 0 writes heavy output.
__global__ __launch_bounds__(256)
void attn_kernel(const unsigned short* __restrict__ qkv,
                 unsigned short* __restrict__ outp) {
    __shared__ unsigned short Ks[2][64][64];   // K[kv][dh], XOR-swizzled rows
    __shared__ unsigned short Vt[2][64][64];   // V^T[dh][kv], XOR-swizzled rows

    const int b = blockIdx.z, h = blockIdx.x, p = blockIdx.y;
    const int qcl = p, qch = 31 - p;
    const int L = p + 1, Hn = 32 - p;
    const int t = threadIdx.x;
    const int w = t >> 6, l = t & 63, ql = l & 31, hi8 = l >> 5;
    const int pr = w >> 1, rg = w & 1;
    const int q0h = qch * 64 + rg * 32;
    const int q0p = (pr ? qcl : qch) * 64 + rg * 32;   // phase-1 q base
    const unsigned short* base = qkv + (size_t)b * TT * N3;

    // Q B-fragments (pre-scaled by 1/sqrt(dh)*log2e in GEMM1)
    short8 bq[4];
#pragma unroll
    for (int ks = 0; ks < 4; ks++)
        bq[ks] = *reinterpret_cast<const short8*>(
            &base[(size_t)(q0p + ql) * N3 + h * 64 + ks * 16 + hi8 * 8]);

    f32x16 o0 = ZERO16, o1 = ZERO16;
    float l_r = 0.f;
    const float FM = 16.0f;   // fixed softmax shift (log2 domain)

    // staging indices (256 threads)
    const int krow = l >> 3;              // 0..7
    const int kc8 = (l & 7) ^ krow;       // pre-swizzled source col group
    const int kv0 = 2 * (t & 31);         // V: kv pair
    const int dh0 = 8 * (t >> 5);         // V: 8 dh rows
    uint4 v0, v1;

#define STAGE_K(KVB, BUF) { \
    GLDS16(&base[(size_t)((KVB) + w * 8 + krow) * N3 + DD + h * 64 + kc8 * 8], &Ks[BUF][w * 8][0]); \
    GLDS16(&base[(size_t)((KVB) + 32 + w * 8 + krow) * N3 + DD + h * 64 + kc8 * 8], &Ks[BUF][32 + w * 8][0]); }

#define STAGE_V_LOAD(KVB) { \
    const unsigned short* gv = &base[(size_t)((KVB) + kv0) * N3 + 2 * DD + h * 64 + dh0]; \
    v0 = *reinterpret_cast<const uint4*>(gv); \
    v1 = *reinterpret_cast<const uint4*>(gv + N3); }

#define STAGE_V_WRITE(BUF) { \
    const unsigned short* e0 = (const unsigned short*)&v0; \
    const unsigned short* e1 = (const unsigned short*)&v1; \
    char* vb = (char*)&Vt[BUF][0][0]; \
    _Pragma("unroll") \
    for (int j = 0; j < 8; j++) { \
        unsigned pk = (unsigned)e0[j] | ((unsigned)e1[j] << 16); \
        *reinterpret_cast<unsigned*>(vb + (dh0 + j) * 128 + ((4 * (t & 31)) ^ (j << 4))) = pk; \
    } }

#define WRITE_OUT(Q0) { \
    _Pragma("unroll") \
    for (int r = 0; r < 16; r++) { \
        int src = (r & 3) + 8 * (r >> 2) + 4 * hi8; \
        float lq = __int_as_float(__builtin_amdgcn_ds_bpermute(src << 2, __float_as_int(l_r))); \
        float inv = 1.0f / lq; \
        size_t off = (size_t)(b * TT + (Q0) + src) * DD + h * 64 + ql; \
        outp[off] = f2bf(o0[r] * inv); \
        outp[off + 32] = f2bf(o1[r] * inv); \
    } }

    STAGE_K(0, 0);
    STAGE_V_LOAD(0);
    STAGE_V_WRITE(0);
    __syncthreads();

    const int sw4 = (ql & 7) << 4;
    int it = 0;
    for (int kvt = 0; kvt < Hn; kvt++, it ^= 1) {
        const bool more = (kvt + 1) < Hn;
        if (more) { STAGE_K(kvt * 64 + 64, it ^ 1); STAGE_V_LOAD(kvt * 64 + 64); }

        if (kvt == L && pr == 1) {
            // light tile complete: write it out, reset accumulators, switch to heavy Q
            WRITE_OUT(qcl * 64 + rg * 32);
            o0 = ZERO16; o1 = ZERO16; l_r = 0.f;
#pragma unroll
            for (int ks = 0; ks < 4; ks++)
                bq[ks] = *reinterpret_cast<const short8*>(
                    &base[(size_t)(q0h + ql) * N3 + h * 64 + ks * 16 + hi8 * 8]);
        }

        const char* kbase = (const char*)&Ks[it][0][0];
        const char* vbase = (const char*)&Vt[it][0][0];
        const int kvb = kvt * 64;

        if (kvt < L) {
            // ================= phase 1: full 64-kv tile =================
            short8 ak0[4], ak1[4];
#pragma unroll
            for (int ks = 0; ks < 4; ks++) {
                ak0[ks] = *reinterpret_cast<const short8*>(kbase + ql * 128 + (((ks * 2 + hi8) << 4) ^ sw4));
                ak1[ks] = *reinterpret_cast<const short8*>(kbase + (32 + ql) * 128 + (((ks * 2 + hi8) << 4) ^ sw4));
            }
            f32x16 sa0 = ZERO16, sa1 = ZERO16;
#pragma unroll
            for (int ks = 0; ks < 4; ks++) {
                sa0 = __builtin_amdgcn_mfma_f32_32x32x16_bf16(ak0[ks], bq[ks], sa0, 0, 0, 0);
                sa1 = __builtin_amdgcn_mfma_f32_32x32x16_bf16(ak1[ks], bq[ks], sa1, 0, 0, 0);
            }
            if (pr == 1 && kvt == L - 1) {   // light diagonal tile
                const int qg = q0p + ql;
#pragma unroll
                for (int r = 0; r < 16; r++) {
                    int crow = (r & 3) + 8 * (r >> 2) + 4 * hi8;
                    if (kvb + crow > qg) sa0[r] = -1e30f;
                    if (kvb + 32 + crow > qg) sa1[r] = -1e30f;
                }
            }
#pragma unroll
            for (int r = 0; r < 16; r++) sa0[r] = exp2f(sa0[r] - FM);
#pragma unroll
            for (int r = 0; r < 16; r++) sa1[r] = exp2f(sa1[r] - FM);
            float s0 = ((sa0[0] + sa0[1]) + (sa0[2] + sa0[3])) + ((sa0[4] + sa0[5]) + (sa0[6] + sa0[7]));
            float s1 = ((sa0[8] + sa0[9]) + (sa0[10] + sa0[11])) + ((sa0[12] + sa0[13]) + (sa0[14] + sa0[15]));
            float s2 = ((sa1[0] + sa1[1]) + (sa1[2] + sa1[3])) + ((sa1[4] + sa1[5]) + (sa1[6] + sa1[7]));
            float s3 = ((sa1[8] + sa1[9]) + (sa1[10] + sa1[11])) + ((sa1[12] + sa1[13]) + (sa1[14] + sa1[15]));
            float ps = (s0 + s1) + (s2 + s3);
            ps += __shfl_xor(ps, 32);
            l_r += ps;

            unsigned a01 = cvt_pk_bf16(sa0[0], sa0[1]),  a23 = cvt_pk_bf16(sa0[2], sa0[3]);
            unsigned a45 = cvt_pk_bf16(sa0[4], sa0[5]),  a67 = cvt_pk_bf16(sa0[6], sa0[7]);
            asm("v_permlane32_swap_b32 %0, %1" : "+v"(a01), "+v"(a45));
            asm("v_permlane32_swap_b32 %0, %1" : "+v"(a23), "+v"(a67));
            unsigned b01 = cvt_pk_bf16(sa0[8], sa0[9]),  b23 = cvt_pk_bf16(sa0[10], sa0[11]);
            unsigned b45 = cvt_pk_bf16(sa0[12], sa0[13]), b67 = cvt_pk_bf16(sa0[14], sa0[15]);
            asm("v_permlane32_swap_b32 %0, %1" : "+v"(b01), "+v"(b45));
            asm("v_permlane32_swap_b32 %0, %1" : "+v"(b23), "+v"(b67));
            unsigned c01 = cvt_pk_bf16(sa1[0], sa1[1]),  c23 = cvt_pk_bf16(sa1[2], sa1[3]);
            unsigned c45 = cvt_pk_bf16(sa1[4], sa1[5]),  c67 = cvt_pk_bf16(sa1[6], sa1[7]);
            asm("v_permlane32_swap_b32 %0, %1" : "+v"(c01), "+v"(c45));
            asm("v_permlane32_swap_b32 %0, %1" : "+v"(c23), "+v"(c67));
            unsigned d01 = cvt_pk_bf16(sa1[8], sa1[9]),  d23 = cvt_pk_bf16(sa1[10], sa1[11]);
            unsigned d45 = cvt_pk_bf16(sa1[12], sa1[13]), d67 = cvt_pk_bf16(sa1[14], sa1[15]);
            asm("v_permlane32_swap_b32 %0, %1" : "+v"(d01), "+v"(d45));
            asm("v_permlane32_swap_b32 %0, %1" : "+v"(d23), "+v"(d67));
            union { unsigned u[4]; short8 s; } f0s0, f1s0, f0s1, f1s1;
            f0s0.u[0] = a01; f0s0.u[1] = a23; f0s0.u[2] = a45; f0s0.u[3] = a67;
            f1s0.u[0] = b01; f1s0.u[1] = b23; f1s0.u[2] = b45; f1s0.u[3] = b67;
            f0s1.u[0] = c01; f0s1.u[1] = c23; f0s1.u[2] = c45; f0s1.u[3] = c67;
            f1s1.u[0] = d01; f1s1.u[1] = d23; f1s1.u[2] = d45; f1s1.u[3] = d67;

            short8 bv00 = *reinterpret_cast<const short8*>(vbase + ql * 128 + (((0 + hi8) << 4) ^ sw4));
            short8 bv01 = *reinterpret_cast<const short8*>(vbase + ql * 128 + (((2 + hi8) << 4) ^ sw4));
            short8 bv02 = *reinterpret_cast<const short8*>(vbase + ql * 128 + (((4 + hi8) << 4) ^ sw4));
            short8 bv03 = *reinterpret_cast<const short8*>(vbase + ql * 128 + (((6 + hi8) << 4) ^ sw4));
            short8 bv10 = *reinterpret_cast<const short8*>(vbase + (32 + ql) * 128 + (((0 + hi8) << 4) ^ sw4));
            short8 bv11 = *reinterpret_cast<const short8*>(vbase + (32 + ql) * 128 + (((2 + hi8) << 4) ^ sw4));
            short8 bv12 = *reinterpret_cast<const short8*>(vbase + (32 + ql) * 128 + (((4 + hi8) << 4) ^ sw4));
            short8 bv13 = *reinterpret_cast<const short8*>(vbase + (32 + ql) * 128 + (((6 + hi8) << 4) ^ sw4));
            o0 = __builtin_amdgcn_mfma_f32_32x32x16_bf16(f0s0.s, bv00, o0, 0, 0, 0);
            o1 = __builtin_amdgcn_mfma_f32_32x32x16_bf16(f0s0.s, bv10, o1, 0, 0, 0);
            o0 = __builtin_amdgcn_mfma_f32_32x32x16_bf16(f1s0.s, bv01, o0, 0, 0, 0);
            o1 = __builtin_amdgcn_mfma_f32_32x32x16_bf16(f1s0.s, bv11, o1, 0, 0, 0);
            o0 = __builtin_amdgcn_mfma_f32_32x32x16_bf16(f0s1.s, bv02, o0, 0, 0, 0);
            o1 = __builtin_amdgcn_mfma_f32_32x32x16_bf16(f0s1.s, bv12, o1, 0, 0, 0);
            o0 = __builtin_amdgcn_mfma_f32_32x32x16_bf16(f1s1.s, bv03, o0, 0, 0, 0);
            o1 = __builtin_amdgcn_mfma_f32_32x32x16_bf16(f1s1.s, bv13, o1, 0, 0, 0);
        } else {
            // ================= phase 2: heavy q, kv sub-half = pr =================
            const int sub = pr;
            short8 ak[4];
#pragma unroll
            for (int ks = 0; ks < 4; ks++)
                ak[ks] = *reinterpret_cast<const short8*>(
                    kbase + (sub * 32 + ql) * 128 + (((ks * 2 + hi8) << 4) ^ sw4));
            f32x16 sa = ZERO16;
#pragma unroll
            for (int ks = 0; ks < 4; ks++)
                sa = __builtin_amdgcn_mfma_f32_32x32x16_bf16(ak[ks], bq[ks], sa, 0, 0, 0);

            if (kvt == Hn - 1) {   // heavy diagonal tile
                const int qg = q0h + ql;
#pragma unroll
                for (int r = 0; r < 16; r++) {
                    int crow = (r & 3) + 8 * (r >> 2) + 4 * hi8;
                    if (kvb + sub * 32 + crow > qg) sa[r] = -1e30f;
                }
            }
#pragma unroll
            for (int r = 0; r < 16; r++) sa[r] = exp2f(sa[r] - FM);
            float s0 = ((sa[0] + sa[1]) + (sa[2] + sa[3])) + ((sa[4] + sa[5]) + (sa[6] + sa[7]));
            float s1 = ((sa[8] + sa[9]) + (sa[10] + sa[11])) + ((sa[12] + sa[13]) + (sa[14] + sa[15]));
            float ps = s0 + s1;
            ps += __shfl_xor(ps, 32);
            l_r += ps;

            unsigned a01 = cvt_pk_bf16(sa[0], sa[1]),  a23 = cvt_pk_bf16(sa[2], sa[3]);
            unsigned a45 = cvt_pk_bf16(sa[4], sa[5]),  a67 = cvt_pk_bf16(sa[6], sa[7]);
            asm("v_permlane32_swap_b32 %0, %1" : "+v"(a01), "+v"(a45));
            asm("v_permlane32_swap_b32 %0, %1" : "+v"(a23), "+v"(a67));
            unsigned b01 = cvt_pk_bf16(sa[8], sa[9]),  b23 = cvt_pk_bf16(sa[10], sa[11]);
            unsigned b45 = cvt_pk_bf16(sa[12], sa[13]), b67 = cvt_pk_bf16(sa[14], sa[15]);
            asm("v_permlane32_swap_b32 %0, %1" : "+v"(b01), "+v"(b45));
            asm("v_permlane32_swap_b32 %0, %1" : "+v"(b23), "+v"(b67));
            union { unsigned u[4]; short8 s; } f0, f1;
            f0.u[0] = a01; f0.u[1] = a23; f0.u[2] = a45; f0.u[3] = a67;
            f1.u[0] = b01; f1.u[1] = b23; f1.u[2] = b45; f1.u[3] = b67;

            short8 bv00 = *reinterpret_cast<const short8*>(vbase + ql * 128 + (((sub * 4 + 0 + hi8) << 4) ^ sw4));
            short8 bv01 = *reinterpret_cast<const short8*>(vbase + ql * 128 + (((sub * 4 + 2 + hi8) << 4) ^ sw4));
            short8 bv10 = *reinterpret_cast<const short8*>(vbase + (32 + ql) * 128 + (((sub * 4 + 0 + hi8) << 4) ^ sw4));
            short8 bv11 = *reinterpret_cast<const short8*>(vbase + (32 + ql) * 128 + (((sub * 4 + 2 + hi8) << 4) ^ sw4));
            o0 = __builtin_amdgcn_mfma_f32_32x32x16_bf16(f0.s, bv00, o0, 0, 0, 0);
            o1 = __builtin_amdgcn_mfma_f32_32x32x16_bf16(f0.s, bv10, o1, 0, 0, 0);
            o0 = __builtin_amdgcn_mfma_f32_32x32x16_bf16(f1.s, bv01, o0, 0, 0, 0);
            o1 = __builtin_amdgcn_mfma_f32_32x32x16_bf16(f1.s, bv11, o1, 0, 0, 0);
        }
        if (more) STAGE_V_WRITE(it ^ 1);
        __syncthreads();
    }

    // ---- merge pair-1 heavy partials into pair 0, write heavy output ----
    float* xf = (float*)&Ks[0][0][0];   // 2*64*32 floats = 16 KB (fits Ks)
    float* xl = (float*)&Vt[0][0][0];
    if (pr == 1) {
        float* dst = xf + ((size_t)(w - 2) * 64 + l) * 32;
#pragma unroll
        for (int r = 0; r < 16; r++) { dst[r] = o0[r]; dst[16 + r] = o1[r]; }
        xl[(w - 2) * 64 + l] = l_r;
    }
    __syncthreads();
    if (pr == 0) {
        const float* src = xf + ((size_t)w * 64 + l) * 32;
#pragma unroll
        for (int r = 0; r < 16; r++) { o0[r] += src[r]; o1[r] += src[16 + r]; }
        l_r += xl[w * 64 + l];
        WRITE_OUT(q0h);
    }
#undef STAGE_K
#undef STAGE_V_LOAD
#undef STAGE_V_WRITE
#undef WRITE_OUT
}

extern "C" void kernel_launch(void* const* d_in, const int* in_sizes, int n_in,
                              void* d_out, int out_size, void* d_ws, size_t ws_size,
                              hipStream_t stream) {
    const float* x     = (const float*)d_in[0];   // [4096][1024]
    const float* Wqkv  = (const float*)d_in[1];   // [1024][3072]
    const float* Wproj = (const float*)d_in[2];   // [1024][1024]
    float* out = (float*)d_out;                    // [4096][1024] fp32

    unsigned short* xb     = (unsigned short*)d_ws;            // 4096*1024
    unsigned short* wqkvt  = xb + (size_t)MM * DD;             // 3072*1024
    unsigned short* wprojt = wqkvt + (size_t)N3 * DD;          // 1024*1024
    unsigned short* qkv    = wprojt + (size_t)DD * DD;         // 4096*3072
    unsigned short* attout = qkv + (size_t)MM * N3;            // 4096*1024
    size_t need = ((size_t)MM * DD + (size_t)N3 * DD + (size_t)DD * DD +
                   (size_t)MM * N3 + (size_t)MM * DD) * 2;
    if (ws_size < need) return;

    const float sc = 0.125f * 1.44269504088896f;   // 1/sqrt(64) * log2(e), folded into Q

    cast_bf16_kernel<<<1024, 256, 0, stream>>>(x, xb, MM * DD / 8);
    transpose_cast_kernel<<<dim3(N3 / 32, DD / 32), dim3(32, 8), 0, stream>>>(Wqkv, wqkvt, DD, N3);
    transpose_cast_kernel<<<dim3(DD / 32, DD / 32), dim3(32, 8), 0, stream>>>(Wproj, wprojt, DD, DD);

    gemm_kernel<1><<<dim3(N3 / 128, MM / 128), 256, 0, stream>>>(xb, wqkvt, qkv, MM, N3, DD, DD, sc);

    attn_kernel<<<dim3(HH, 16, BB), 256, 0, stream>>>(qkv, attout);

    gemm_kernel<0><<<dim3(DD / 128, MM / 128), 256, 0, stream>>>(attout, wprojt, out, MM, DD, DD, 0, 1.0f);
}

// Round 7
// 151.305 us; speedup vs baseline: 1.2427x; 1.0576x over previous
//
#include <hip/hip_runtime.h>
#include <hip/hip_bf16.h>

// Problem: B=2, T=2048, D=1024, H=16, DH=64
#define BB 2
#define TT 2048
#define DD 1024
#define HH 16
#define MM (BB*TT)        // 4096
#define N3 (3*DD)         // 3072
#define QKW 2048          // qkv2 row width (Q|K only)

typedef __attribute__((ext_vector_type(8))) short short8;
typedef __attribute__((ext_vector_type(4))) float f32x4;
typedef __attribute__((ext_vector_type(16))) float f32x16;

#define ZERO16 (f32x16){0,0,0,0,0,0,0,0,0,0,0,0,0,0,0,0}

#define GLDS16(g, l) __builtin_amdgcn_global_load_lds( \
    (const __attribute__((address_space(1))) void*)(g), \
    (__attribute__((address_space(3))) void*)(l), 16, 0, 0)

__device__ __forceinline__ unsigned short f2bf(float f) {
    union { float f; unsigned u; } v; v.f = f;
    unsigned r = v.u + 0x7FFFu + ((v.u >> 16) & 1u);
    return (unsigned short)(r >> 16);
}

__device__ __forceinline__ unsigned cvt_pk_bf16(float lo, float hi) {
    unsigned r;
    asm("v_cvt_pk_bf16_f32 %0, %1, %2" : "=v"(r) : "v"(lo), "v"(hi));
    return r;
}

// ---------------- cast fp32 -> bf16, vectorized ----------------
__global__ void cast_bf16_kernel(const float* __restrict__ src,
                                 unsigned short* __restrict__ dst, int n8) {
    int i = blockIdx.x * blockDim.x + threadIdx.x;
    int stride = gridDim.x * blockDim.x;
    for (; i < n8; i += stride) {
        const float4* s = reinterpret_cast<const float4*>(src) + (size_t)i * 2;
        float4 a = s[0], b = s[1];
        unsigned short r[8] = {f2bf(a.x), f2bf(a.y), f2bf(a.z), f2bf(a.w),
                               f2bf(b.x), f2bf(b.y), f2bf(b.z), f2bf(b.w)};
        *reinterpret_cast<uint4*>(dst + (size_t)i * 8) = *reinterpret_cast<uint4*>(r);
    }
}

// ---------------- transpose + cast: src[rows][cols] f32 -> dst[cols][rows] bf16 ----------------
__global__ void transpose_cast_kernel(const float* __restrict__ src,
                                      unsigned short* __restrict__ dst,
                                      int rows, int cols) {
    __shared__ float tile[32][33];
    int c0 = blockIdx.x * 32, r0 = blockIdx.y * 32;
    int tx = threadIdx.x, ty = threadIdx.y;   // block (32,8)
#pragma unroll
    for (int i = 0; i < 4; i++) {
        int r = ty + i * 8;
        tile[r][tx] = src[(size_t)(r0 + r) * cols + c0 + tx];
    }
    __syncthreads();
#pragma unroll
    for (int i = 0; i < 4; i++) {
        int r = ty + i * 8;
        dst[(size_t)(c0 + r) * rows + r0 + tx] = f2bf(tile[tx][r]);
    }
}

// ---------------- GEMM (m97 structure): C = A[M][K] * Bt[N][K]^T ----------------
// MODE 0: write f32 to Cout[M][N].
// MODE 1 (qkv): cols [0,2048) -> bf16 qkv2[row][2048] (cols<1024 scaled);
//               cols [2048,3072) -> transposed bf16 Vout[col-2048][M] (packed 4-row stores).
template<int MODE>
__global__ __launch_bounds__(256)
void gemm_kernel(const unsigned short* __restrict__ A,
                 const unsigned short* __restrict__ Bt,
                 void* __restrict__ Cout, unsigned short* __restrict__ Vout,
                 int M, int N, int K, float scale) {
    __shared__ unsigned short As[128][64];
    __shared__ unsigned short Bs[128][64];
    const int nbx = gridDim.x;
    const int id = blockIdx.y * nbx + blockIdx.x;
    const int cpx = (nbx * gridDim.y) >> 3;
    const int swz = (id & 7) * cpx + (id >> 3);
    const int tm = (swz / nbx) * 128, tn = (swz % nbx) * 128;
    const int t = threadIdx.x;
    const int w = t >> 6, lane = t & 63, lo = lane & 15, hi = lane >> 4;
    const int wr = w >> 1, wc = w & 1;

    f32x4 acc[4][4];
#pragma unroll
    for (int i = 0; i < 4; i++)
#pragma unroll
        for (int j = 0; j < 4; j++) acc[i][j] = (f32x4){0.f, 0.f, 0.f, 0.f};

    const int srow = w * 32 + (lane >> 3);
    const int scol = (lane & 7) * 8;
    const unsigned short* ga = &A[(size_t)(tm + srow) * K + scol];
    const unsigned short* gb = &Bt[(size_t)(tn + srow) * K + scol];

    for (int k0 = 0; k0 < K; k0 += 64) {
        __syncthreads();
#pragma unroll
        for (int i = 0; i < 4; i++) {
            GLDS16(ga + (size_t)(i * 8) * K + k0, &As[w * 32 + i * 8][0]);
            GLDS16(gb + (size_t)(i * 8) * K + k0, &Bs[w * 32 + i * 8][0]);
        }
        __syncthreads();

        short8 af[4][2], bf[4][2];
#pragma unroll
        for (int i = 0; i < 4; i++)
#pragma unroll
            for (int ks = 0; ks < 2; ks++) {
                af[i][ks] = *reinterpret_cast<const short8*>(&As[wr * 64 + i * 16 + lo][ks * 32 + hi * 8]);
                bf[i][ks] = *reinterpret_cast<const short8*>(&Bs[wc * 64 + i * 16 + lo][ks * 32 + hi * 8]);
            }
#pragma unroll
        for (int ks = 0; ks < 2; ks++)
#pragma unroll
            for (int i = 0; i < 4; i++)
#pragma unroll
                for (int j = 0; j < 4; j++)
                    acc[i][j] = __builtin_amdgcn_mfma_f32_16x16x32_bf16(af[i][ks], bf[j][ks], acc[i][j], 0, 0, 0);
    }
#pragma unroll
    for (int i = 0; i < 4; i++)
#pragma unroll
        for (int j = 0; j < 4; j++) {
            const int col = tn + wc * 64 + j * 16 + lo;
            const int row0 = tm + wr * 64 + i * 16 + hi * 4;
            if (MODE == 0) {
#pragma unroll
                for (int r = 0; r < 4; r++)
                    ((float*)Cout)[(size_t)(row0 + r) * N + col] = acc[i][j][r];
            } else {
                if (col < 2 * DD) {
                    float s = (col < DD) ? scale : 1.0f;
#pragma unroll
                    for (int r = 0; r < 4; r++)
                        ((unsigned short*)Cout)[(size_t)(row0 + r) * QKW + col] = f2bf(acc[i][j][r] * s);
                } else {
                    unsigned short pk[4];
#pragma unroll
                    for (int r = 0; r < 4; r++) pk[r] = f2bf(acc[i][j][r]);
                    *reinterpret_cast<uint2*>(&Vout[(size_t)(col - 2 * DD) * MM + row0]) =
                        *reinterpret_cast<uint2*>(pk);
                }
            }
        }
}

// ---------------- Flash attention: fixed-shift-free softmax, MFMA row-sum, GLDS K&V ----------------
// grid (H, 16 pairs, B), 256 threads = 4 waves.
// Pair p: light q-tile qcl=p, heavy q-tile qch=31-p. L=p+1, Hn=32-p.
// Phase 1 (kvt<L): pair0 -> heavy full tile, pair1 -> light full tile.
// Phase 2 (kvt>=L): pair0 -> kv rows 0-31, pair1 -> kv rows 32-63 of heavy (order-free sums).
__global__ __launch_bounds__(256)
void attn_kernel(const unsigned short* __restrict__ qkv2,   // [B*T][2048] Q|K bf16
                 const unsigned short* __restrict__ vtg,    // [1024][B*T]  V^T bf16
                 unsigned short* __restrict__ outp) {
    __shared__ unsigned short Ks[2][64][64];   // K[kv][dh], XOR-swizzled rows
    __shared__ unsigned short Vt[2][64][64];   // V^T[dh][kv], XOR-swizzled rows

    const int b = blockIdx.z, h = blockIdx.x, p = blockIdx.y;
    const int qcl = p, qch = 31 - p;
    const int L = p + 1, Hn = 32 - p;
    const int t = threadIdx.x;
    const int w = t >> 6, l = t & 63, ql = l & 31, hi8 = l >> 5;
    const int pr = w >> 1, rg = w & 1;
    const int q0h = qch * 64 + rg * 32;
    const int q0p = (pr ? qcl : qch) * 64 + rg * 32;
    const unsigned short* base2 = qkv2 + (size_t)b * TT * QKW;

    // Q B-fragments (pre-scaled by 1/sqrt(dh)*log2e in GEMM1)
    short8 bq[4];
#pragma unroll
    for (int ks = 0; ks < 4; ks++)
        bq[ks] = *reinterpret_cast<const short8*>(
            &base2[(size_t)(q0p + ql) * QKW + h * 64 + ks * 16 + hi8 * 8]);

    f32x16 o0 = ZERO16, o1 = ZERO16, lD = ZERO16;

    // constant ones B-fragment (bf16 1.0) for MFMA row-sum
    short8 ones1;
#pragma unroll
    for (int j = 0; j < 8; j++) ones1[j] = (short)0x3F80;

    // staging pointers (pre-swizzled source, GLDS linear dest)
    const int krow = l >> 3;
    const int kc8 = (l & 7) ^ krow;
    const unsigned short* gk = &base2[(size_t)(w * 8 + krow) * QKW + DD + h * 64 + kc8 * 8];
    const unsigned short* gv = &vtg[(size_t)(h * 64 + w * 8 + krow) * MM + b * TT + kc8 * 8];

#define STAGE(KVB, BUF) { \
    GLDS16(gk + (size_t)(KVB) * QKW, &Ks[BUF][w * 8][0]); \
    GLDS16(gk + (size_t)((KVB) + 32) * QKW, &Ks[BUF][32 + w * 8][0]); \
    GLDS16(gv + (KVB), &Vt[BUF][w * 8][0]); \
    GLDS16(gv + (size_t)32 * MM + (KVB), &Vt[BUF][32 + w * 8][0]); }

#define WRITE_OUT(Q0) { \
    _Pragma("unroll") \
    for (int r = 0; r < 16; r++) { \
        int src = (r & 3) + 8 * (r >> 2) + 4 * hi8; \
        float inv = 1.0f / lD[r]; \
        size_t off = (size_t)(b * TT + (Q0) + src) * DD + h * 64 + ql; \
        outp[off] = f2bf(o0[r] * inv); \
        outp[off + 32] = f2bf(o1[r] * inv); \
    } }

    STAGE(0, 0);
    __syncthreads();

    const int sw4 = (ql & 7) << 4;
    int it = 0;
    for (int kvt = 0; kvt < Hn; kvt++, it ^= 1) {
        const bool more = (kvt + 1) < Hn;
        if (more) STAGE((kvt + 1) * 64, it ^ 1);

        if (kvt == L && pr == 1) {
            // light tile done: emit, reset, switch to heavy Q
            WRITE_OUT(qcl * 64 + rg * 32);
            o0 = ZERO16; o1 = ZERO16; lD = ZERO16;
#pragma unroll
            for (int ks = 0; ks < 4; ks++)
                bq[ks] = *reinterpret_cast<const short8*>(
                    &base2[(size_t)(q0h + ql) * QKW + h * 64 + ks * 16 + hi8 * 8]);
        }

        const char* kbase = (const char*)&Ks[it][0][0];
        const char* vbase = (const char*)&Vt[it][0][0];
        const int kvb = kvt * 64;

        if (kvt < L) {
            // ========== phase 1: full 64-kv tile ==========
            short8 ak0[4], ak1[4];
#pragma unroll
            for (int ks = 0; ks < 4; ks++) {
                ak0[ks] = *reinterpret_cast<const short8*>(kbase + ql * 128 + (((ks * 2 + hi8) << 4) ^ sw4));
                ak1[ks] = *reinterpret_cast<const short8*>(kbase + (32 + ql) * 128 + (((ks * 2 + hi8) << 4) ^ sw4));
            }
            f32x16 sa0 = ZERO16, sa1 = ZERO16;
#pragma unroll
            for (int ks = 0; ks < 4; ks++) {
                sa0 = __builtin_amdgcn_mfma_f32_32x32x16_bf16(ak0[ks], bq[ks], sa0, 0, 0, 0);
                sa1 = __builtin_amdgcn_mfma_f32_32x32x16_bf16(ak1[ks], bq[ks], sa1, 0, 0, 0);
            }
            if (pr == 1 && kvt == L - 1) {   // light diagonal tile
                const int qg = q0p + ql;
#pragma unroll
                for (int r = 0; r < 16; r++) {
                    int crow = (r & 3) + 8 * (r >> 2) + 4 * hi8;
                    if (kvb + crow > qg) sa0[r] = -1e30f;
                    if (kvb + 32 + crow > qg) sa1[r] = -1e30f;
                }
            }
#pragma unroll
            for (int r = 0; r < 16; r++) sa0[r] = exp2f(sa0[r]);
#pragma unroll
            for (int r = 0; r < 16; r++) sa1[r] = exp2f(sa1[r]);

            unsigned a01 = cvt_pk_bf16(sa0[0], sa0[1]),  a23 = cvt_pk_bf16(sa0[2], sa0[3]);
            unsigned a45 = cvt_pk_bf16(sa0[4], sa0[5]),  a67 = cvt_pk_bf16(sa0[6], sa0[7]);
            asm("v_permlane32_swap_b32 %0, %1" : "+v"(a01), "+v"(a45));
            asm("v_permlane32_swap_b32 %0, %1" : "+v"(a23), "+v"(a67));
            unsigned b01 = cvt_pk_bf16(sa0[8], sa0[9]),  b23 = cvt_pk_bf16(sa0[10], sa0[11]);
            unsigned b45 = cvt_pk_bf16(sa0[12], sa0[13]), b67 = cvt_pk_bf16(sa0[14], sa0[15]);
            asm("v_permlane32_swap_b32 %0, %1" : "+v"(b01), "+v"(b45));
            asm("v_permlane32_swap_b32 %0, %1" : "+v"(b23), "+v"(b67));
            unsigned c01 = cvt_pk_bf16(sa1[0], sa1[1]),  c23 = cvt_pk_bf16(sa1[2], sa1[3]);
            unsigned c45 = cvt_pk_bf16(sa1[4], sa1[5]),  c67 = cvt_pk_bf16(sa1[6], sa1[7]);
            asm("v_permlane32_swap_b32 %0, %1" : "+v"(c01), "+v"(c45));
            asm("v_permlane32_swap_b32 %0, %1" : "+v"(c23), "+v"(c67));
            unsigned d01 = cvt_pk_bf16(sa1[8], sa1[9]),  d23 = cvt_pk_bf16(sa1[10], sa1[11]);
            unsigned d45 = cvt_pk_bf16(sa1[12], sa1[13]), d67 = cvt_pk_bf16(sa1[14], sa1[15]);
            asm("v_permlane32_swap_b32 %0, %1" : "+v"(d01), "+v"(d45));
            asm("v_permlane32_swap_b32 %0, %1" : "+v"(d23), "+v"(d67));
            union { unsigned u[4]; short8 s; } f0s0, f1s0, f0s1, f1s1;
            f0s0.u[0] = a01; f0s0.u[1] = a23; f0s0.u[2] = a45; f0s0.u[3] = a67;
            f1s0.u[0] = b01; f1s0.u[1] = b23; f1s0.u[2] = b45; f1s0.u[3] = b67;
            f0s1.u[0] = c01; f0s1.u[1] = c23; f0s1.u[2] = c45; f0s1.u[3] = c67;
            f1s1.u[0] = d01; f1s1.u[1] = d23; f1s1.u[2] = d45; f1s1.u[3] = d67;

            // row-sum via MFMA-ones (matrix pipe is idle; D-layout matches o0 rows)
            lD = __builtin_amdgcn_mfma_f32_32x32x16_bf16(f0s0.s, ones1, lD, 0, 0, 0);
            lD = __builtin_amdgcn_mfma_f32_32x32x16_bf16(f1s0.s, ones1, lD, 0, 0, 0);
            lD = __builtin_amdgcn_mfma_f32_32x32x16_bf16(f0s1.s, ones1, lD, 0, 0, 0);
            lD = __builtin_amdgcn_mfma_f32_32x32x16_bf16(f1s1.s, ones1, lD, 0, 0, 0);

            short8 bv00 = *reinterpret_cast<const short8*>(vbase + ql * 128 + (((0 + hi8) << 4) ^ sw4));
            short8 bv01 = *reinterpret_cast<const short8*>(vbase + ql * 128 + (((2 + hi8) << 4) ^ sw4));
            short8 bv02 = *reinterpret_cast<const short8*>(vbase + ql * 128 + (((4 + hi8) << 4) ^ sw4));
            short8 bv03 = *reinterpret_cast<const short8*>(vbase + ql * 128 + (((6 + hi8) << 4) ^ sw4));
            short8 bv10 = *reinterpret_cast<const short8*>(vbase + (32 + ql) * 128 + (((0 + hi8) << 4) ^ sw4));
            short8 bv11 = *reinterpret_cast<const short8*>(vbase + (32 + ql) * 128 + (((2 + hi8) << 4) ^ sw4));
            short8 bv12 = *reinterpret_cast<const short8*>(vbase + (32 + ql) * 128 + (((4 + hi8) << 4) ^ sw4));
            short8 bv13 = *reinterpret_cast<const short8*>(vbase + (32 + ql) * 128 + (((6 + hi8) << 4) ^ sw4));
            o0 = __builtin_amdgcn_mfma_f32_32x32x16_bf16(f0s0.s, bv00, o0, 0, 0, 0);
            o1 = __builtin_amdgcn_mfma_f32_32x32x16_bf16(f0s0.s, bv10, o1, 0, 0, 0);
            o0 = __builtin_amdgcn_mfma_f32_32x32x16_bf16(f1s0.s, bv01, o0, 0, 0, 0);
            o1 = __builtin_amdgcn_mfma_f32_32x32x16_bf16(f1s0.s, bv11, o1, 0, 0, 0);
            o0 = __builtin_amdgcn_mfma_f32_32x32x16_bf16(f0s1.s, bv02, o0, 0, 0, 0);
            o1 = __builtin_amdgcn_mfma_f32_32x32x16_bf16(f0s1.s, bv12, o1, 0, 0, 0);
            o0 = __builtin_amdgcn_mfma_f32_32x32x16_bf16(f1s1.s, bv03, o0, 0, 0, 0);
            o1 = __builtin_amdgcn_mfma_f32_32x32x16_bf16(f1s1.s, bv13, o1, 0, 0, 0);
        } else {
            // ========== phase 2: heavy q, kv sub-half = pr ==========
            const int sub = pr;
            short8 ak[4];
#pragma unroll
            for (int ks = 0; ks < 4; ks++)
                ak[ks] = *reinterpret_cast<const short8*>(
                    kbase + (sub * 32 + ql) * 128 + (((ks * 2 + hi8) << 4) ^ sw4));
            f32x16 sa = ZERO16;
#pragma unroll
            for (int ks = 0; ks < 4; ks++)
                sa = __builtin_amdgcn_mfma_f32_32x32x16_bf16(ak[ks], bq[ks], sa, 0, 0, 0);

            if (kvt == Hn - 1) {   // heavy diagonal tile
                const int qg = q0h + ql;
#pragma unroll
                for (int r = 0; r < 16; r++) {
                    int crow = (r & 3) + 8 * (r >> 2) + 4 * hi8;
                    if (kvb + sub * 32 + crow > qg) sa[r] = -1e30f;
                }
            }
#pragma unroll
            for (int r = 0; r < 16; r++) sa[r] = exp2f(sa[r]);

            unsigned a01 = cvt_pk_bf16(sa[0], sa[1]),  a23 = cvt_pk_bf16(sa[2], sa[3]);
            unsigned a45 = cvt_pk_bf16(sa[4], sa[5]),  a67 = cvt_pk_bf16(sa[6], sa[7]);
            asm("v_permlane32_swap_b32 %0, %1" : "+v"(a01), "+v"(a45));
            asm("v_permlane32_swap_b32 %0, %1" : "+v"(a23), "+v"(a67));
            unsigned b01 = cvt_pk_bf16(sa[8], sa[9]),  b23 = cvt_pk_bf16(sa[10], sa[11]);
            unsigned b45 = cvt_pk_bf16(sa[12], sa[13]), b67 = cvt_pk_bf16(sa[14], sa[15]);
            asm("v_permlane32_swap_b32 %0, %1" : "+v"(b01), "+v"(b45));
            asm("v_permlane32_swap_b32 %0, %1" : "+v"(b23), "+v"(b67));
            union { unsigned u[4]; short8 s; } f0, f1;
            f0.u[0] = a01; f0.u[1] = a23; f0.u[2] = a45; f0.u[3] = a67;
            f1.u[0] = b01; f1.u[1] = b23; f1.u[2] = b45; f1.u[3] = b67;

            lD = __builtin_amdgcn_mfma_f32_32x32x16_bf16(f0.s, ones1, lD, 0, 0, 0);
            lD = __builtin_amdgcn_mfma_f32_32x32x16_bf16(f1.s, ones1, lD, 0, 0, 0);

            short8 bv00 = *reinterpret_cast<const short8*>(vbase + ql * 128 + (((sub * 4 + 0 + hi8) << 4) ^ sw4));
            short8 bv01 = *reinterpret_cast<const short8*>(vbase + ql * 128 + (((sub * 4 + 2 + hi8) << 4) ^ sw4));
            short8 bv10 = *reinterpret_cast<const short8*>(vbase + (32 + ql) * 128 + (((sub * 4 + 0 + hi8) << 4) ^ sw4));
            short8 bv11 = *reinterpret_cast<const short8*>(vbase + (32 + ql) * 128 + (((sub * 4 + 2 + hi8) << 4) ^ sw4));
            o0 = __builtin_amdgcn_mfma_f32_32x32x16_bf16(f0.s, bv00, o0, 0, 0, 0);
            o1 = __builtin_amdgcn_mfma_f32_32x32x16_bf16(f0.s, bv10, o1, 0, 0, 0);
            o0 = __builtin_amdgcn_mfma_f32_32x32x16_bf16(f1.s, bv01, o0, 0, 0, 0);
            o1 = __builtin_amdgcn_mfma_f32_32x32x16_bf16(f1.s, bv11, o1, 0, 0, 0);
        }
        __syncthreads();
    }

    // ---- merge pair-1 heavy partials into pair 0 ([r][thread] layout: conflict-free) ----
    float* xf = (float*)&Ks[0][0][0];   // 32 x 128 floats = 16 KB
    float* xl = (float*)&Vt[0][0][0];   // 16 x 128 floats = 8 KB
    const int tid128 = (w & 1) * 64 + l;
    if (pr == 1) {
#pragma unroll
        for (int r = 0; r < 16; r++) {
            xf[r * 128 + tid128] = o0[r];
            xf[(16 + r) * 128 + tid128] = o1[r];
            xl[r * 128 + tid128] = lD[r];
        }
    }
    __syncthreads();
    if (pr == 0) {
#pragma unroll
        for (int r = 0; r < 16; r++) {
            o0[r] += xf[r * 128 + tid128];
            o1[r] += xf[(16 + r) * 128 + tid128];
            lD[r] += xl[r * 128 + tid128];
        }
        WRITE_OUT(q0h);
    }
#undef STAGE
#undef WRITE_OUT
}

extern "C" void kernel_launch(void* const* d_in, const int* in_sizes, int n_in,
                              void* d_out, int out_size, void* d_ws, size_t ws_size,
                              hipStream_t stream) {
    const float* x     = (const float*)d_in[0];   // [4096][1024]
    const float* Wqkv  = (const float*)d_in[1];   // [1024][3072]
    const float* Wproj = (const float*)d_in[2];   // [1024][1024]
    float* out = (float*)d_out;                    // [4096][1024] fp32

    unsigned short* xb     = (unsigned short*)d_ws;            // 4096*1024
    unsigned short* wqkvt  = xb + (size_t)MM * DD;             // 3072*1024
    unsigned short* wprojt = wqkvt + (size_t)N3 * DD;          // 1024*1024
    unsigned short* qkv2   = wprojt + (size_t)DD * DD;         // 4096*2048 (Q|K)
    unsigned short* vtg    = qkv2 + (size_t)MM * QKW;          // 1024*4096 (V^T)
    unsigned short* attout = vtg + (size_t)DD * MM;            // 4096*1024
    size_t need = ((size_t)MM * DD + (size_t)N3 * DD + (size_t)DD * DD +
                   (size_t)MM * QKW + (size_t)DD * MM + (size_t)MM * DD) * 2;
    if (ws_size < need) return;

    const float sc = 0.125f * 1.44269504088896f;   // 1/sqrt(64) * log2(e), folded into Q

    cast_bf16_kernel<<<1024, 256, 0, stream>>>(x, xb, MM * DD / 8);
    transpose_cast_kernel<<<dim3(N3 / 32, DD / 32), dim3(32, 8), 0, stream>>>(Wqkv, wqkvt, DD, N3);
    transpose_cast_kernel<<<dim3(DD / 32, DD / 32), dim3(32, 8), 0, stream>>>(Wproj, wprojt, DD, DD);

    gemm_kernel<1><<<dim3(N3 / 128, MM / 128), 256, 0, stream>>>(xb, wqkvt, qkv2, vtg, MM, N3, DD, sc);

    attn_kernel<<<dim3(HH, 16, BB), 256, 0, stream>>>(qkv2, vtg, attout);

    gemm_kernel<0><<<dim3(DD / 128, MM / 128), 256, 0, stream>>>(attout, wprojt, out, nullptr, MM, DD, DD, 1.0f);
}

// Round 8
// 135.028 us; speedup vs baseline: 1.3926x; 1.1205x over previous
//
#include <hip/hip_runtime.h>
#include <hip/hip_bf16.h>

// Problem: B=2, T=2048, D=1024, H=16, DH=64
#define BB 2
#define TT 2048
#define DD 1024
#define HH 16
#define MM (BB*TT)        // 4096
#define N3 (3*DD)         // 3072
#define QKW 2048          // qkv2 row width (Q|K only)

typedef __attribute__((ext_vector_type(8))) short short8;
typedef __attribute__((ext_vector_type(4))) float f32x4;
typedef __attribute__((ext_vector_type(16))) float f32x16;

#define ZERO16 (f32x16){0,0,0,0,0,0,0,0,0,0,0,0,0,0,0,0}

#define GLDS16(g, l) __builtin_amdgcn_global_load_lds( \
    (const __attribute__((address_space(1))) void*)(g), \
    (__attribute__((address_space(3))) void*)(l), 16, 0, 0)

__device__ __forceinline__ unsigned short f2bf(float f) {
    union { float f; unsigned u; } v; v.f = f;
    unsigned r = v.u + 0x7FFFu + ((v.u >> 16) & 1u);
    return (unsigned short)(r >> 16);
}

__device__ __forceinline__ unsigned cvt_pk_bf16(float lo, float hi) {
    unsigned r;
    asm("v_cvt_pk_bf16_f32 %0, %1, %2" : "=v"(r) : "v"(lo), "v"(hi));
    return r;
}

// ---------------- cast fp32 -> bf16, vectorized ----------------
__global__ void cast_bf16_kernel(const float* __restrict__ src,
                                 unsigned short* __restrict__ dst, int n8) {
    int i = blockIdx.x * blockDim.x + threadIdx.x;
    int stride = gridDim.x * blockDim.x;
    for (; i < n8; i += stride) {
        const float4* s = reinterpret_cast<const float4*>(src) + (size_t)i * 2;
        float4 a = s[0], b = s[1];
        unsigned short r[8] = {f2bf(a.x), f2bf(a.y), f2bf(a.z), f2bf(a.w),
                               f2bf(b.x), f2bf(b.y), f2bf(b.z), f2bf(b.w)};
        *reinterpret_cast<uint4*>(dst + (size_t)i * 8) = *reinterpret_cast<uint4*>(r);
    }
}

// ---------------- transpose + cast: src[rows][cols] f32 -> dst[cols][rows] bf16 ----------------
__global__ void transpose_cast_kernel(const float* __restrict__ src,
                                      unsigned short* __restrict__ dst,
                                      int rows, int cols) {
    __shared__ float tile[32][33];
    int c0 = blockIdx.x * 32, r0 = blockIdx.y * 32;
    int tx = threadIdx.x, ty = threadIdx.y;   // block (32,8)
#pragma unroll
    for (int i = 0; i < 4; i++) {
        int r = ty + i * 8;
        tile[r][tx] = src[(size_t)(r0 + r) * cols + c0 + tx];
    }
    __syncthreads();
#pragma unroll
    for (int i = 0; i < 4; i++) {
        int r = ty + i * 8;
        dst[(size_t)(c0 + r) * rows + r0 + tx] = f2bf(tile[tx][r]);
    }
}

// ================= 256x256 8-phase GEMM for QKV (M=4096, N=3072, K=1024) =================
// 512 threads = 8 waves (2M x 4N). LDS: A/B double-buffered per K-tile parity, 128 KB.
// Counted vmcnt (6/4), XOR-swizzled LDS (pre-swizzled GLDS source), setprio MFMA clusters.
// Epilogue: cols [0,2048) -> bf16 qkv2 (cols<1024 scaled); cols [2048,3072) -> V^T.
__global__ __launch_bounds__(512, 2)
void gemm256_qkv(const unsigned short* __restrict__ A,
                 const unsigned short* __restrict__ Bt,
                 unsigned short* __restrict__ qkv2,
                 unsigned short* __restrict__ Vout,
                 float scale) {
    __shared__ unsigned short Al[2][2][128][64];   // [kt parity][half][row][col]
    __shared__ unsigned short Bl[2][2][128][64];

    const int id = blockIdx.y * 12 + blockIdx.x;          // nwg = 192, %8 == 0
    const int swzid = (id & 7) * 24 + (id >> 3);          // bijective XCD swizzle
    const int tm = (swzid / 12) * 256, tn = (swzid % 12) * 256;
    const int t = threadIdx.x, w = t >> 6, l = t & 63;
    const int wm = w >> 2, wn = w & 3, bh = wn >> 1;
    const int lo = l & 15, hi = l >> 4;
    const int srow = l >> 3;                 // 0..7 (staging row within 8-row group)
    const int sg = (l & 7) ^ srow;           // pre-swizzled source granule

    f32x4 acc[8][4];
#pragma unroll
    for (int i = 0; i < 8; i++)
#pragma unroll
        for (int j = 0; j < 4; j++) acc[i][j] = (f32x4){0.f, 0.f, 0.f, 0.f};

    const unsigned short* Abase = A + (size_t)(tm + w * 16 + srow) * 1024 + sg * 8;
    const unsigned short* Bbase = Bt + (size_t)(tn + w * 16 + srow) * 1024 + sg * 8;

// stage half H of K-tile KT (2 GLDS16 per wave; dest linear, source pre-swizzled)
#define STG_A(KT, H) { \
    GLDS16(Abase + (size_t)(H) * 128 * 1024 + ((KT) & 15) * 64, &Al[(KT) & 1][H][w * 16][0]); \
    GLDS16(Abase + (size_t)(H) * 128 * 1024 + 8 * 1024 + ((KT) & 15) * 64, &Al[(KT) & 1][H][w * 16 + 8][0]); }
#define STG_B(KT, H) { \
    GLDS16(Bbase + (size_t)(H) * 128 * 1024 + ((KT) & 15) * 64, &Bl[(KT) & 1][H][w * 16][0]); \
    GLDS16(Bbase + (size_t)(H) * 128 * 1024 + 8 * 1024 + ((KT) & 15) * 64, &Bl[(KT) & 1][H][w * 16 + 8][0]); }

#define LOAD_A(AFR, KP, MH) { \
    const char* ab = (const char*)&Al[KP][wm][0][0]; \
    _Pragma("unroll") \
    for (int fi = 0; fi < 4; fi++) \
    _Pragma("unroll") \
    for (int ks = 0; ks < 2; ks++) \
        AFR[fi][ks] = *reinterpret_cast<const short8*>( \
            ab + ((MH) * 64 + fi * 16 + lo) * 128 + (((ks * 4 + hi) ^ (lo & 7)) << 4)); }
#define LOAD_B(BFR, KP, NH) { \
    const char* bb = (const char*)&Bl[KP][bh][0][0]; \
    _Pragma("unroll") \
    for (int fj = 0; fj < 2; fj++) \
    _Pragma("unroll") \
    for (int ks = 0; ks < 2; ks++) \
        BFR[fj][ks] = *reinterpret_cast<const short8*>( \
            bb + ((wn & 1) * 64 + (NH) * 32 + fj * 16 + lo) * 128 + (((ks * 4 + hi) ^ (lo & 7)) << 4)); }

#define MFMA16(MH, NH, AFR, BFR) { \
    _Pragma("unroll") \
    for (int ks = 0; ks < 2; ks++) \
    _Pragma("unroll") \
    for (int fi = 0; fi < 4; fi++) \
    _Pragma("unroll") \
    for (int fj = 0; fj < 2; fj++) \
        acc[(MH) * 4 + fi][(NH) * 2 + fj] = __builtin_amdgcn_mfma_f32_16x16x32_bf16( \
            AFR[fi][ks], BFR[fj][ks], acc[(MH) * 4 + fi][(NH) * 2 + fj], 0, 0, 0); }

#define BAR __builtin_amdgcn_s_barrier()
#define LGKM0 asm volatile("s_waitcnt lgkmcnt(0)")
#define P1 __builtin_amdgcn_s_setprio(1)
#define P0 __builtin_amdgcn_s_setprio(0)

    // prologue: kt0 fully + kt1's B (12 GLDS/wave); drain kt0 (leave B1's 4)
    STG_A(0, 0); STG_A(0, 1); STG_B(0, 0); STG_B(0, 1);
    STG_B(1, 0); STG_B(1, 1);
    asm volatile("s_waitcnt vmcnt(4)");
    BAR;

    for (int i = 0; i < 8; i++) {
        const int kt = 2 * i;
        short8 AF[4][2], BA[2][2], BBf[2][2];
        // ---- ph0: kt quadrant (0,0); stage A(kt+1) both halves ----
        LOAD_A(AF, 0, 0); LOAD_B(BA, 0, 0);
        STG_A(kt + 1, 0); STG_A(kt + 1, 1);
        BAR; LGKM0; P1; MFMA16(0, 0, AF, BA); P0; BAR;
        // ---- ph1: quadrant (0,1) ----
        LOAD_B(BBf, 0, 1);
        BAR; LGKM0; P1; MFMA16(0, 1, AF, BBf); P0; BAR;
        // ---- ph2: quadrant (1,1); stage B(kt+2) both halves ----
        LOAD_A(AF, 0, 1);
        STG_B(kt + 2, 0); STG_B(kt + 2, 1);
        BAR; LGKM0; P1; MFMA16(1, 1, AF, BBf); P0; BAR;
        // ---- ph3: quadrant (1,0); stage A(kt+2,0); vmcnt(6) -> kt+1 ready ----
        STG_A(kt + 2, 0);
        BAR; LGKM0; P1; MFMA16(1, 0, AF, BA); P0;
        asm volatile("s_waitcnt vmcnt(6)");
        BAR;
        // ---- ph4: kt+1 quadrant (0,0); stage A(kt+2,1) ----
        LOAD_A(AF, 1, 0); LOAD_B(BA, 1, 0);
        STG_A(kt + 2, 1);
        BAR; LGKM0; P1; MFMA16(0, 0, AF, BA); P0; BAR;
        // ---- ph5: quadrant (0,1) ----
        LOAD_B(BBf, 1, 1);
        BAR; LGKM0; P1; MFMA16(0, 1, AF, BBf); P0; BAR;
        // ---- ph6: quadrant (1,1); stage B(kt+3) both halves ----
        LOAD_A(AF, 1, 1);
        STG_B(kt + 3, 0); STG_B(kt + 3, 1);
        BAR; LGKM0; P1; MFMA16(1, 1, AF, BBf); P0; BAR;
        // ---- ph7: quadrant (1,0); vmcnt(4) -> kt+2 ready ----
        BAR; LGKM0; P1; MFMA16(1, 0, AF, BA); P0;
        asm volatile("s_waitcnt vmcnt(4)");
        BAR;
    }

    // ---- epilogue: Q|K -> qkv2 bf16 (Q scaled); V -> transposed Vout ----
#pragma unroll
    for (int i = 0; i < 8; i++)
#pragma unroll
        for (int j = 0; j < 4; j++) {
            const int col = tn + wn * 64 + j * 16 + lo;
            const int row0 = tm + wm * 128 + i * 16 + hi * 4;
            if (col < 2 * DD) {
                float s = (col < DD) ? scale : 1.0f;
#pragma unroll
                for (int r = 0; r < 4; r++)
                    qkv2[(size_t)(row0 + r) * QKW + col] = f2bf(acc[i][j][r] * s);
            } else {
                unsigned short pk[4];
#pragma unroll
                for (int r = 0; r < 4; r++) pk[r] = f2bf(acc[i][j][r]);
                *reinterpret_cast<uint2*>(&Vout[(size_t)(col - 2 * DD) * MM + row0]) =
                    *reinterpret_cast<uint2*>(pk);
            }
        }
#undef STG_A
#undef STG_B
#undef LOAD_A
#undef LOAD_B
#undef MFMA16
#undef BAR
#undef LGKM0
#undef P1
#undef P0
}

// ---------------- GEMM (m97 structure) for the output projection ----------------
template<int MODE>
__global__ __launch_bounds__(256)
void gemm_kernel(const unsigned short* __restrict__ A,
                 const unsigned short* __restrict__ Bt,
                 void* __restrict__ Cout, unsigned short* __restrict__ Vout,
                 int M, int N, int K, float scale) {
    __shared__ unsigned short As[128][64];
    __shared__ unsigned short Bs[128][64];
    const int nbx = gridDim.x;
    const int id = blockIdx.y * nbx + blockIdx.x;
    const int cpx = (nbx * gridDim.y) >> 3;
    const int swz = (id & 7) * cpx + (id >> 3);
    const int tm = (swz / nbx) * 128, tn = (swz % nbx) * 128;
    const int t = threadIdx.x;
    const int w = t >> 6, lane = t & 63, lo = lane & 15, hi = lane >> 4;
    const int wr = w >> 1, wc = w & 1;

    f32x4 acc[4][4];
#pragma unroll
    for (int i = 0; i < 4; i++)
#pragma unroll
        for (int j = 0; j < 4; j++) acc[i][j] = (f32x4){0.f, 0.f, 0.f, 0.f};

    const int srow = w * 32 + (lane >> 3);
    const int scol = (lane & 7) * 8;
    const unsigned short* ga = &A[(size_t)(tm + srow) * K + scol];
    const unsigned short* gb = &Bt[(size_t)(tn + srow) * K + scol];

    for (int k0 = 0; k0 < K; k0 += 64) {
        __syncthreads();
#pragma unroll
        for (int i = 0; i < 4; i++) {
            GLDS16(ga + (size_t)(i * 8) * K + k0, &As[w * 32 + i * 8][0]);
            GLDS16(gb + (size_t)(i * 8) * K + k0, &Bs[w * 32 + i * 8][0]);
        }
        __syncthreads();

        short8 af[4][2], bf[4][2];
#pragma unroll
        for (int i = 0; i < 4; i++)
#pragma unroll
            for (int ks = 0; ks < 2; ks++) {
                af[i][ks] = *reinterpret_cast<const short8*>(&As[wr * 64 + i * 16 + lo][ks * 32 + hi * 8]);
                bf[i][ks] = *reinterpret_cast<const short8*>(&Bs[wc * 64 + i * 16 + lo][ks * 32 + hi * 8]);
            }
#pragma unroll
        for (int ks = 0; ks < 2; ks++)
#pragma unroll
            for (int i = 0; i < 4; i++)
#pragma unroll
                for (int j = 0; j < 4; j++)
                    acc[i][j] = __builtin_amdgcn_mfma_f32_16x16x32_bf16(af[i][ks], bf[j][ks], acc[i][j], 0, 0, 0);
    }
#pragma unroll
    for (int i = 0; i < 4; i++)
#pragma unroll
        for (int j = 0; j < 4; j++) {
            const int col = tn + wc * 64 + j * 16 + lo;
            const int row0 = tm + wr * 64 + i * 16 + hi * 4;
            if (MODE == 0) {
#pragma unroll
                for (int r = 0; r < 4; r++)
                    ((float*)Cout)[(size_t)(row0 + r) * N + col] = acc[i][j][r];
            } else {
                if (col < 2 * DD) {
                    float s = (col < DD) ? scale : 1.0f;
#pragma unroll
                    for (int r = 0; r < 4; r++)
                        ((unsigned short*)Cout)[(size_t)(row0 + r) * QKW + col] = f2bf(acc[i][j][r] * s);
                } else {
                    unsigned short pk[4];
#pragma unroll
                    for (int r = 0; r < 4; r++) pk[r] = f2bf(acc[i][j][r]);
                    *reinterpret_cast<uint2*>(&Vout[(size_t)(col - 2 * DD) * MM + row0]) =
                        *reinterpret_cast<uint2*>(pk);
                }
            }
        }
}

// ---------------- Flash attention: shift-free softmax, MFMA row-sum, GLDS K&V ----------------
// grid (H, 16 pairs, B), 256 threads = 4 waves.
// Pair p: light q-tile qcl=p, heavy q-tile qch=31-p. L=p+1, Hn=32-p.
__global__ __launch_bounds__(256)
void attn_kernel(const unsigned short* __restrict__ qkv2,   // [B*T][2048] Q|K bf16
                 const unsigned short* __restrict__ vtg,    // [1024][B*T]  V^T bf16
                 unsigned short* __restrict__ outp) {
    __shared__ unsigned short Ks[2][64][64];   // K[kv][dh], XOR-swizzled rows
    __shared__ unsigned short Vt[2][64][64];   // V^T[dh][kv], XOR-swizzled rows

    const int b = blockIdx.z, h = blockIdx.x, p = blockIdx.y;
    const int qcl = p, qch = 31 - p;
    const int L = p + 1, Hn = 32 - p;
    const int t = threadIdx.x;
    const int w = t >> 6, l = t & 63, ql = l & 31, hi8 = l >> 5;
    const int pr = w >> 1, rg = w & 1;
    const int q0h = qch * 64 + rg * 32;
    const int q0p = (pr ? qcl : qch) * 64 + rg * 32;
    const unsigned short* base2 = qkv2 + (size_t)b * TT * QKW;

    short8 bq[4];
#pragma unroll
    for (int ks = 0; ks < 4; ks++)
        bq[ks] = *reinterpret_cast<const short8*>(
            &base2[(size_t)(q0p + ql) * QKW + h * 64 + ks * 16 + hi8 * 8]);

    f32x16 o0 = ZERO16, o1 = ZERO16, lD = ZERO16;

    short8 ones1;
#pragma unroll
    for (int j = 0; j < 8; j++) ones1[j] = (short)0x3F80;

    const int krow = l >> 3;
    const int kc8 = (l & 7) ^ krow;
    const unsigned short* gk = &base2[(size_t)(w * 8 + krow) * QKW + DD + h * 64 + kc8 * 8];
    const unsigned short* gv = &vtg[(size_t)(h * 64 + w * 8 + krow) * MM + b * TT + kc8 * 8];

#define STAGE(KVB, BUF) { \
    GLDS16(gk + (size_t)(KVB) * QKW, &Ks[BUF][w * 8][0]); \
    GLDS16(gk + (size_t)((KVB) + 32) * QKW, &Ks[BUF][32 + w * 8][0]); \
    GLDS16(gv + (KVB), &Vt[BUF][w * 8][0]); \
    GLDS16(gv + (size_t)32 * MM + (KVB), &Vt[BUF][32 + w * 8][0]); }

#define WRITE_OUT(Q0) { \
    _Pragma("unroll") \
    for (int r = 0; r < 16; r++) { \
        int src = (r & 3) + 8 * (r >> 2) + 4 * hi8; \
        float inv = 1.0f / lD[r]; \
        size_t off = (size_t)(b * TT + (Q0) + src) * DD + h * 64 + ql; \
        outp[off] = f2bf(o0[r] * inv); \
        outp[off + 32] = f2bf(o1[r] * inv); \
    } }

    STAGE(0, 0);
    __syncthreads();

    const int sw4 = (ql & 7) << 4;
    int it = 0;
    for (int kvt = 0; kvt < Hn; kvt++, it ^= 1) {
        const bool more = (kvt + 1) < Hn;
        if (more) STAGE((kvt + 1) * 64, it ^ 1);

        if (kvt == L && pr == 1) {
            WRITE_OUT(qcl * 64 + rg * 32);
            o0 = ZERO16; o1 = ZERO16; lD = ZERO16;
#pragma unroll
            for (int ks = 0; ks < 4; ks++)
                bq[ks] = *reinterpret_cast<const short8*>(
                    &base2[(size_t)(q0h + ql) * QKW + h * 64 + ks * 16 + hi8 * 8]);
        }

        const char* kbase = (const char*)&Ks[it][0][0];
        const char* vbase = (const char*)&Vt[it][0][0];
        const int kvb = kvt * 64;

        if (kvt < L) {
            short8 ak0[4], ak1[4];
#pragma unroll
            for (int ks = 0; ks < 4; ks++) {
                ak0[ks] = *reinterpret_cast<const short8*>(kbase + ql * 128 + (((ks * 2 + hi8) << 4) ^ sw4));
                ak1[ks] = *reinterpret_cast<const short8*>(kbase + (32 + ql) * 128 + (((ks * 2 + hi8) << 4) ^ sw4));
            }
            f32x16 sa0 = ZERO16, sa1 = ZERO16;
#pragma unroll
            for (int ks = 0; ks < 4; ks++) {
                sa0 = __builtin_amdgcn_mfma_f32_32x32x16_bf16(ak0[ks], bq[ks], sa0, 0, 0, 0);
                sa1 = __builtin_amdgcn_mfma_f32_32x32x16_bf16(ak1[ks], bq[ks], sa1, 0, 0, 0);
            }
            if (pr == 1 && kvt == L - 1) {
                const int qg = q0p + ql;
#pragma unroll
                for (int r = 0; r < 16; r++) {
                    int crow = (r & 3) + 8 * (r >> 2) + 4 * hi8;
                    if (kvb + crow > qg) sa0[r] = -1e30f;
                    if (kvb + 32 + crow > qg) sa1[r] = -1e30f;
                }
            }
#pragma unroll
            for (int r = 0; r < 16; r++) sa0[r] = exp2f(sa0[r]);
#pragma unroll
            for (int r = 0; r < 16; r++) sa1[r] = exp2f(sa1[r]);

            unsigned a01 = cvt_pk_bf16(sa0[0], sa0[1]),  a23 = cvt_pk_bf16(sa0[2], sa0[3]);
            unsigned a45 = cvt_pk_bf16(sa0[4], sa0[5]),  a67 = cvt_pk_bf16(sa0[6], sa0[7]);
            asm("v_permlane32_swap_b32 %0, %1" : "+v"(a01), "+v"(a45));
            asm("v_permlane32_swap_b32 %0, %1" : "+v"(a23), "+v"(a67));
            unsigned b01 = cvt_pk_bf16(sa0[8], sa0[9]),  b23 = cvt_pk_bf16(sa0[10], sa0[11]);
            unsigned b45 = cvt_pk_bf16(sa0[12], sa0[13]), b67 = cvt_pk_bf16(sa0[14], sa0[15]);
            asm("v_permlane32_swap_b32 %0, %1" : "+v"(b01), "+v"(b45));
            asm("v_permlane32_swap_b32 %0, %1" : "+v"(b23), "+v"(b67));
            unsigned c01 = cvt_pk_bf16(sa1[0], sa1[1]),  c23 = cvt_pk_bf16(sa1[2], sa1[3]);
            unsigned c45 = cvt_pk_bf16(sa1[4], sa1[5]),  c67 = cvt_pk_bf16(sa1[6], sa1[7]);
            asm("v_permlane32_swap_b32 %0, %1" : "+v"(c01), "+v"(c45));
            asm("v_permlane32_swap_b32 %0, %1" : "+v"(c23), "+v"(c67));
            unsigned d01 = cvt_pk_bf16(sa1[8], sa1[9]),  d23 = cvt_pk_bf16(sa1[10], sa1[11]);
            unsigned d45 = cvt_pk_bf16(sa1[12], sa1[13]), d67 = cvt_pk_bf16(sa1[14], sa1[15]);
            asm("v_permlane32_swap_b32 %0, %1" : "+v"(d01), "+v"(d45));
            asm("v_permlane32_swap_b32 %0, %1" : "+v"(d23), "+v"(d67));
            union { unsigned u[4]; short8 s; } f0s0, f1s0, f0s1, f1s1;
            f0s0.u[0] = a01; f0s0.u[1] = a23; f0s0.u[2] = a45; f0s0.u[3] = a67;
            f1s0.u[0] = b01; f1s0.u[1] = b23; f1s0.u[2] = b45; f1s0.u[3] = b67;
            f0s1.u[0] = c01; f0s1.u[1] = c23; f0s1.u[2] = c45; f0s1.u[3] = c67;
            f1s1.u[0] = d01; f1s1.u[1] = d23; f1s1.u[2] = d45; f1s1.u[3] = d67;

            lD = __builtin_amdgcn_mfma_f32_32x32x16_bf16(f0s0.s, ones1, lD, 0, 0, 0);
            lD = __builtin_amdgcn_mfma_f32_32x32x16_bf16(f1s0.s, ones1, lD, 0, 0, 0);
            lD = __builtin_amdgcn_mfma_f32_32x32x16_bf16(f0s1.s, ones1, lD, 0, 0, 0);
            lD = __builtin_amdgcn_mfma_f32_32x32x16_bf16(f1s1.s, ones1, lD, 0, 0, 0);

            short8 bv00 = *reinterpret_cast<const short8*>(vbase + ql * 128 + (((0 + hi8) << 4) ^ sw4));
            short8 bv01 = *reinterpret_cast<const short8*>(vbase + ql * 128 + (((2 + hi8) << 4) ^ sw4));
            short8 bv02 = *reinterpret_cast<const short8*>(vbase + ql * 128 + (((4 + hi8) << 4) ^ sw4));
            short8 bv03 = *reinterpret_cast<const short8*>(vbase + ql * 128 + (((6 + hi8) << 4) ^ sw4));
            short8 bv10 = *reinterpret_cast<const short8*>(vbase + (32 + ql) * 128 + (((0 + hi8) << 4) ^ sw4));
            short8 bv11 = *reinterpret_cast<const short8*>(vbase + (32 + ql) * 128 + (((2 + hi8) << 4) ^ sw4));
            short8 bv12 = *reinterpret_cast<const short8*>(vbase + (32 + ql) * 128 + (((4 + hi8) << 4) ^ sw4));
            short8 bv13 = *reinterpret_cast<const short8*>(vbase + (32 + ql) * 128 + (((6 + hi8) << 4) ^ sw4));
            o0 = __builtin_amdgcn_mfma_f32_32x32x16_bf16(f0s0.s, bv00, o0, 0, 0, 0);
            o1 = __builtin_amdgcn_mfma_f32_32x32x16_bf16(f0s0.s, bv10, o1, 0, 0, 0);
            o0 = __builtin_amdgcn_mfma_f32_32x32x16_bf16(f1s0.s, bv01, o0, 0, 0, 0);
            o1 = __builtin_amdgcn_mfma_f32_32x32x16_bf16(f1s0.s, bv11, o1, 0, 0, 0);
            o0 = __builtin_amdgcn_mfma_f32_32x32x16_bf16(f0s1.s, bv02, o0, 0, 0, 0);
            o1 = __builtin_amdgcn_mfma_f32_32x32x16_bf16(f0s1.s, bv12, o1, 0, 0, 0);
            o0 = __builtin_amdgcn_mfma_f32_32x32x16_bf16(f1s1.s, bv03, o0, 0, 0, 0);
            o1 = __builtin_amdgcn_mfma_f32_32x32x16_bf16(f1s1.s, bv13, o1, 0, 0, 0);
        } else {
            const int sub = pr;
            short8 ak[4];
#pragma unroll
            for (int ks = 0; ks < 4; ks++)
                ak[ks] = *reinterpret_cast<const short8*>(
                    kbase + (sub * 32 + ql) * 128 + (((ks * 2 + hi8) << 4) ^ sw4));
            f32x16 sa = ZERO16;
#pragma unroll
            for (int ks = 0; ks < 4; ks++)
                sa = __builtin_amdgcn_mfma_f32_32x32x16_bf16(ak[ks], bq[ks], sa, 0, 0, 0);

            if (kvt == Hn - 1) {
                const int qg = q0h + ql;
#pragma unroll
                for (int r = 0; r < 16; r++) {
                    int crow = (r & 3) + 8 * (r >> 2) + 4 * hi8;
                    if (kvb + sub * 32 + crow > qg) sa[r] = -1e30f;
                }
            }
#pragma unroll
            for (int r = 0; r < 16; r++) sa[r] = exp2f(sa[r]);

            unsigned a01 = cvt_pk_bf16(sa[0], sa[1]),  a23 = cvt_pk_bf16(sa[2], sa[3]);
            unsigned a45 = cvt_pk_bf16(sa[4], sa[5]),  a67 = cvt_pk_bf16(sa[6], sa[7]);
            asm("v_permlane32_swap_b32 %0, %1" : "+v"(a01), "+v"(a45));
            asm("v_permlane32_swap_b32 %0, %1" : "+v"(a23), "+v"(a67));
            unsigned b01 = cvt_pk_bf16(sa[8], sa[9]),  b23 = cvt_pk_bf16(sa[10], sa[11]);
            unsigned b45 = cvt_pk_bf16(sa[12], sa[13]), b67 = cvt_pk_bf16(sa[14], sa[15]);
            asm("v_permlane32_swap_b32 %0, %1" : "+v"(b01), "+v"(b45));
            asm("v_permlane32_swap_b32 %0, %1" : "+v"(b23), "+v"(b67));
            union { unsigned u[4]; short8 s; } f0, f1;
            f0.u[0] = a01; f0.u[1] = a23; f0.u[2] = a45; f0.u[3] = a67;
            f1.u[0] = b01; f1.u[1] = b23; f1.u[2] = b45; f1.u[3] = b67;

            lD = __builtin_amdgcn_mfma_f32_32x32x16_bf16(f0.s, ones1, lD, 0, 0, 0);
            lD = __builtin_amdgcn_mfma_f32_32x32x16_bf16(f1.s, ones1, lD, 0, 0, 0);

            short8 bv00 = *reinterpret_cast<const short8*>(vbase + ql * 128 + (((sub * 4 + 0 + hi8) << 4) ^ sw4));
            short8 bv01 = *reinterpret_cast<const short8*>(vbase + ql * 128 + (((sub * 4 + 2 + hi8) << 4) ^ sw4));
            short8 bv10 = *reinterpret_cast<const short8*>(vbase + (32 + ql) * 128 + (((sub * 4 + 0 + hi8) << 4) ^ sw4));
            short8 bv11 = *reinterpret_cast<const short8*>(vbase + (32 + ql) * 128 + (((sub * 4 + 2 + hi8) << 4) ^ sw4));
            o0 = __builtin_amdgcn_mfma_f32_32x32x16_bf16(f0.s, bv00, o0, 0, 0, 0);
            o1 = __builtin_amdgcn_mfma_f32_32x32x16_bf16(f0.s, bv10, o1, 0, 0, 0);
            o0 = __builtin_amdgcn_mfma_f32_32x32x16_bf16(f1.s, bv01, o0, 0, 0, 0);
            o1 = __builtin_amdgcn_mfma_f32_32x32x16_bf16(f1.s, bv11, o1, 0, 0, 0);
        }
        __syncthreads();
    }

    float* xf = (float*)&Ks[0][0][0];
    float* xl = (float*)&Vt[0][0][0];
    const int tid128 = (w & 1) * 64 + l;
    if (pr == 1) {
#pragma unroll
        for (int r = 0; r < 16; r++) {
            xf[r * 128 + tid128] = o0[r];
            xf[(16 + r) * 128 + tid128] = o1[r];
            xl[r * 128 + tid128] = lD[r];
        }
    }
    __syncthreads();
    if (pr == 0) {
#pragma unroll
        for (int r = 0; r < 16; r++) {
            o0[r] += xf[r * 128 + tid128];
            o1[r] += xf[(16 + r) * 128 + tid128];
            lD[r] += xl[r * 128 + tid128];
        }
        WRITE_OUT(q0h);
    }
#undef STAGE
#undef WRITE_OUT
}

extern "C" void kernel_launch(void* const* d_in, const int* in_sizes, int n_in,
                              void* d_out, int out_size, void* d_ws, size_t ws_size,
                              hipStream_t stream) {
    const float* x     = (const float*)d_in[0];   // [4096][1024]
    const float* Wqkv  = (const float*)d_in[1];   // [1024][3072]
    const float* Wproj = (const float*)d_in[2];   // [1024][1024]
    float* out = (float*)d_out;                    // [4096][1024] fp32

    unsigned short* xb     = (unsigned short*)d_ws;            // 4096*1024
    unsigned short* wqkvt  = xb + (size_t)MM * DD;             // 3072*1024
    unsigned short* wprojt = wqkvt + (size_t)N3 * DD;          // 1024*1024
    unsigned short* qkv2   = wprojt + (size_t)DD * DD;         // 4096*2048 (Q|K)
    unsigned short* vtg    = qkv2 + (size_t)MM * QKW;          // 1024*4096 (V^T)
    unsigned short* attout = vtg + (size_t)DD * MM;            // 4096*1024
    size_t need = ((size_t)MM * DD + (size_t)N3 * DD + (size_t)DD * DD +
                   (size_t)MM * QKW + (size_t)DD * MM + (size_t)MM * DD) * 2;
    if (ws_size < need) return;

    const float sc = 0.125f * 1.44269504088896f;   // 1/sqrt(64) * log2(e), folded into Q

    cast_bf16_kernel<<<1024, 256, 0, stream>>>(x, xb, MM * DD / 8);
    transpose_cast_kernel<<<dim3(N3 / 32, DD / 32), dim3(32, 8), 0, stream>>>(Wqkv, wqkvt, DD, N3);
    transpose_cast_kernel<<<dim3(DD / 32, DD / 32), dim3(32, 8), 0, stream>>>(Wproj, wprojt, DD, DD);

    gemm256_qkv<<<dim3(12, 16), 512, 0, stream>>>(xb, wqkvt, qkv2, vtg, sc);

    attn_kernel<<<dim3(HH, 16, BB), 256, 0, stream>>>(qkv2, vtg, attout);

    gemm_kernel<0><<<dim3(DD / 128, MM / 128), 256, 0, stream>>>(attout, wprojt, out, nullptr, MM, DD, DD, 1.0f);
}

// Round 9
// 120.161 us; speedup vs baseline: 1.5648x; 1.1237x over previous
//
#include <hip/hip_runtime.h>
#include <hip/hip_bf16.h>

// Problem: B=2, T=2048, D=1024, H=16, DH=64
#define BB 2
#define TT 2048
#define DD 1024
#define HH 16
#define MM (BB*TT)        // 4096
#define N3 (3*DD)         // 3072
#define QKW 2048          // qkv2 row width (Q|K only)

typedef __attribute__((ext_vector_type(8))) short short8;
typedef __attribute__((ext_vector_type(4))) float f32x4;
typedef __attribute__((ext_vector_type(16))) float f32x16;

#define ZERO16 (f32x16){0,0,0,0,0,0,0,0,0,0,0,0,0,0,0,0}

#define GLDS16(g, l) __builtin_amdgcn_global_load_lds( \
    (const __attribute__((address_space(1))) void*)(g), \
    (__attribute__((address_space(3))) void*)(l), 16, 0, 0)

__device__ __forceinline__ unsigned short f2bf(float f) {
    union { float f; unsigned u; } v; v.f = f;
    unsigned r = v.u + 0x7FFFu + ((v.u >> 16) & 1u);
    return (unsigned short)(r >> 16);
}

__device__ __forceinline__ unsigned cvt_pk_bf16(float lo, float hi) {
    unsigned r;
    asm("v_cvt_pk_bf16_f32 %0, %1, %2" : "=v"(r) : "v"(lo), "v"(hi));
    return r;
}

// raw HW transcendentals (exp2f/div compile to multi-op OCML sequences without fast-math)
__device__ __forceinline__ float fast_exp2(float x) {
    float r;
    asm("v_exp_f32 %0, %1" : "=v"(r) : "v"(x));
    return r;
}
__device__ __forceinline__ float fast_rcp(float x) {
    float r;
    asm("v_rcp_f32 %0, %1" : "=v"(r) : "v"(x));
    return r;
}

// ---------------- merged prep: Wqkv^T + Wproj^T + cast(x), one launch ----------------
// grid 5120 blocks, block (32,8):
//   [0,3072)    : Wqkv [1024][3072] -> wqkvt [3072][1024] bf16
//   [3072,4096) : Wproj [1024][1024] -> wprojt [1024][1024] bf16
//   [4096,5120) : cast x (4096*1024 f32) -> xb bf16
__global__ void prep_kernel(const float* __restrict__ x,
                            const float* __restrict__ Wqkv,
                            const float* __restrict__ Wproj,
                            unsigned short* __restrict__ xb,
                            unsigned short* __restrict__ wqkvt,
                            unsigned short* __restrict__ wprojt) {
    __shared__ float tile[32][33];
    const int bid = blockIdx.x;
    const int tx = threadIdx.x, ty = threadIdx.y;
    if (bid < 4096) {
        const float* src;
        unsigned short* dst;
        int rows, cols, c0, r0;
        if (bid < 3072) {
            src = Wqkv; dst = wqkvt; rows = DD; cols = N3;
            c0 = (bid % 96) * 32; r0 = (bid / 96) * 32;
        } else {
            src = Wproj; dst = wprojt; rows = DD; cols = DD;
            int b2 = bid - 3072;
            c0 = (b2 & 31) * 32; r0 = (b2 >> 5) * 32;
        }
#pragma unroll
        for (int i = 0; i < 4; i++) {
            int r = ty + i * 8;
            tile[r][tx] = src[(size_t)(r0 + r) * cols + c0 + tx];
        }
        __syncthreads();
#pragma unroll
        for (int i = 0; i < 4; i++) {
            int r = ty + i * 8;
            dst[(size_t)(c0 + r) * rows + r0 + tx] = f2bf(tile[tx][r]);
        }
    } else {
        const int t = ty * 32 + tx;
        int i = (bid - 4096) * 256 + t;                 // 0..262143
        const int n8 = MM * DD / 8;                     // 524288
#pragma unroll
        for (int k = 0; k < 2; k++, i += 262144) {
            const float4* s = reinterpret_cast<const float4*>(x) + (size_t)i * 2;
            float4 a = s[0], b = s[1];
            unsigned short r[8] = {f2bf(a.x), f2bf(a.y), f2bf(a.z), f2bf(a.w),
                                   f2bf(b.x), f2bf(b.y), f2bf(b.z), f2bf(b.w)};
            *reinterpret_cast<uint4*>(xb + (size_t)i * 8) = *reinterpret_cast<uint4*>(r);
            (void)n8;
        }
    }
}

// ================= 256x256 8-phase GEMM for QKV (M=4096, N=3072, K=1024) =================
__global__ __launch_bounds__(512, 2)
void gemm256_qkv(const unsigned short* __restrict__ A,
                 const unsigned short* __restrict__ Bt,
                 unsigned short* __restrict__ qkv2,
                 unsigned short* __restrict__ Vout,
                 float scale) {
    __shared__ unsigned short Al[2][2][128][64];
    __shared__ unsigned short Bl[2][2][128][64];

    const int id = blockIdx.y * 12 + blockIdx.x;          // nwg = 192, %8 == 0
    const int swzid = (id & 7) * 24 + (id >> 3);
    const int tm = (swzid / 12) * 256, tn = (swzid % 12) * 256;
    const int t = threadIdx.x, w = t >> 6, l = t & 63;
    const int wm = w >> 2, wn = w & 3, bh = wn >> 1;
    const int lo = l & 15, hi = l >> 4;
    const int srow = l >> 3;
    const int sg = (l & 7) ^ srow;

    f32x4 acc[8][4];
#pragma unroll
    for (int i = 0; i < 8; i++)
#pragma unroll
        for (int j = 0; j < 4; j++) acc[i][j] = (f32x4){0.f, 0.f, 0.f, 0.f};

    const unsigned short* Abase = A + (size_t)(tm + w * 16 + srow) * 1024 + sg * 8;
    const unsigned short* Bbase = Bt + (size_t)(tn + w * 16 + srow) * 1024 + sg * 8;

#define STG_A(KT, H) { \
    GLDS16(Abase + (size_t)(H) * 128 * 1024 + ((KT) & 15) * 64, &Al[(KT) & 1][H][w * 16][0]); \
    GLDS16(Abase + (size_t)(H) * 128 * 1024 + 8 * 1024 + ((KT) & 15) * 64, &Al[(KT) & 1][H][w * 16 + 8][0]); }
#define STG_B(KT, H) { \
    GLDS16(Bbase + (size_t)(H) * 128 * 1024 + ((KT) & 15) * 64, &Bl[(KT) & 1][H][w * 16][0]); \
    GLDS16(Bbase + (size_t)(H) * 128 * 1024 + 8 * 1024 + ((KT) & 15) * 64, &Bl[(KT) & 1][H][w * 16 + 8][0]); }

#define LOAD_A(AFR, KP, MH) { \
    const char* ab = (const char*)&Al[KP][wm][0][0]; \
    _Pragma("unroll") \
    for (int fi = 0; fi < 4; fi++) \
    _Pragma("unroll") \
    for (int ks = 0; ks < 2; ks++) \
        AFR[fi][ks] = *reinterpret_cast<const short8*>( \
            ab + ((MH) * 64 + fi * 16 + lo) * 128 + (((ks * 4 + hi) ^ (lo & 7)) << 4)); }
#define LOAD_B(BFR, KP, NH) { \
    const char* bb = (const char*)&Bl[KP][bh][0][0]; \
    _Pragma("unroll") \
    for (int fj = 0; fj < 2; fj++) \
    _Pragma("unroll") \
    for (int ks = 0; ks < 2; ks++) \
        BFR[fj][ks] = *reinterpret_cast<const short8*>( \
            bb + ((wn & 1) * 64 + (NH) * 32 + fj * 16 + lo) * 128 + (((ks * 4 + hi) ^ (lo & 7)) << 4)); }

#define MFMA16(MH, NH, AFR, BFR) { \
    _Pragma("unroll") \
    for (int ks = 0; ks < 2; ks++) \
    _Pragma("unroll") \
    for (int fi = 0; fi < 4; fi++) \
    _Pragma("unroll") \
    for (int fj = 0; fj < 2; fj++) \
        acc[(MH) * 4 + fi][(NH) * 2 + fj] = __builtin_amdgcn_mfma_f32_16x16x32_bf16( \
            AFR[fi][ks], BFR[fj][ks], acc[(MH) * 4 + fi][(NH) * 2 + fj], 0, 0, 0); }

#define BAR __builtin_amdgcn_s_barrier()
#define LGKM0 asm volatile("s_waitcnt lgkmcnt(0)")
#define P1 __builtin_amdgcn_s_setprio(1)
#define P0 __builtin_amdgcn_s_setprio(0)

    STG_A(0, 0); STG_A(0, 1); STG_B(0, 0); STG_B(0, 1);
    STG_B(1, 0); STG_B(1, 1);
    asm volatile("s_waitcnt vmcnt(4)");
    BAR;

    for (int i = 0; i < 8; i++) {
        const int kt = 2 * i;
        short8 AF[4][2], BA[2][2], BBf[2][2];
        LOAD_A(AF, 0, 0); LOAD_B(BA, 0, 0);
        STG_A(kt + 1, 0); STG_A(kt + 1, 1);
        BAR; LGKM0; P1; MFMA16(0, 0, AF, BA); P0; BAR;
        LOAD_B(BBf, 0, 1);
        BAR; LGKM0; P1; MFMA16(0, 1, AF, BBf); P0; BAR;
        LOAD_A(AF, 0, 1);
        STG_B(kt + 2, 0); STG_B(kt + 2, 1);
        BAR; LGKM0; P1; MFMA16(1, 1, AF, BBf); P0; BAR;
        STG_A(kt + 2, 0);
        BAR; LGKM0; P1; MFMA16(1, 0, AF, BA); P0;
        asm volatile("s_waitcnt vmcnt(6)");
        BAR;
        LOAD_A(AF, 1, 0); LOAD_B(BA, 1, 0);
        STG_A(kt + 2, 1);
        BAR; LGKM0; P1; MFMA16(0, 0, AF, BA); P0; BAR;
        LOAD_B(BBf, 1, 1);
        BAR; LGKM0; P1; MFMA16(0, 1, AF, BBf); P0; BAR;
        LOAD_A(AF, 1, 1);
        STG_B(kt + 3, 0); STG_B(kt + 3, 1);
        BAR; LGKM0; P1; MFMA16(1, 1, AF, BBf); P0; BAR;
        BAR; LGKM0; P1; MFMA16(1, 0, AF, BA); P0;
        asm volatile("s_waitcnt vmcnt(4)");
        BAR;
    }

#pragma unroll
    for (int i = 0; i < 8; i++)
#pragma unroll
        for (int j = 0; j < 4; j++) {
            const int col = tn + wn * 64 + j * 16 + lo;
            const int row0 = tm + wm * 128 + i * 16 + hi * 4;
            if (col < 2 * DD) {
                float s = (col < DD) ? scale : 1.0f;
#pragma unroll
                for (int r = 0; r < 4; r++)
                    qkv2[(size_t)(row0 + r) * QKW + col] = f2bf(acc[i][j][r] * s);
            } else {
                unsigned short pk[4];
#pragma unroll
                for (int r = 0; r < 4; r++) pk[r] = f2bf(acc[i][j][r]);
                *reinterpret_cast<uint2*>(&Vout[(size_t)(col - 2 * DD) * MM + row0]) =
                    *reinterpret_cast<uint2*>(pk);
            }
        }
#undef STG_A
#undef STG_B
#undef LOAD_A
#undef LOAD_B
#undef MFMA16
#undef BAR
#undef LGKM0
#undef P1
#undef P0
}

// ---------------- GEMM (m97 structure) for the output projection ----------------
__global__ __launch_bounds__(256)
void gemm_kernel(const unsigned short* __restrict__ A,
                 const unsigned short* __restrict__ Bt,
                 float* __restrict__ Cout, int M, int N, int K) {
    __shared__ unsigned short As[128][64];
    __shared__ unsigned short Bs[128][64];
    const int nbx = gridDim.x;
    const int id = blockIdx.y * nbx + blockIdx.x;
    const int cpx = (nbx * gridDim.y) >> 3;
    const int swz = (id & 7) * cpx + (id >> 3);
    const int tm = (swz / nbx) * 128, tn = (swz % nbx) * 128;
    const int t = threadIdx.x;
    const int w = t >> 6, lane = t & 63, lo = lane & 15, hi = lane >> 4;
    const int wr = w >> 1, wc = w & 1;

    f32x4 acc[4][4];
#pragma unroll
    for (int i = 0; i < 4; i++)
#pragma unroll
        for (int j = 0; j < 4; j++) acc[i][j] = (f32x4){0.f, 0.f, 0.f, 0.f};

    const int srow = w * 32 + (lane >> 3);
    const int scol = (lane & 7) * 8;
    const unsigned short* ga = &A[(size_t)(tm + srow) * K + scol];
    const unsigned short* gb = &Bt[(size_t)(tn + srow) * K + scol];

    for (int k0 = 0; k0 < K; k0 += 64) {
        __syncthreads();
#pragma unroll
        for (int i = 0; i < 4; i++) {
            GLDS16(ga + (size_t)(i * 8) * K + k0, &As[w * 32 + i * 8][0]);
            GLDS16(gb + (size_t)(i * 8) * K + k0, &Bs[w * 32 + i * 8][0]);
        }
        __syncthreads();

        short8 af[4][2], bf[4][2];
#pragma unroll
        for (int i = 0; i < 4; i++)
#pragma unroll
            for (int ks = 0; ks < 2; ks++) {
                af[i][ks] = *reinterpret_cast<const short8*>(&As[wr * 64 + i * 16 + lo][ks * 32 + hi * 8]);
                bf[i][ks] = *reinterpret_cast<const short8*>(&Bs[wc * 64 + i * 16 + lo][ks * 32 + hi * 8]);
            }
#pragma unroll
        for (int ks = 0; ks < 2; ks++)
#pragma unroll
            for (int i = 0; i < 4; i++)
#pragma unroll
                for (int j = 0; j < 4; j++)
                    acc[i][j] = __builtin_amdgcn_mfma_f32_16x16x32_bf16(af[i][ks], bf[j][ks], acc[i][j], 0, 0, 0);
    }
#pragma unroll
    for (int i = 0; i < 4; i++)
#pragma unroll
        for (int j = 0; j < 4; j++) {
            const int col = tn + wc * 64 + j * 16 + lo;
            const int row0 = tm + wr * 64 + i * 16 + hi * 4;
#pragma unroll
            for (int r = 0; r < 4; r++)
                Cout[(size_t)(row0 + r) * N + col] = acc[i][j][r];
        }
}

// ---------------- Flash attention: shift-free softmax, MFMA row-sum, GLDS K&V ----------------
// grid (H, 16 pairs, B), 256 threads = 4 waves.
__global__ __launch_bounds__(256)
void attn_kernel(const unsigned short* __restrict__ qkv2,   // [B*T][2048] Q|K bf16
                 const unsigned short* __restrict__ vtg,    // [1024][B*T]  V^T bf16
                 unsigned short* __restrict__ outp) {
    __shared__ unsigned short Ks[2][64][64];
    __shared__ unsigned short Vt[2][64][64];

    const int b = blockIdx.z, h = blockIdx.x, p = blockIdx.y;
    const int qcl = p, qch = 31 - p;
    const int L = p + 1, Hn = 32 - p;
    const int t = threadIdx.x;
    const int w = t >> 6, l = t & 63, ql = l & 31, hi8 = l >> 5;
    const int pr = w >> 1, rg = w & 1;
    const int q0h = qch * 64 + rg * 32;
    const int q0p = (pr ? qcl : qch) * 64 + rg * 32;
    const unsigned short* base2 = qkv2 + (size_t)b * TT * QKW;

    short8 bq[4];
#pragma unroll
    for (int ks = 0; ks < 4; ks++)
        bq[ks] = *reinterpret_cast<const short8*>(
            &base2[(size_t)(q0p + ql) * QKW + h * 64 + ks * 16 + hi8 * 8]);

    f32x16 o0 = ZERO16, o1 = ZERO16, lD = ZERO16;

    short8 ones1;
#pragma unroll
    for (int j = 0; j < 8; j++) ones1[j] = (short)0x3F80;

    const int krow = l >> 3;
    const int kc8 = (l & 7) ^ krow;
    const unsigned short* gk = &base2[(size_t)(w * 8 + krow) * QKW + DD + h * 64 + kc8 * 8];
    const unsigned short* gv = &vtg[(size_t)(h * 64 + w * 8 + krow) * MM + b * TT + kc8 * 8];

#define STAGE(KVB, BUF) { \
    GLDS16(gk + (size_t)(KVB) * QKW, &Ks[BUF][w * 8][0]); \
    GLDS16(gk + (size_t)((KVB) + 32) * QKW, &Ks[BUF][32 + w * 8][0]); \
    GLDS16(gv + (KVB), &Vt[BUF][w * 8][0]); \
    GLDS16(gv + (size_t)32 * MM + (KVB), &Vt[BUF][32 + w * 8][0]); }

#define WRITE_OUT(Q0) { \
    _Pragma("unroll") \
    for (int r = 0; r < 16; r++) { \
        int src = (r & 3) + 8 * (r >> 2) + 4 * hi8; \
        float inv = fast_rcp(lD[r]); \
        size_t off = (size_t)(b * TT + (Q0) + src) * DD + h * 64 + ql; \
        outp[off] = f2bf(o0[r] * inv); \
        outp[off + 32] = f2bf(o1[r] * inv); \
    } }

    STAGE(0, 0);
    __syncthreads();

    const int sw4 = (ql & 7) << 4;
    int it = 0;
    for (int kvt = 0; kvt < Hn; kvt++, it ^= 1) {
        const bool more = (kvt + 1) < Hn;
        if (more) STAGE((kvt + 1) * 64, it ^ 1);

        if (kvt == L && pr == 1) {
            WRITE_OUT(qcl * 64 + rg * 32);
            o0 = ZERO16; o1 = ZERO16; lD = ZERO16;
#pragma unroll
            for (int ks = 0; ks < 4; ks++)
                bq[ks] = *reinterpret_cast<const short8*>(
                    &base2[(size_t)(q0h + ql) * QKW + h * 64 + ks * 16 + hi8 * 8]);
        }

        const char* kbase = (const char*)&Ks[it][0][0];
        const char* vbase = (const char*)&Vt[it][0][0];
        const int kvb = kvt * 64;

        if (kvt < L) {
            short8 ak0[4], ak1[4];
#pragma unroll
            for (int ks = 0; ks < 4; ks++) {
                ak0[ks] = *reinterpret_cast<const short8*>(kbase + ql * 128 + (((ks * 2 + hi8) << 4) ^ sw4));
                ak1[ks] = *reinterpret_cast<const short8*>(kbase + (32 + ql) * 128 + (((ks * 2 + hi8) << 4) ^ sw4));
            }
            f32x16 sa0 = ZERO16, sa1 = ZERO16;
#pragma unroll
            for (int ks = 0; ks < 4; ks++) {
                sa0 = __builtin_amdgcn_mfma_f32_32x32x16_bf16(ak0[ks], bq[ks], sa0, 0, 0, 0);
                sa1 = __builtin_amdgcn_mfma_f32_32x32x16_bf16(ak1[ks], bq[ks], sa1, 0, 0, 0);
            }
            if (pr == 1 && kvt == L - 1) {
                const int qg = q0p + ql;
#pragma unroll
                for (int r = 0; r < 16; r++) {
                    int crow = (r & 3) + 8 * (r >> 2) + 4 * hi8;
                    if (kvb + crow > qg) sa0[r] = -1e30f;
                    if (kvb + 32 + crow > qg) sa1[r] = -1e30f;
                }
            }
#pragma unroll
            for (int r = 0; r < 16; r++) sa0[r] = fast_exp2(sa0[r]);
#pragma unroll
            for (int r = 0; r < 16; r++) sa1[r] = fast_exp2(sa1[r]);

            unsigned a01 = cvt_pk_bf16(sa0[0], sa0[1]),  a23 = cvt_pk_bf16(sa0[2], sa0[3]);
            unsigned a45 = cvt_pk_bf16(sa0[4], sa0[5]),  a67 = cvt_pk_bf16(sa0[6], sa0[7]);
            asm("v_permlane32_swap_b32 %0, %1" : "+v"(a01), "+v"(a45));
            asm("v_permlane32_swap_b32 %0, %1" : "+v"(a23), "+v"(a67));
            unsigned b01 = cvt_pk_bf16(sa0[8], sa0[9]),  b23 = cvt_pk_bf16(sa0[10], sa0[11]);
            unsigned b45 = cvt_pk_bf16(sa0[12], sa0[13]), b67 = cvt_pk_bf16(sa0[14], sa0[15]);
            asm("v_permlane32_swap_b32 %0, %1" : "+v"(b01), "+v"(b45));
            asm("v_permlane32_swap_b32 %0, %1" : "+v"(b23), "+v"(b67));
            unsigned c01 = cvt_pk_bf16(sa1[0], sa1[1]),  c23 = cvt_pk_bf16(sa1[2], sa1[3]);
            unsigned c45 = cvt_pk_bf16(sa1[4], sa1[5]),  c67 = cvt_pk_bf16(sa1[6], sa1[7]);
            asm("v_permlane32_swap_b32 %0, %1" : "+v"(c01), "+v"(c45));
            asm("v_permlane32_swap_b32 %0, %1" : "+v"(c23), "+v"(c67));
            unsigned d01 = cvt_pk_bf16(sa1[8], sa1[9]),  d23 = cvt_pk_bf16(sa1[10], sa1[11]);
            unsigned d45 = cvt_pk_bf16(sa1[12], sa1[13]), d67 = cvt_pk_bf16(sa1[14], sa1[15]);
            asm("v_permlane32_swap_b32 %0, %1" : "+v"(d01), "+v"(d45));
            asm("v_permlane32_swap_b32 %0, %1" : "+v"(d23), "+v"(d67));
            union { unsigned u[4]; short8 s; } f0s0, f1s0, f0s1, f1s1;
            f0s0.u[0] = a01; f0s0.u[1] = a23; f0s0.u[2] = a45; f0s0.u[3] = a67;
            f1s0.u[0] = b01; f1s0.u[1] = b23; f1s0.u[2] = b45; f1s0.u[3] = b67;
            f0s1.u[0] = c01; f0s1.u[1] = c23; f0s1.u[2] = c45; f0s1.u[3] = c67;
            f1s1.u[0] = d01; f1s1.u[1] = d23; f1s1.u[2] = d45; f1s1.u[3] = d67;

            lD = __builtin_amdgcn_mfma_f32_32x32x16_bf16(f0s0.s, ones1, lD, 0, 0, 0);
            lD = __builtin_amdgcn_mfma_f32_32x32x16_bf16(f1s0.s, ones1, lD, 0, 0, 0);
            lD = __builtin_amdgcn_mfma_f32_32x32x16_bf16(f0s1.s, ones1, lD, 0, 0, 0);
            lD = __builtin_amdgcn_mfma_f32_32x32x16_bf16(f1s1.s, ones1, lD, 0, 0, 0);

            short8 bv00 = *reinterpret_cast<const short8*>(vbase + ql * 128 + (((0 + hi8) << 4) ^ sw4));
            short8 bv01 = *reinterpret_cast<const short8*>(vbase + ql * 128 + (((2 + hi8) << 4) ^ sw4));
            short8 bv02 = *reinterpret_cast<const short8*>(vbase + ql * 128 + (((4 + hi8) << 4) ^ sw4));
            short8 bv03 = *reinterpret_cast<const short8*>(vbase + ql * 128 + (((6 + hi8) << 4) ^ sw4));
            short8 bv10 = *reinterpret_cast<const short8*>(vbase + (32 + ql) * 128 + (((0 + hi8) << 4) ^ sw4));
            short8 bv11 = *reinterpret_cast<const short8*>(vbase + (32 + ql) * 128 + (((2 + hi8) << 4) ^ sw4));
            short8 bv12 = *reinterpret_cast<const short8*>(vbase + (32 + ql) * 128 + (((4 + hi8) << 4) ^ sw4));
            short8 bv13 = *reinterpret_cast<const short8*>(vbase + (32 + ql) * 128 + (((6 + hi8) << 4) ^ sw4));
            o0 = __builtin_amdgcn_mfma_f32_32x32x16_bf16(f0s0.s, bv00, o0, 0, 0, 0);
            o1 = __builtin_amdgcn_mfma_f32_32x32x16_bf16(f0s0.s, bv10, o1, 0, 0, 0);
            o0 = __builtin_amdgcn_mfma_f32_32x32x16_bf16(f1s0.s, bv01, o0, 0, 0, 0);
            o1 = __builtin_amdgcn_mfma_f32_32x32x16_bf16(f1s0.s, bv11, o1, 0, 0, 0);
            o0 = __builtin_amdgcn_mfma_f32_32x32x16_bf16(f0s1.s, bv02, o0, 0, 0, 0);
            o1 = __builtin_amdgcn_mfma_f32_32x32x16_bf16(f0s1.s, bv12, o1, 0, 0, 0);
            o0 = __builtin_amdgcn_mfma_f32_32x32x16_bf16(f1s1.s, bv03, o0, 0, 0, 0);
            o1 = __builtin_amdgcn_mfma_f32_32x32x16_bf16(f1s1.s, bv13, o1, 0, 0, 0);
        } else {
            const int sub = pr;
            short8 ak[4];
#pragma unroll
            for (int ks = 0; ks < 4; ks++)
                ak[ks] = *reinterpret_cast<const short8*>(
                    kbase + (sub * 32 + ql) * 128 + (((ks * 2 + hi8) << 4) ^ sw4));
            f32x16 sa = ZERO16;
#pragma unroll
            for (int ks = 0; ks < 4; ks++)
                sa = __builtin_amdgcn_mfma_f32_32x32x16_bf16(ak[ks], bq[ks], sa, 0, 0, 0);

            if (kvt == Hn - 1) {
                const int qg = q0h + ql;
#pragma unroll
                for (int r = 0; r < 16; r++) {
                    int crow = (r & 3) + 8 * (r >> 2) + 4 * hi8;
                    if (kvb + sub * 32 + crow > qg) sa[r] = -1e30f;
                }
            }
#pragma unroll
            for (int r = 0; r < 16; r++) sa[r] = fast_exp2(sa[r]);

            unsigned a01 = cvt_pk_bf16(sa[0], sa[1]),  a23 = cvt_pk_bf16(sa[2], sa[3]);
            unsigned a45 = cvt_pk_bf16(sa[4], sa[5]),  a67 = cvt_pk_bf16(sa[6], sa[7]);
            asm("v_permlane32_swap_b32 %0, %1" : "+v"(a01), "+v"(a45));
            asm("v_permlane32_swap_b32 %0, %1" : "+v"(a23), "+v"(a67));
            unsigned b01 = cvt_pk_bf16(sa[8], sa[9]),  b23 = cvt_pk_bf16(sa[10], sa[11]);
            unsigned b45 = cvt_pk_bf16(sa[12], sa[13]), b67 = cvt_pk_bf16(sa[14], sa[15]);
            asm("v_permlane32_swap_b32 %0, %1" : "+v"(b01), "+v"(b45));
            asm("v_permlane32_swap_b32 %0, %1" : "+v"(b23), "+v"(b67));
            union { unsigned u[4]; short8 s; } f0, f1;
            f0.u[0] = a01; f0.u[1] = a23; f0.u[2] = a45; f0.u[3] = a67;
            f1.u[0] = b01; f1.u[1] = b23; f1.u[2] = b45; f1.u[3] = b67;

            lD = __builtin_amdgcn_mfma_f32_32x32x16_bf16(f0.s, ones1, lD, 0, 0, 0);
            lD = __builtin_amdgcn_mfma_f32_32x32x16_bf16(f1.s, ones1, lD, 0, 0, 0);

            short8 bv00 = *reinterpret_cast<const short8*>(vbase + ql * 128 + (((sub * 4 + 0 + hi8) << 4) ^ sw4));
            short8 bv01 = *reinterpret_cast<const short8*>(vbase + ql * 128 + (((sub * 4 + 2 + hi8) << 4) ^ sw4));
            short8 bv10 = *reinterpret_cast<const short8*>(vbase + (32 + ql) * 128 + (((sub * 4 + 0 + hi8) << 4) ^ sw4));
            short8 bv11 = *reinterpret_cast<const short8*>(vbase + (32 + ql) * 128 + (((sub * 4 + 2 + hi8) << 4) ^ sw4));
            o0 = __builtin_amdgcn_mfma_f32_32x32x16_bf16(f0.s, bv00, o0, 0, 0, 0);
            o1 = __builtin_amdgcn_mfma_f32_32x32x16_bf16(f0.s, bv10, o1, 0, 0, 0);
            o0 = __builtin_amdgcn_mfma_f32_32x32x16_bf16(f1.s, bv01, o0, 0, 0, 0);
            o1 = __builtin_amdgcn_mfma_f32_32x32x16_bf16(f1.s, bv11, o1, 0, 0, 0);
        }
        __syncthreads();
    }

    float* xf = (float*)&Ks[0][0][0];
    float* xl = (float*)&Vt[0][0][0];
    const int tid128 = (w & 1) * 64 + l;
    if (pr == 1) {
#pragma unroll
        for (int r = 0; r < 16; r++) {
            xf[r * 128 + tid128] = o0[r];
            xf[(16 + r) * 128 + tid128] = o1[r];
            xl[r * 128 + tid128] = lD[r];
        }
    }
    __syncthreads();
    if (pr == 0) {
#pragma unroll
        for (int r = 0; r < 16; r++) {
            o0[r] += xf[r * 128 + tid128];
            o1[r] += xf[(16 + r) * 128 + tid128];
            lD[r] += xl[r * 128 + tid128];
        }
        WRITE_OUT(q0h);
    }
#undef STAGE
#undef WRITE_OUT
}

extern "C" void kernel_launch(void* const* d_in, const int* in_sizes, int n_in,
                              void* d_out, int out_size, void* d_ws, size_t ws_size,
                              hipStream_t stream) {
    const float* x     = (const float*)d_in[0];   // [4096][1024]
    const float* Wqkv  = (const float*)d_in[1];   // [1024][3072]
    const float* Wproj = (const float*)d_in[2];   // [1024][1024]
    float* out = (float*)d_out;                    // [4096][1024] fp32

    unsigned short* xb     = (unsigned short*)d_ws;            // 4096*1024
    unsigned short* wqkvt  = xb + (size_t)MM * DD;             // 3072*1024
    unsigned short* wprojt = wqkvt + (size_t)N3 * DD;          // 1024*1024
    unsigned short* qkv2   = wprojt + (size_t)DD * DD;         // 4096*2048 (Q|K)
    unsigned short* vtg    = qkv2 + (size_t)MM * QKW;          // 1024*4096 (V^T)
    unsigned short* attout = vtg + (size_t)DD * MM;            // 4096*1024
    size_t need = ((size_t)MM * DD + (size_t)N3 * DD + (size_t)DD * DD +
                   (size_t)MM * QKW + (size_t)DD * MM + (size_t)MM * DD) * 2;
    if (ws_size < need) return;

    const float sc = 0.125f * 1.44269504088896f;   // 1/sqrt(64) * log2(e), folded into Q

    prep_kernel<<<5120, dim3(32, 8), 0, stream>>>(x, Wqkv, Wproj, xb, wqkvt, wprojt);

    gemm256_qkv<<<dim3(12, 16), 512, 0, stream>>>(xb, wqkvt, qkv2, vtg, sc);

    attn_kernel<<<dim3(HH, 16, BB), 256, 0, stream>>>(qkv2, vtg, attout);

    gemm_kernel<<<dim3(DD / 128, MM / 128), 256, 0, stream>>>(attout, wprojt, out, MM, DD, DD);
}

// Round 10
// 117.648 us; speedup vs baseline: 1.5983x; 1.0214x over previous
//
#include <hip/hip_runtime.h>
#include <hip/hip_bf16.h>

// Problem: B=2, T=2048, D=1024, H=16, DH=64
#define BB 2
#define TT 2048
#define DD 1024
#define HH 16
#define MM (BB*TT)        // 4096
#define N3 (3*DD)         // 3072
#define QKW 2048          // qkv2 row width (Q|K only)

typedef __attribute__((ext_vector_type(8))) short short8;
typedef __attribute__((ext_vector_type(4))) float f32x4;
typedef __attribute__((ext_vector_type(16))) float f32x16;

#define ZERO16 (f32x16){0,0,0,0,0,0,0,0,0,0,0,0,0,0,0,0}

#define GLDS16(g, l) __builtin_amdgcn_global_load_lds( \
    (const __attribute__((address_space(1))) void*)(g), \
    (__attribute__((address_space(3))) void*)(l), 16, 0, 0)

__device__ __forceinline__ unsigned short f2bf(float f) {
    union { float f; unsigned u; } v; v.f = f;
    unsigned r = v.u + 0x7FFFu + ((v.u >> 16) & 1u);
    return (unsigned short)(r >> 16);
}

__device__ __forceinline__ unsigned cvt_pk_bf16(float lo, float hi) {
    unsigned r;
    asm("v_cvt_pk_bf16_f32 %0, %1, %2" : "=v"(r) : "v"(lo), "v"(hi));
    return r;
}

// raw HW transcendentals (exp2f/div compile to multi-op OCML sequences without fast-math)
__device__ __forceinline__ float fast_exp2(float x) {
    float r;
    asm("v_exp_f32 %0, %1" : "=v"(r) : "v"(x));
    return r;
}
__device__ __forceinline__ float fast_rcp(float x) {
    float r;
    asm("v_rcp_f32 %0, %1" : "=v"(r) : "v"(x));
    return r;
}

// ---------------- merged prep: Wqkv^T + Wproj^T + cast(x), one launch ----------------
__global__ void prep_kernel(const float* __restrict__ x,
                            const float* __restrict__ Wqkv,
                            const float* __restrict__ Wproj,
                            unsigned short* __restrict__ xb,
                            unsigned short* __restrict__ wqkvt,
                            unsigned short* __restrict__ wprojt) {
    __shared__ float tile[32][33];
    const int bid = blockIdx.x;
    const int tx = threadIdx.x, ty = threadIdx.y;
    if (bid < 4096) {
        const float* src;
        unsigned short* dst;
        int rows, cols, c0, r0;
        if (bid < 3072) {
            src = Wqkv; dst = wqkvt; rows = DD; cols = N3;
            c0 = (bid % 96) * 32; r0 = (bid / 96) * 32;
        } else {
            src = Wproj; dst = wprojt; rows = DD; cols = DD;
            int b2 = bid - 3072;
            c0 = (b2 & 31) * 32; r0 = (b2 >> 5) * 32;
        }
#pragma unroll
        for (int i = 0; i < 4; i++) {
            int r = ty + i * 8;
            tile[r][tx] = src[(size_t)(r0 + r) * cols + c0 + tx];
        }
        __syncthreads();
#pragma unroll
        for (int i = 0; i < 4; i++) {
            int r = ty + i * 8;
            dst[(size_t)(c0 + r) * rows + r0 + tx] = f2bf(tile[tx][r]);
        }
    } else {
        const int t = ty * 32 + tx;
        int i = (bid - 4096) * 256 + t;
#pragma unroll
        for (int k = 0; k < 2; k++, i += 262144) {
            const float4* s = reinterpret_cast<const float4*>(x) + (size_t)i * 2;
            float4 a = s[0], b = s[1];
            unsigned short r[8] = {f2bf(a.x), f2bf(a.y), f2bf(a.z), f2bf(a.w),
                                   f2bf(b.x), f2bf(b.y), f2bf(b.z), f2bf(b.w)};
            *reinterpret_cast<uint4*>(xb + (size_t)i * 8) = *reinterpret_cast<uint4*>(r);
        }
    }
}

// ================= 256x256 8-phase GEMM for QKV (M=4096, N=3072, K=1024) =================
__global__ __launch_bounds__(512, 2)
void gemm256_qkv(const unsigned short* __restrict__ A,
                 const unsigned short* __restrict__ Bt,
                 unsigned short* __restrict__ qkv2,
                 unsigned short* __restrict__ Vout,
                 float scale) {
    __shared__ unsigned short Al[2][2][128][64];
    __shared__ unsigned short Bl[2][2][128][64];

    const int id = blockIdx.y * 12 + blockIdx.x;          // nwg = 192, %8 == 0
    const int swzid = (id & 7) * 24 + (id >> 3);
    const int tm = (swzid / 12) * 256, tn = (swzid % 12) * 256;
    const int t = threadIdx.x, w = t >> 6, l = t & 63;
    const int wm = w >> 2, wn = w & 3, bh = wn >> 1;
    const int lo = l & 15, hi = l >> 4;
    const int srow = l >> 3;
    const int sg = (l & 7) ^ srow;

    f32x4 acc[8][4];
#pragma unroll
    for (int i = 0; i < 8; i++)
#pragma unroll
        for (int j = 0; j < 4; j++) acc[i][j] = (f32x4){0.f, 0.f, 0.f, 0.f};

    const unsigned short* Abase = A + (size_t)(tm + w * 16 + srow) * 1024 + sg * 8;
    const unsigned short* Bbase = Bt + (size_t)(tn + w * 16 + srow) * 1024 + sg * 8;

#define STG_A(KT, H) { \
    GLDS16(Abase + (size_t)(H) * 128 * 1024 + ((KT) & 15) * 64, &Al[(KT) & 1][H][w * 16][0]); \
    GLDS16(Abase + (size_t)(H) * 128 * 1024 + 8 * 1024 + ((KT) & 15) * 64, &Al[(KT) & 1][H][w * 16 + 8][0]); }
#define STG_B(KT, H) { \
    GLDS16(Bbase + (size_t)(H) * 128 * 1024 + ((KT) & 15) * 64, &Bl[(KT) & 1][H][w * 16][0]); \
    GLDS16(Bbase + (size_t)(H) * 128 * 1024 + 8 * 1024 + ((KT) & 15) * 64, &Bl[(KT) & 1][H][w * 16 + 8][0]); }

#define LOAD_A(AFR, KP, MH) { \
    const char* ab = (const char*)&Al[KP][wm][0][0]; \
    _Pragma("unroll") \
    for (int fi = 0; fi < 4; fi++) \
    _Pragma("unroll") \
    for (int ks = 0; ks < 2; ks++) \
        AFR[fi][ks] = *reinterpret_cast<const short8*>( \
            ab + ((MH) * 64 + fi * 16 + lo) * 128 + (((ks * 4 + hi) ^ (lo & 7)) << 4)); }
#define LOAD_B(BFR, KP, NH) { \
    const char* bb = (const char*)&Bl[KP][bh][0][0]; \
    _Pragma("unroll") \
    for (int fj = 0; fj < 2; fj++) \
    _Pragma("unroll") \
    for (int ks = 0; ks < 2; ks++) \
        BFR[fj][ks] = *reinterpret_cast<const short8*>( \
            bb + ((wn & 1) * 64 + (NH) * 32 + fj * 16 + lo) * 128 + (((ks * 4 + hi) ^ (lo & 7)) << 4)); }

#define MFMA16(MH, NH, AFR, BFR) { \
    _Pragma("unroll") \
    for (int ks = 0; ks < 2; ks++) \
    _Pragma("unroll") \
    for (int fi = 0; fi < 4; fi++) \
    _Pragma("unroll") \
    for (int fj = 0; fj < 2; fj++) \
        acc[(MH) * 4 + fi][(NH) * 2 + fj] = __builtin_amdgcn_mfma_f32_16x16x32_bf16( \
            AFR[fi][ks], BFR[fj][ks], acc[(MH) * 4 + fi][(NH) * 2 + fj], 0, 0, 0); }

#define BAR __builtin_amdgcn_s_barrier()
#define LGKM0 asm volatile("s_waitcnt lgkmcnt(0)")
#define P1 __builtin_amdgcn_s_setprio(1)
#define P0 __builtin_amdgcn_s_setprio(0)

    STG_A(0, 0); STG_A(0, 1); STG_B(0, 0); STG_B(0, 1);
    STG_B(1, 0); STG_B(1, 1);
    asm volatile("s_waitcnt vmcnt(4)");
    BAR;

    for (int i = 0; i < 8; i++) {
        const int kt = 2 * i;
        short8 AF[4][2], BA[2][2], BBf[2][2];
        LOAD_A(AF, 0, 0); LOAD_B(BA, 0, 0);
        STG_A(kt + 1, 0); STG_A(kt + 1, 1);
        BAR; LGKM0; P1; MFMA16(0, 0, AF, BA); P0; BAR;
        LOAD_B(BBf, 0, 1);
        BAR; LGKM0; P1; MFMA16(0, 1, AF, BBf); P0; BAR;
        LOAD_A(AF, 0, 1);
        STG_B(kt + 2, 0); STG_B(kt + 2, 1);
        BAR; LGKM0; P1; MFMA16(1, 1, AF, BBf); P0; BAR;
        STG_A(kt + 2, 0);
        BAR; LGKM0; P1; MFMA16(1, 0, AF, BA); P0;
        asm volatile("s_waitcnt vmcnt(6)");
        BAR;
        LOAD_A(AF, 1, 0); LOAD_B(BA, 1, 0);
        STG_A(kt + 2, 1);
        BAR; LGKM0; P1; MFMA16(0, 0, AF, BA); P0; BAR;
        LOAD_B(BBf, 1, 1);
        BAR; LGKM0; P1; MFMA16(0, 1, AF, BBf); P0; BAR;
        LOAD_A(AF, 1, 1);
        STG_B(kt + 3, 0); STG_B(kt + 3, 1);
        BAR; LGKM0; P1; MFMA16(1, 1, AF, BBf); P0; BAR;
        BAR; LGKM0; P1; MFMA16(1, 0, AF, BA); P0;
        asm volatile("s_waitcnt vmcnt(4)");
        BAR;
    }

#pragma unroll
    for (int i = 0; i < 8; i++)
#pragma unroll
        for (int j = 0; j < 4; j++) {
            const int col = tn + wn * 64 + j * 16 + lo;
            const int row0 = tm + wm * 128 + i * 16 + hi * 4;
            if (col < 2 * DD) {
                float s = (col < DD) ? scale : 1.0f;
#pragma unroll
                for (int r = 0; r < 4; r++)
                    qkv2[(size_t)(row0 + r) * QKW + col] = f2bf(acc[i][j][r] * s);
            } else {
                unsigned short pk[4];
#pragma unroll
                for (int r = 0; r < 4; r++) pk[r] = f2bf(acc[i][j][r]);
                *reinterpret_cast<uint2*>(&Vout[(size_t)(col - 2 * DD) * MM + row0]) =
                    *reinterpret_cast<uint2*>(pk);
            }
        }
#undef STG_A
#undef STG_B
#undef LOAD_A
#undef LOAD_B
#undef MFMA16
#undef BAR
#undef LGKM0
#undef P1
#undef P0
}

// ---------------- output projection GEMM: 128x64 tiles -> 512 blocks (2/CU, 8 waves/CU) ----------------
// M=4096, N=1024, K=1024
__global__ __launch_bounds__(256)
void gemm_proj(const unsigned short* __restrict__ A,
               const unsigned short* __restrict__ Bt,
               float* __restrict__ Cout) {
    __shared__ unsigned short As[128][64];
    __shared__ unsigned short Bs[64][64];
    const int nbx = 16;                          // N/64
    const int id = blockIdx.y * nbx + blockIdx.x;  // 512 blocks, %8==0
    const int cpx = 512 >> 3;
    const int swz = (id & 7) * cpx + (id >> 3);
    const int tm = (swz / nbx) * 128, tn = (swz % nbx) * 64;
    const int t = threadIdx.x;
    const int w = t >> 6, lane = t & 63, lo = lane & 15, hi = lane >> 4;
    const int wr = w >> 1, wc = w & 1;

    f32x4 acc[4][2];
#pragma unroll
    for (int i = 0; i < 4; i++)
#pragma unroll
        for (int j = 0; j < 2; j++) acc[i][j] = (f32x4){0.f, 0.f, 0.f, 0.f};

    const int sr8 = lane >> 3;
    const int scol = (lane & 7) * 8;
    const unsigned short* ga = &A[(size_t)(tm + w * 32 + sr8) * 1024 + scol];
    const unsigned short* gb = &Bt[(size_t)(tn + w * 16 + sr8) * 1024 + scol];

    for (int k0 = 0; k0 < 1024; k0 += 64) {
        __syncthreads();
#pragma unroll
        for (int i = 0; i < 4; i++)
            GLDS16(ga + (size_t)(i * 8) * 1024 + k0, &As[w * 32 + i * 8][0]);
#pragma unroll
        for (int i = 0; i < 2; i++)
            GLDS16(gb + (size_t)(i * 8) * 1024 + k0, &Bs[w * 16 + i * 8][0]);
        __syncthreads();

        short8 af[4][2], bf[2][2];
#pragma unroll
        for (int i = 0; i < 4; i++)
#pragma unroll
            for (int ks = 0; ks < 2; ks++)
                af[i][ks] = *reinterpret_cast<const short8*>(&As[wr * 64 + i * 16 + lo][ks * 32 + hi * 8]);
#pragma unroll
        for (int j = 0; j < 2; j++)
#pragma unroll
            for (int ks = 0; ks < 2; ks++)
                bf[j][ks] = *reinterpret_cast<const short8*>(&Bs[wc * 32 + j * 16 + lo][ks * 32 + hi * 8]);
#pragma unroll
        for (int ks = 0; ks < 2; ks++)
#pragma unroll
            for (int i = 0; i < 4; i++)
#pragma unroll
                for (int j = 0; j < 2; j++)
                    acc[i][j] = __builtin_amdgcn_mfma_f32_16x16x32_bf16(af[i][ks], bf[j][ks], acc[i][j], 0, 0, 0);
    }
#pragma unroll
    for (int i = 0; i < 4; i++)
#pragma unroll
        for (int j = 0; j < 2; j++) {
            const int col = tn + wc * 32 + j * 16 + lo;
            const int row0 = tm + wr * 64 + i * 16 + hi * 4;
#pragma unroll
            for (int r = 0; r < 4; r++)
                Cout[(size_t)(row0 + r) * DD + col] = acc[i][j][r];
        }
}

// ---------------- Flash attention: triple-buffered K/V, counted vmcnt, MFMA row-sum ----------------
// grid (H, 16 pairs, B), 256 threads = 4 waves.
__global__ __launch_bounds__(256)
void attn_kernel(const unsigned short* __restrict__ qkv2,   // [B*T][2048] Q|K bf16
                 const unsigned short* __restrict__ vtg,    // [1024][B*T]  V^T bf16
                 unsigned short* __restrict__ outp) {
    __shared__ unsigned short Ks[3][64][64];
    __shared__ unsigned short Vt[3][64][64];

    const int b = blockIdx.z, h = blockIdx.x, p = blockIdx.y;
    const int qcl = p, qch = 31 - p;
    const int L = p + 1, Hn = 32 - p;                 // Hn >= 17
    const int t = threadIdx.x;
    const int w = t >> 6, l = t & 63, ql = l & 31, hi8 = l >> 5;
    const int pr = w >> 1, rg = w & 1;
    const int q0h = qch * 64 + rg * 32;
    const int q0p = (pr ? qcl : qch) * 64 + rg * 32;
    const unsigned short* base2 = qkv2 + (size_t)b * TT * QKW;

    short8 bq[4];
#pragma unroll
    for (int ks = 0; ks < 4; ks++)
        bq[ks] = *reinterpret_cast<const short8*>(
            &base2[(size_t)(q0p + ql) * QKW + h * 64 + ks * 16 + hi8 * 8]);

    f32x16 o0 = ZERO16, o1 = ZERO16, lD = ZERO16;

    short8 ones1;
#pragma unroll
    for (int j = 0; j < 8; j++) ones1[j] = (short)0x3F80;

    const int krow = l >> 3;
    const int kc8 = (l & 7) ^ krow;
    const unsigned short* gk = &base2[(size_t)(w * 8 + krow) * QKW + DD + h * 64 + kc8 * 8];
    const unsigned short* gv = &vtg[(size_t)(h * 64 + w * 8 + krow) * MM + b * TT + kc8 * 8];

#define STAGE(KVB, BUF) { \
    GLDS16(gk + (size_t)(KVB) * QKW, &Ks[BUF][w * 8][0]); \
    GLDS16(gk + (size_t)((KVB) + 32) * QKW, &Ks[BUF][32 + w * 8][0]); \
    GLDS16(gv + (KVB), &Vt[BUF][w * 8][0]); \
    GLDS16(gv + (size_t)32 * MM + (KVB), &Vt[BUF][32 + w * 8][0]); }

#define WRITE_OUT(Q0) { \
    _Pragma("unroll") \
    for (int r = 0; r < 16; r++) { \
        int src = (r & 3) + 8 * (r >> 2) + 4 * hi8; \
        float inv = fast_rcp(lD[r]); \
        size_t off = (size_t)(b * TT + (Q0) + src) * DD + h * 64 + ql; \
        outp[off] = f2bf(o0[r] * inv); \
        outp[off + 32] = f2bf(o1[r] * inv); \
    } }

    // prologue: two tiles in flight; wait for tile 0 only (counted)
    STAGE(0, 0);
    STAGE(64, 1);
    asm volatile("s_waitcnt vmcnt(4)");
    __builtin_amdgcn_s_barrier();

    const int sw4 = (ql & 7) << 4;
    int cur = 0;
    for (int kvt = 0; kvt < Hn; kvt++) {
        const bool deep = (kvt + 2) < Hn;
        if (deep) { STAGE((kvt + 2) * 64, cur == 0 ? 2 : cur - 1); }

        if (kvt == L && pr == 1) {
            WRITE_OUT(qcl * 64 + rg * 32);
            o0 = ZERO16; o1 = ZERO16; lD = ZERO16;
#pragma unroll
            for (int ks = 0; ks < 4; ks++)
                bq[ks] = *reinterpret_cast<const short8*>(
                    &base2[(size_t)(q0h + ql) * QKW + h * 64 + ks * 16 + hi8 * 8]);
        }

        const char* kbase = (const char*)&Ks[cur][0][0];
        const char* vbase = (const char*)&Vt[cur][0][0];
        const int kvb = kvt * 64;

        if (kvt < L) {
            short8 ak0[4], ak1[4];
#pragma unroll
            for (int ks = 0; ks < 4; ks++) {
                ak0[ks] = *reinterpret_cast<const short8*>(kbase + ql * 128 + (((ks * 2 + hi8) << 4) ^ sw4));
                ak1[ks] = *reinterpret_cast<const short8*>(kbase + (32 + ql) * 128 + (((ks * 2 + hi8) << 4) ^ sw4));
            }
            f32x16 sa0 = ZERO16, sa1 = ZERO16;
#pragma unroll
            for (int ks = 0; ks < 4; ks++) {
                sa0 = __builtin_amdgcn_mfma_f32_32x32x16_bf16(ak0[ks], bq[ks], sa0, 0, 0, 0);
                sa1 = __builtin_amdgcn_mfma_f32_32x32x16_bf16(ak1[ks], bq[ks], sa1, 0, 0, 0);
            }
            if (pr == 1 && kvt == L - 1) {
                const int qg = q0p + ql;
#pragma unroll
                for (int r = 0; r < 16; r++) {
                    int crow = (r & 3) + 8 * (r >> 2) + 4 * hi8;
                    if (kvb + crow > qg) sa0[r] = -1e30f;
                    if (kvb + 32 + crow > qg) sa1[r] = -1e30f;
                }
            }
#pragma unroll
            for (int r = 0; r < 16; r++) sa0[r] = fast_exp2(sa0[r]);
#pragma unroll
            for (int r = 0; r < 16; r++) sa1[r] = fast_exp2(sa1[r]);

            unsigned a01 = cvt_pk_bf16(sa0[0], sa0[1]),  a23 = cvt_pk_bf16(sa0[2], sa0[3]);
            unsigned a45 = cvt_pk_bf16(sa0[4], sa0[5]),  a67 = cvt_pk_bf16(sa0[6], sa0[7]);
            asm("v_permlane32_swap_b32 %0, %1" : "+v"(a01), "+v"(a45));
            asm("v_permlane32_swap_b32 %0, %1" : "+v"(a23), "+v"(a67));
            unsigned b01 = cvt_pk_bf16(sa0[8], sa0[9]),  b23 = cvt_pk_bf16(sa0[10], sa0[11]);
            unsigned b45 = cvt_pk_bf16(sa0[12], sa0[13]), b67 = cvt_pk_bf16(sa0[14], sa0[15]);
            asm("v_permlane32_swap_b32 %0, %1" : "+v"(b01), "+v"(b45));
            asm("v_permlane32_swap_b32 %0, %1" : "+v"(b23), "+v"(b67));
            unsigned c01 = cvt_pk_bf16(sa1[0], sa1[1]),  c23 = cvt_pk_bf16(sa1[2], sa1[3]);
            unsigned c45 = cvt_pk_bf16(sa1[4], sa1[5]),  c67 = cvt_pk_bf16(sa1[6], sa1[7]);
            asm("v_permlane32_swap_b32 %0, %1" : "+v"(c01), "+v"(c45));
            asm("v_permlane32_swap_b32 %0, %1" : "+v"(c23), "+v"(c67));
            unsigned d01 = cvt_pk_bf16(sa1[8], sa1[9]),  d23 = cvt_pk_bf16(sa1[10], sa1[11]);
            unsigned d45 = cvt_pk_bf16(sa1[12], sa1[13]), d67 = cvt_pk_bf16(sa1[14], sa1[15]);
            asm("v_permlane32_swap_b32 %0, %1" : "+v"(d01), "+v"(d45));
            asm("v_permlane32_swap_b32 %0, %1" : "+v"(d23), "+v"(d67));
            union { unsigned u[4]; short8 s; } f0s0, f1s0, f0s1, f1s1;
            f0s0.u[0] = a01; f0s0.u[1] = a23; f0s0.u[2] = a45; f0s0.u[3] = a67;
            f1s0.u[0] = b01; f1s0.u[1] = b23; f1s0.u[2] = b45; f1s0.u[3] = b67;
            f0s1.u[0] = c01; f0s1.u[1] = c23; f0s1.u[2] = c45; f0s1.u[3] = c67;
            f1s1.u[0] = d01; f1s1.u[1] = d23; f1s1.u[2] = d45; f1s1.u[3] = d67;

            lD = __builtin_amdgcn_mfma_f32_32x32x16_bf16(f0s0.s, ones1, lD, 0, 0, 0);
            lD = __builtin_amdgcn_mfma_f32_32x32x16_bf16(f1s0.s, ones1, lD, 0, 0, 0);
            lD = __builtin_amdgcn_mfma_f32_32x32x16_bf16(f0s1.s, ones1, lD, 0, 0, 0);
            lD = __builtin_amdgcn_mfma_f32_32x32x16_bf16(f1s1.s, ones1, lD, 0, 0, 0);

            short8 bv00 = *reinterpret_cast<const short8*>(vbase + ql * 128 + (((0 + hi8) << 4) ^ sw4));
            short8 bv01 = *reinterpret_cast<const short8*>(vbase + ql * 128 + (((2 + hi8) << 4) ^ sw4));
            short8 bv02 = *reinterpret_cast<const short8*>(vbase + ql * 128 + (((4 + hi8) << 4) ^ sw4));
            short8 bv03 = *reinterpret_cast<const short8*>(vbase + ql * 128 + (((6 + hi8) << 4) ^ sw4));
            short8 bv10 = *reinterpret_cast<const short8*>(vbase + (32 + ql) * 128 + (((0 + hi8) << 4) ^ sw4));
            short8 bv11 = *reinterpret_cast<const short8*>(vbase + (32 + ql) * 128 + (((2 + hi8) << 4) ^ sw4));
            short8 bv12 = *reinterpret_cast<const short8*>(vbase + (32 + ql) * 128 + (((4 + hi8) << 4) ^ sw4));
            short8 bv13 = *reinterpret_cast<const short8*>(vbase + (32 + ql) * 128 + (((6 + hi8) << 4) ^ sw4));
            o0 = __builtin_amdgcn_mfma_f32_32x32x16_bf16(f0s0.s, bv00, o0, 0, 0, 0);
            o1 = __builtin_amdgcn_mfma_f32_32x32x16_bf16(f0s0.s, bv10, o1, 0, 0, 0);
            o0 = __builtin_amdgcn_mfma_f32_32x32x16_bf16(f1s0.s, bv01, o0, 0, 0, 0);
            o1 = __builtin_amdgcn_mfma_f32_32x32x16_bf16(f1s0.s, bv11, o1, 0, 0, 0);
            o0 = __builtin_amdgcn_mfma_f32_32x32x16_bf16(f0s1.s, bv02, o0, 0, 0, 0);
            o1 = __builtin_amdgcn_mfma_f32_32x32x16_bf16(f0s1.s, bv12, o1, 0, 0, 0);
            o0 = __builtin_amdgcn_mfma_f32_32x32x16_bf16(f1s1.s, bv03, o0, 0, 0, 0);
            o1 = __builtin_amdgcn_mfma_f32_32x32x16_bf16(f1s1.s, bv13, o1, 0, 0, 0);
        } else {
            const int sub = pr;
            short8 ak[4];
#pragma unroll
            for (int ks = 0; ks < 4; ks++)
                ak[ks] = *reinterpret_cast<const short8*>(
                    kbase + (sub * 32 + ql) * 128 + (((ks * 2 + hi8) << 4) ^ sw4));
            f32x16 sa = ZERO16;
#pragma unroll
            for (int ks = 0; ks < 4; ks++)
                sa = __builtin_amdgcn_mfma_f32_32x32x16_bf16(ak[ks], bq[ks], sa, 0, 0, 0);

            if (kvt == Hn - 1) {
                const int qg = q0h + ql;
#pragma unroll
                for (int r = 0; r < 16; r++) {
                    int crow = (r & 3) + 8 * (r >> 2) + 4 * hi8;
                    if (kvb + sub * 32 + crow > qg) sa[r] = -1e30f;
                }
            }
#pragma unroll
            for (int r = 0; r < 16; r++) sa[r] = fast_exp2(sa[r]);

            unsigned a01 = cvt_pk_bf16(sa[0], sa[1]),  a23 = cvt_pk_bf16(sa[2], sa[3]);
            unsigned a45 = cvt_pk_bf16(sa[4], sa[5]),  a67 = cvt_pk_bf16(sa[6], sa[7]);
            asm("v_permlane32_swap_b32 %0, %1" : "+v"(a01), "+v"(a45));
            asm("v_permlane32_swap_b32 %0, %1" : "+v"(a23), "+v"(a67));
            unsigned b01 = cvt_pk_bf16(sa[8], sa[9]),  b23 = cvt_pk_bf16(sa[10], sa[11]);
            unsigned b45 = cvt_pk_bf16(sa[12], sa[13]), b67 = cvt_pk_bf16(sa[14], sa[15]);
            asm("v_permlane32_swap_b32 %0, %1" : "+v"(b01), "+v"(b45));
            asm("v_permlane32_swap_b32 %0, %1" : "+v"(b23), "+v"(b67));
            union { unsigned u[4]; short8 s; } f0, f1;
            f0.u[0] = a01; f0.u[1] = a23; f0.u[2] = a45; f0.u[3] = a67;
            f1.u[0] = b01; f1.u[1] = b23; f1.u[2] = b45; f1.u[3] = b67;

            lD = __builtin_amdgcn_mfma_f32_32x32x16_bf16(f0.s, ones1, lD, 0, 0, 0);
            lD = __builtin_amdgcn_mfma_f32_32x32x16_bf16(f1.s, ones1, lD, 0, 0, 0);

            short8 bv00 = *reinterpret_cast<const short8*>(vbase + ql * 128 + (((sub * 4 + 0 + hi8) << 4) ^ sw4));
            short8 bv01 = *reinterpret_cast<const short8*>(vbase + ql * 128 + (((sub * 4 + 2 + hi8) << 4) ^ sw4));
            short8 bv10 = *reinterpret_cast<const short8*>(vbase + (32 + ql) * 128 + (((sub * 4 + 0 + hi8) << 4) ^ sw4));
            short8 bv11 = *reinterpret_cast<const short8*>(vbase + (32 + ql) * 128 + (((sub * 4 + 2 + hi8) << 4) ^ sw4));
            o0 = __builtin_amdgcn_mfma_f32_32x32x16_bf16(f0.s, bv00, o0, 0, 0, 0);
            o1 = __builtin_amdgcn_mfma_f32_32x32x16_bf16(f0.s, bv10, o1, 0, 0, 0);
            o0 = __builtin_amdgcn_mfma_f32_32x32x16_bf16(f1.s, bv01, o0, 0, 0, 0);
            o1 = __builtin_amdgcn_mfma_f32_32x32x16_bf16(f1.s, bv11, o1, 0, 0, 0);
        }

        // counted drain: only the NEXT tile's 4 loads must be complete
        if (deep) asm volatile("s_waitcnt vmcnt(4)");
        else if (kvt + 1 < Hn) asm volatile("s_waitcnt vmcnt(0)");
        __builtin_amdgcn_s_barrier();
        cur = (cur == 2) ? 0 : cur + 1;
    }

    float* xf = (float*)&Ks[0][0][0];   // 16 KB scratch (Ks is 24 KB)
    float* xl = (float*)&Vt[0][0][0];
    const int tid128 = (w & 1) * 64 + l;
    if (pr == 1) {
#pragma unroll
        for (int r = 0; r < 16; r++) {
            xf[r * 128 + tid128] = o0[r];
            xf[(16 + r) * 128 + tid128] = o1[r];
            xl[r * 128 + tid128] = lD[r];
        }
    }
    __syncthreads();
    if (pr == 0) {
#pragma unroll
        for (int r = 0; r < 16; r++) {
            o0[r] += xf[r * 128 + tid128];
            o1[r] += xf[(16 + r) * 128 + tid128];
            lD[r] += xl[r * 128 + tid128];
        }
        WRITE_OUT(q0h);
    }
#undef STAGE
#undef WRITE_OUT
}

extern "C" void kernel_launch(void* const* d_in, const int* in_sizes, int n_in,
                              void* d_out, int out_size, void* d_ws, size_t ws_size,
                              hipStream_t stream) {
    const float* x     = (const float*)d_in[0];   // [4096][1024]
    const float* Wqkv  = (const float*)d_in[1];   // [1024][3072]
    const float* Wproj = (const float*)d_in[2];   // [1024][1024]
    float* out = (float*)d_out;                    // [4096][1024] fp32

    unsigned short* xb     = (unsigned short*)d_ws;            // 4096*1024
    unsigned short* wqkvt  = xb + (size_t)MM * DD;             // 3072*1024
    unsigned short* wprojt = wqkvt + (size_t)N3 * DD;          // 1024*1024
    unsigned short* qkv2   = wprojt + (size_t)DD * DD;         // 4096*2048 (Q|K)
    unsigned short* vtg    = qkv2 + (size_t)MM * QKW;          // 1024*4096 (V^T)
    unsigned short* attout = vtg + (size_t)DD * MM;            // 4096*1024
    size_t need = ((size_t)MM * DD + (size_t)N3 * DD + (size_t)DD * DD +
                   (size_t)MM * QKW + (size_t)DD * MM + (size_t)MM * DD) * 2;
    if (ws_size < need) return;

    const float sc = 0.125f * 1.44269504088896f;   // 1/sqrt(64) * log2(e), folded into Q

    prep_kernel<<<5120, dim3(32, 8), 0, stream>>>(x, Wqkv, Wproj, xb, wqkvt, wprojt);

    gemm256_qkv<<<dim3(12, 16), 512, 0, stream>>>(xb, wqkvt, qkv2, vtg, sc);

    attn_kernel<<<dim3(HH, 16, BB), 256, 0, stream>>>(qkv2, vtg, attout);

    gemm_proj<<<dim3(16, 32), 256, 0, stream>>>(attout, wprojt, out);
}

// Round 11
// 109.959 us; speedup vs baseline: 1.7100x; 1.0699x over previous
//
#include <hip/hip_runtime.h>
#include <hip/hip_bf16.h>

// Problem: B=2, T=2048, D=1024, H=16, DH=64
#define BB 2
#define TT 2048
#define DD 1024
#define HH 16
#define MM (BB*TT)        // 4096
#define N3 (3*DD)         // 3072
#define QKW 2048          // qkv2 row width (Q|K only)

typedef __attribute__((ext_vector_type(8))) short short8;
typedef __attribute__((ext_vector_type(4))) float f32x4;
typedef __attribute__((ext_vector_type(16))) float f32x16;

#define ZERO16 (f32x16){0,0,0,0,0,0,0,0,0,0,0,0,0,0,0,0}

#define GLDS16(g, l) __builtin_amdgcn_global_load_lds( \
    (const __attribute__((address_space(1))) void*)(g), \
    (__attribute__((address_space(3))) void*)(l), 16, 0, 0)

__device__ __forceinline__ unsigned short f2bf(float f) {
    union { float f; unsigned u; } v; v.f = f;
    unsigned r = v.u + 0x7FFFu + ((v.u >> 16) & 1u);
    return (unsigned short)(r >> 16);
}

__device__ __forceinline__ unsigned cvt_pk_bf16(float lo, float hi) {
    unsigned r;
    asm("v_cvt_pk_bf16_f32 %0, %1, %2" : "=v"(r) : "v"(lo), "v"(hi));
    return r;
}

__device__ __forceinline__ float fast_exp2(float x) {
    float r;
    asm("v_exp_f32 %0, %1" : "=v"(r) : "v"(x));
    return r;
}
__device__ __forceinline__ float fast_rcp(float x) {
    float r;
    asm("v_rcp_f32 %0, %1" : "=v"(r) : "v"(x));
    return r;
}

// ---------------- merged prep: Wqkv^T + Wproj^T + cast(x), one launch ----------------
__global__ void prep_kernel(const float* __restrict__ x,
                            const float* __restrict__ Wqkv,
                            const float* __restrict__ Wproj,
                            unsigned short* __restrict__ xb,
                            unsigned short* __restrict__ wqkvt,
                            unsigned short* __restrict__ wprojt) {
    __shared__ float tile[32][33];
    const int bid = blockIdx.x;
    const int tx = threadIdx.x, ty = threadIdx.y;
    if (bid < 4096) {
        const float* src;
        unsigned short* dst;
        int rows, cols, c0, r0;
        if (bid < 3072) {
            src = Wqkv; dst = wqkvt; rows = DD; cols = N3;
            c0 = (bid % 96) * 32; r0 = (bid / 96) * 32;
        } else {
            src = Wproj; dst = wprojt; rows = DD; cols = DD;
            int b2 = bid - 3072;
            c0 = (b2 & 31) * 32; r0 = (b2 >> 5) * 32;
        }
#pragma unroll
        for (int i = 0; i < 4; i++) {
            int r = ty + i * 8;
            tile[r][tx] = src[(size_t)(r0 + r) * cols + c0 + tx];
        }
        __syncthreads();
#pragma unroll
        for (int i = 0; i < 4; i++) {
            int r = ty + i * 8;
            dst[(size_t)(c0 + r) * rows + r0 + tx] = f2bf(tile[tx][r]);
        }
    } else {
        const int t = ty * 32 + tx;
        int i = (bid - 4096) * 256 + t;
#pragma unroll
        for (int k = 0; k < 2; k++, i += 262144) {
            const float4* s = reinterpret_cast<const float4*>(x) + (size_t)i * 2;
            float4 a = s[0], b = s[1];
            unsigned short r[8] = {f2bf(a.x), f2bf(a.y), f2bf(a.z), f2bf(a.w),
                                   f2bf(b.x), f2bf(b.y), f2bf(b.z), f2bf(b.w)};
            *reinterpret_cast<uint4*>(xb + (size_t)i * 8) = *reinterpret_cast<uint4*>(r);
        }
    }
}

// ================= 256x256 8-phase GEMM for QKV (M=4096, N=3072, K=1024) =================
__global__ __launch_bounds__(512, 2)
void gemm256_qkv(const unsigned short* __restrict__ A,
                 const unsigned short* __restrict__ Bt,
                 unsigned short* __restrict__ qkv2,
                 unsigned short* __restrict__ Vout,
                 float scale) {
    __shared__ unsigned short Al[2][2][128][64];
    __shared__ unsigned short Bl[2][2][128][64];

    const int id = blockIdx.y * 12 + blockIdx.x;          // nwg = 192, %8 == 0
    const int swzid = (id & 7) * 24 + (id >> 3);
    const int tm = (swzid / 12) * 256, tn = (swzid % 12) * 256;
    const int t = threadIdx.x, w = t >> 6, l = t & 63;
    const int wm = w >> 2, wn = w & 3, bh = wn >> 1;
    const int lo = l & 15, hi = l >> 4;
    const int srow = l >> 3;
    const int sg = (l & 7) ^ srow;

    f32x4 acc[8][4];
#pragma unroll
    for (int i = 0; i < 8; i++)
#pragma unroll
        for (int j = 0; j < 4; j++) acc[i][j] = (f32x4){0.f, 0.f, 0.f, 0.f};

    const unsigned short* Abase = A + (size_t)(tm + w * 16 + srow) * 1024 + sg * 8;
    const unsigned short* Bbase = Bt + (size_t)(tn + w * 16 + srow) * 1024 + sg * 8;

#define STG_A(KT, H) { \
    GLDS16(Abase + (size_t)(H) * 128 * 1024 + ((KT) & 15) * 64, &Al[(KT) & 1][H][w * 16][0]); \
    GLDS16(Abase + (size_t)(H) * 128 * 1024 + 8 * 1024 + ((KT) & 15) * 64, &Al[(KT) & 1][H][w * 16 + 8][0]); }
#define STG_B(KT, H) { \
    GLDS16(Bbase + (size_t)(H) * 128 * 1024 + ((KT) & 15) * 64, &Bl[(KT) & 1][H][w * 16][0]); \
    GLDS16(Bbase + (size_t)(H) * 128 * 1024 + 8 * 1024 + ((KT) & 15) * 64, &Bl[(KT) & 1][H][w * 16 + 8][0]); }

#define LOAD_A(AFR, KP, MH) { \
    const char* ab = (const char*)&Al[KP][wm][0][0]; \
    _Pragma("unroll") \
    for (int fi = 0; fi < 4; fi++) \
    _Pragma("unroll") \
    for (int ks = 0; ks < 2; ks++) \
        AFR[fi][ks] = *reinterpret_cast<const short8*>( \
            ab + ((MH) * 64 + fi * 16 + lo) * 128 + (((ks * 4 + hi) ^ (lo & 7)) << 4)); }
#define LOAD_B(BFR, KP, NH) { \
    const char* bb = (const char*)&Bl[KP][bh][0][0]; \
    _Pragma("unroll") \
    for (int fj = 0; fj < 2; fj++) \
    _Pragma("unroll") \
    for (int ks = 0; ks < 2; ks++) \
        BFR[fj][ks] = *reinterpret_cast<const short8*>( \
            bb + ((wn & 1) * 64 + (NH) * 32 + fj * 16 + lo) * 128 + (((ks * 4 + hi) ^ (lo & 7)) << 4)); }

#define MFMA16(MH, NH, AFR, BFR) { \
    _Pragma("unroll") \
    for (int ks = 0; ks < 2; ks++) \
    _Pragma("unroll") \
    for (int fi = 0; fi < 4; fi++) \
    _Pragma("unroll") \
    for (int fj = 0; fj < 2; fj++) \
        acc[(MH) * 4 + fi][(NH) * 2 + fj] = __builtin_amdgcn_mfma_f32_16x16x32_bf16( \
            AFR[fi][ks], BFR[fj][ks], acc[(MH) * 4 + fi][(NH) * 2 + fj], 0, 0, 0); }

#define BAR __builtin_amdgcn_s_barrier()
#define LGKM0 asm volatile("s_waitcnt lgkmcnt(0)")
#define P1 __builtin_amdgcn_s_setprio(1)
#define P0 __builtin_amdgcn_s_setprio(0)

    STG_A(0, 0); STG_A(0, 1); STG_B(0, 0); STG_B(0, 1);
    STG_B(1, 0); STG_B(1, 1);
    asm volatile("s_waitcnt vmcnt(4)");
    BAR;

    for (int i = 0; i < 8; i++) {
        const int kt = 2 * i;
        short8 AF[4][2], BA[2][2], BBf[2][2];
        LOAD_A(AF, 0, 0); LOAD_B(BA, 0, 0);
        STG_A(kt + 1, 0); STG_A(kt + 1, 1);
        BAR; LGKM0; P1; MFMA16(0, 0, AF, BA); P0; BAR;
        LOAD_B(BBf, 0, 1);
        BAR; LGKM0; P1; MFMA16(0, 1, AF, BBf); P0; BAR;
        LOAD_A(AF, 0, 1);
        STG_B(kt + 2, 0); STG_B(kt + 2, 1);
        BAR; LGKM0; P1; MFMA16(1, 1, AF, BBf); P0; BAR;
        STG_A(kt + 2, 0);
        BAR; LGKM0; P1; MFMA16(1, 0, AF, BA); P0;
        asm volatile("s_waitcnt vmcnt(6)");
        BAR;
        LOAD_A(AF, 1, 0); LOAD_B(BA, 1, 0);
        STG_A(kt + 2, 1);
        BAR; LGKM0; P1; MFMA16(0, 0, AF, BA); P0; BAR;
        LOAD_B(BBf, 1, 1);
        BAR; LGKM0; P1; MFMA16(0, 1, AF, BBf); P0; BAR;
        LOAD_A(AF, 1, 1);
        STG_B(kt + 3, 0); STG_B(kt + 3, 1);
        BAR; LGKM0; P1; MFMA16(1, 1, AF, BBf); P0; BAR;
        BAR; LGKM0; P1; MFMA16(1, 0, AF, BA); P0;
        asm volatile("s_waitcnt vmcnt(4)");
        BAR;
    }

#pragma unroll
    for (int i = 0; i < 8; i++)
#pragma unroll
        for (int j = 0; j < 4; j++) {
            const int col = tn + wn * 64 + j * 16 + lo;
            const int row0 = tm + wm * 128 + i * 16 + hi * 4;
            if (col < 2 * DD) {
                float s = (col < DD) ? scale : 1.0f;
#pragma unroll
                for (int r = 0; r < 4; r++)
                    qkv2[(size_t)(row0 + r) * QKW + col] = f2bf(acc[i][j][r] * s);
            } else {
                unsigned short pk[4];
#pragma unroll
                for (int r = 0; r < 4; r++) pk[r] = f2bf(acc[i][j][r]);
                *reinterpret_cast<uint2*>(&Vout[(size_t)(col - 2 * DD) * MM + row0]) =
                    *reinterpret_cast<uint2*>(pk);
            }
        }
#undef STG_A
#undef STG_B
#undef LOAD_A
#undef LOAD_B
#undef MFMA16
#undef BAR
#undef LGKM0
#undef P1
#undef P0
}

// ---------------- output projection GEMM: 128x64 tiles -> 512 blocks ----------------
__global__ __launch_bounds__(256)
void gemm_proj(const unsigned short* __restrict__ A,
               const unsigned short* __restrict__ Bt,
               float* __restrict__ Cout) {
    __shared__ unsigned short As[128][64];
    __shared__ unsigned short Bs[64][64];
    const int nbx = 16;
    const int id = blockIdx.y * nbx + blockIdx.x;
    const int cpx = 512 >> 3;
    const int swz = (id & 7) * cpx + (id >> 3);
    const int tm = (swz / nbx) * 128, tn = (swz % nbx) * 64;
    const int t = threadIdx.x;
    const int w = t >> 6, lane = t & 63, lo = lane & 15, hi = lane >> 4;
    const int wr = w >> 1, wc = w & 1;

    f32x4 acc[4][2];
#pragma unroll
    for (int i = 0; i < 4; i++)
#pragma unroll
        for (int j = 0; j < 2; j++) acc[i][j] = (f32x4){0.f, 0.f, 0.f, 0.f};

    const int sr8 = lane >> 3;
    const int scol = (lane & 7) * 8;
    const unsigned short* ga = &A[(size_t)(tm + w * 32 + sr8) * 1024 + scol];
    const unsigned short* gb = &Bt[(size_t)(tn + w * 16 + sr8) * 1024 + scol];

    for (int k0 = 0; k0 < 1024; k0 += 64) {
        __syncthreads();
#pragma unroll
        for (int i = 0; i < 4; i++)
            GLDS16(ga + (size_t)(i * 8) * 1024 + k0, &As[w * 32 + i * 8][0]);
#pragma unroll
        for (int i = 0; i < 2; i++)
            GLDS16(gb + (size_t)(i * 8) * 1024 + k0, &Bs[w * 16 + i * 8][0]);
        __syncthreads();

        short8 af[4][2], bf[2][2];
#pragma unroll
        for (int i = 0; i < 4; i++)
#pragma unroll
            for (int ks = 0; ks < 2; ks++)
                af[i][ks] = *reinterpret_cast<const short8*>(&As[wr * 64 + i * 16 + lo][ks * 32 + hi * 8]);
#pragma unroll
        for (int j = 0; j < 2; j++)
#pragma unroll
            for (int ks = 0; ks < 2; ks++)
                bf[j][ks] = *reinterpret_cast<const short8*>(&Bs[wc * 32 + j * 16 + lo][ks * 32 + hi * 8]);
#pragma unroll
        for (int ks = 0; ks < 2; ks++)
#pragma unroll
            for (int i = 0; i < 4; i++)
#pragma unroll
                for (int j = 0; j < 2; j++)
                    acc[i][j] = __builtin_amdgcn_mfma_f32_16x16x32_bf16(af[i][ks], bf[j][ks], acc[i][j], 0, 0, 0);
    }
#pragma unroll
    for (int i = 0; i < 4; i++)
#pragma unroll
        for (int j = 0; j < 2; j++) {
            const int col = tn + wc * 32 + j * 16 + lo;
            const int row0 = tm + wr * 64 + i * 16 + hi * 4;
#pragma unroll
            for (int r = 0; r < 4; r++)
                Cout[(size_t)(row0 + r) * DD + col] = acc[i][j][r];
        }
}

// ================ Flash attention: balanced 17-step schedule, 4-slot LDS ring ================
// grid (H, 16 pairs, B), 256 threads = 4 waves (2 wave-pairs).
// Pair p: light q-tile qcl=p (L=p+1 kv tiles), heavy q-tile qch=31-p (Hn=32-p kv tiles).
// Steps (17 for ALL p):
//   s < L            : both pairs compute FULL tile s (pair0: heavy Q, pair1: light Q; light mask @ s==L-1)
//   L <= s < 16      : pair pr computes FULL tile L+2(s-L)+pr (no mask; count 30-2p is even)
//   s == 16          : tile Hn-1, kv-half split (sub=pr), heavy mask
// Fixed-shift softmax makes all sums order-free -> merge at end.
struct AttnState {
    f32x16 o0, o1, lD;
};

__device__ __forceinline__ void attn_full_tile(
        const char* kbase, const char* vbase, const short8* bq, short8 ones1,
        AttnState& st, int sw4, int ql, int hi8, bool domask, int kvb, int qg) {
    short8 ak0[4], ak1[4];
#pragma unroll
    for (int ks = 0; ks < 4; ks++) {
        ak0[ks] = *reinterpret_cast<const short8*>(kbase + ql * 128 + (((ks * 2 + hi8) << 4) ^ sw4));
        ak1[ks] = *reinterpret_cast<const short8*>(kbase + (32 + ql) * 128 + (((ks * 2 + hi8) << 4) ^ sw4));
    }
    f32x16 sa0 = ZERO16, sa1 = ZERO16;
#pragma unroll
    for (int ks = 0; ks < 4; ks++) {
        sa0 = __builtin_amdgcn_mfma_f32_32x32x16_bf16(ak0[ks], bq[ks], sa0, 0, 0, 0);
        sa1 = __builtin_amdgcn_mfma_f32_32x32x16_bf16(ak1[ks], bq[ks], sa1, 0, 0, 0);
    }
    if (domask) {
#pragma unroll
        for (int r = 0; r < 16; r++) {
            int crow = (r & 3) + 8 * (r >> 2) + 4 * hi8;
            if (kvb + crow > qg) sa0[r] = -1e30f;
            if (kvb + 32 + crow > qg) sa1[r] = -1e30f;
        }
    }
#pragma unroll
    for (int r = 0; r < 16; r++) sa0[r] = fast_exp2(sa0[r]);
#pragma unroll
    for (int r = 0; r < 16; r++) sa1[r] = fast_exp2(sa1[r]);

    unsigned a01 = cvt_pk_bf16(sa0[0], sa0[1]),  a23 = cvt_pk_bf16(sa0[2], sa0[3]);
    unsigned a45 = cvt_pk_bf16(sa0[4], sa0[5]),  a67 = cvt_pk_bf16(sa0[6], sa0[7]);
    asm("v_permlane32_swap_b32 %0, %1" : "+v"(a01), "+v"(a45));
    asm("v_permlane32_swap_b32 %0, %1" : "+v"(a23), "+v"(a67));
    unsigned b01 = cvt_pk_bf16(sa0[8], sa0[9]),  b23 = cvt_pk_bf16(sa0[10], sa0[11]);
    unsigned b45 = cvt_pk_bf16(sa0[12], sa0[13]), b67 = cvt_pk_bf16(sa0[14], sa0[15]);
    asm("v_permlane32_swap_b32 %0, %1" : "+v"(b01), "+v"(b45));
    asm("v_permlane32_swap_b32 %0, %1" : "+v"(b23), "+v"(b67));
    unsigned c01 = cvt_pk_bf16(sa1[0], sa1[1]),  c23 = cvt_pk_bf16(sa1[2], sa1[3]);
    unsigned c45 = cvt_pk_bf16(sa1[4], sa1[5]),  c67 = cvt_pk_bf16(sa1[6], sa1[7]);
    asm("v_permlane32_swap_b32 %0, %1" : "+v"(c01), "+v"(c45));
    asm("v_permlane32_swap_b32 %0, %1" : "+v"(c23), "+v"(c67));
    unsigned d01 = cvt_pk_bf16(sa1[8], sa1[9]),  d23 = cvt_pk_bf16(sa1[10], sa1[11]);
    unsigned d45 = cvt_pk_bf16(sa1[12], sa1[13]), d67 = cvt_pk_bf16(sa1[14], sa1[15]);
    asm("v_permlane32_swap_b32 %0, %1" : "+v"(d01), "+v"(d45));
    asm("v_permlane32_swap_b32 %0, %1" : "+v"(d23), "+v"(d67));
    union { unsigned u[4]; short8 s; } f0s0, f1s0, f0s1, f1s1;
    f0s0.u[0] = a01; f0s0.u[1] = a23; f0s0.u[2] = a45; f0s0.u[3] = a67;
    f1s0.u[0] = b01; f1s0.u[1] = b23; f1s0.u[2] = b45; f1s0.u[3] = b67;
    f0s1.u[0] = c01; f0s1.u[1] = c23; f0s1.u[2] = c45; f0s1.u[3] = c67;
    f1s1.u[0] = d01; f1s1.u[1] = d23; f1s1.u[2] = d45; f1s1.u[3] = d67;

    st.lD = __builtin_amdgcn_mfma_f32_32x32x16_bf16(f0s0.s, ones1, st.lD, 0, 0, 0);
    st.lD = __builtin_amdgcn_mfma_f32_32x32x16_bf16(f1s0.s, ones1, st.lD, 0, 0, 0);
    st.lD = __builtin_amdgcn_mfma_f32_32x32x16_bf16(f0s1.s, ones1, st.lD, 0, 0, 0);
    st.lD = __builtin_amdgcn_mfma_f32_32x32x16_bf16(f1s1.s, ones1, st.lD, 0, 0, 0);

    short8 bv00 = *reinterpret_cast<const short8*>(vbase + ql * 128 + (((0 + hi8) << 4) ^ sw4));
    short8 bv01 = *reinterpret_cast<const short8*>(vbase + ql * 128 + (((2 + hi8) << 4) ^ sw4));
    short8 bv02 = *reinterpret_cast<const short8*>(vbase + ql * 128 + (((4 + hi8) << 4) ^ sw4));
    short8 bv03 = *reinterpret_cast<const short8*>(vbase + ql * 128 + (((6 + hi8) << 4) ^ sw4));
    short8 bv10 = *reinterpret_cast<const short8*>(vbase + (32 + ql) * 128 + (((0 + hi8) << 4) ^ sw4));
    short8 bv11 = *reinterpret_cast<const short8*>(vbase + (32 + ql) * 128 + (((2 + hi8) << 4) ^ sw4));
    short8 bv12 = *reinterpret_cast<const short8*>(vbase + (32 + ql) * 128 + (((4 + hi8) << 4) ^ sw4));
    short8 bv13 = *reinterpret_cast<const short8*>(vbase + (32 + ql) * 128 + (((6 + hi8) << 4) ^ sw4));
    st.o0 = __builtin_amdgcn_mfma_f32_32x32x16_bf16(f0s0.s, bv00, st.o0, 0, 0, 0);
    st.o1 = __builtin_amdgcn_mfma_f32_32x32x16_bf16(f0s0.s, bv10, st.o1, 0, 0, 0);
    st.o0 = __builtin_amdgcn_mfma_f32_32x32x16_bf16(f1s0.s, bv01, st.o0, 0, 0, 0);
    st.o1 = __builtin_amdgcn_mfma_f32_32x32x16_bf16(f1s0.s, bv11, st.o1, 0, 0, 0);
    st.o0 = __builtin_amdgcn_mfma_f32_32x32x16_bf16(f0s1.s, bv02, st.o0, 0, 0, 0);
    st.o1 = __builtin_amdgcn_mfma_f32_32x32x16_bf16(f0s1.s, bv12, st.o1, 0, 0, 0);
    st.o0 = __builtin_amdgcn_mfma_f32_32x32x16_bf16(f1s1.s, bv03, st.o0, 0, 0, 0);
    st.o1 = __builtin_amdgcn_mfma_f32_32x32x16_bf16(f1s1.s, bv13, st.o1, 0, 0, 0);
}

__device__ __forceinline__ void attn_half_tile(
        const char* kbase, const char* vbase, const short8* bq, short8 ones1,
        AttnState& st, int sw4, int ql, int hi8, int sub, int kvb, int qg) {
    short8 ak[4];
#pragma unroll
    for (int ks = 0; ks < 4; ks++)
        ak[ks] = *reinterpret_cast<const short8*>(
            kbase + (sub * 32 + ql) * 128 + (((ks * 2 + hi8) << 4) ^ sw4));
    f32x16 sa = ZERO16;
#pragma unroll
    for (int ks = 0; ks < 4; ks++)
        sa = __builtin_amdgcn_mfma_f32_32x32x16_bf16(ak[ks], bq[ks], sa, 0, 0, 0);

#pragma unroll
    for (int r = 0; r < 16; r++) {
        int crow = (r & 3) + 8 * (r >> 2) + 4 * hi8;
        if (kvb + sub * 32 + crow > qg) sa[r] = -1e30f;
    }
#pragma unroll
    for (int r = 0; r < 16; r++) sa[r] = fast_exp2(sa[r]);

    unsigned a01 = cvt_pk_bf16(sa[0], sa[1]),  a23 = cvt_pk_bf16(sa[2], sa[3]);
    unsigned a45 = cvt_pk_bf16(sa[4], sa[5]),  a67 = cvt_pk_bf16(sa[6], sa[7]);
    asm("v_permlane32_swap_b32 %0, %1" : "+v"(a01), "+v"(a45));
    asm("v_permlane32_swap_b32 %0, %1" : "+v"(a23), "+v"(a67));
    unsigned b01 = cvt_pk_bf16(sa[8], sa[9]),  b23 = cvt_pk_bf16(sa[10], sa[11]);
    unsigned b45 = cvt_pk_bf16(sa[12], sa[13]), b67 = cvt_pk_bf16(sa[14], sa[15]);
    asm("v_permlane32_swap_b32 %0, %1" : "+v"(b01), "+v"(b45));
    asm("v_permlane32_swap_b32 %0, %1" : "+v"(b23), "+v"(b67));
    union { unsigned u[4]; short8 s; } f0, f1;
    f0.u[0] = a01; f0.u[1] = a23; f0.u[2] = a45; f0.u[3] = a67;
    f1.u[0] = b01; f1.u[1] = b23; f1.u[2] = b45; f1.u[3] = b67;

    st.lD = __builtin_amdgcn_mfma_f32_32x32x16_bf16(f0.s, ones1, st.lD, 0, 0, 0);
    st.lD = __builtin_amdgcn_mfma_f32_32x32x16_bf16(f1.s, ones1, st.lD, 0, 0, 0);

    short8 bv00 = *reinterpret_cast<const short8*>(vbase + ql * 128 + (((sub * 4 + 0 + hi8) << 4) ^ sw4));
    short8 bv01 = *reinterpret_cast<const short8*>(vbase + ql * 128 + (((sub * 4 + 2 + hi8) << 4) ^ sw4));
    short8 bv10 = *reinterpret_cast<const short8*>(vbase + (32 + ql) * 128 + (((sub * 4 + 0 + hi8) << 4) ^ sw4));
    short8 bv11 = *reinterpret_cast<const short8*>(vbase + (32 + ql) * 128 + (((sub * 4 + 2 + hi8) << 4) ^ sw4));
    st.o0 = __builtin_amdgcn_mfma_f32_32x32x16_bf16(f0.s, bv00, st.o0, 0, 0, 0);
    st.o1 = __builtin_amdgcn_mfma_f32_32x32x16_bf16(f0.s, bv10, st.o1, 0, 0, 0);
    st.o0 = __builtin_amdgcn_mfma_f32_32x32x16_bf16(f1.s, bv01, st.o0, 0, 0, 0);
    st.o1 = __builtin_amdgcn_mfma_f32_32x32x16_bf16(f1.s, bv11, st.o1, 0, 0, 0);
}

__global__ __launch_bounds__(256)
void attn_kernel(const unsigned short* __restrict__ qkv2,   // [B*T][2048] Q|K bf16
                 const unsigned short* __restrict__ vtg,    // [1024][B*T]  V^T bf16
                 unsigned short* __restrict__ outp) {
    __shared__ unsigned short Ks[4][64][64];   // 4-slot ring, XOR-swizzled rows
    __shared__ unsigned short Vt[4][64][64];

    const int b = blockIdx.z, h = blockIdx.x, p = blockIdx.y;
    const int qcl = p, qch = 31 - p;
    const int L = p + 1, Hn = 32 - p;
    const int NSTEP = 17;                      // L + (15 - p) + 1, constant
    const int t = threadIdx.x;
    const int w = t >> 6, l = t & 63, ql = l & 31, hi8 = l >> 5;
    const int pr = w >> 1, rg = w & 1;
    const int q0h = qch * 64 + rg * 32;
    const int q0l = qcl * 64 + rg * 32;
    const int q0p = pr ? q0l : q0h;
    const unsigned short* base2 = qkv2 + (size_t)b * TT * QKW;

    short8 bq[4];
#pragma unroll
    for (int ks = 0; ks < 4; ks++)
        bq[ks] = *reinterpret_cast<const short8*>(
            &base2[(size_t)(q0p + ql) * QKW + h * 64 + ks * 16 + hi8 * 8]);

    AttnState st;
    st.o0 = ZERO16; st.o1 = ZERO16; st.lD = ZERO16;

    short8 ones1;
#pragma unroll
    for (int j = 0; j < 8; j++) ones1[j] = (short)0x3F80;

    const int krow = l >> 3;
    const int kc8 = (l & 7) ^ krow;
    const unsigned short* gk = &base2[(size_t)(w * 8 + krow) * QKW + DD + h * 64 + kc8 * 8];
    const unsigned short* gv = &vtg[(size_t)(h * 64 + w * 8 + krow) * MM + b * TT + kc8 * 8];

#define STAGE(TI) { \
    const int _s = (TI) & 3; \
    const size_t _kb = (size_t)(TI) * 64; \
    GLDS16(gk + _kb * QKW, &Ks[_s][w * 8][0]); \
    GLDS16(gk + (_kb + 32) * QKW, &Ks[_s][32 + w * 8][0]); \
    GLDS16(gv + _kb, &Vt[_s][w * 8][0]); \
    GLDS16(gv + (size_t)32 * MM + _kb, &Vt[_s][32 + w * 8][0]); }

#define WRITE_OUT(Q0) { \
    _Pragma("unroll") \
    for (int r = 0; r < 16; r++) { \
        int src = (r & 3) + 8 * (r >> 2) + 4 * hi8; \
        float inv = fast_rcp(st.lD[r]); \
        size_t off = (size_t)(b * TT + (Q0) + src) * DD + h * 64 + ql; \
        outp[off] = f2bf(st.o0[r] * inv); \
        outp[off + 32] = f2bf(st.o1[r] * inv); \
    } }

    STAGE(0);
    int nIss = 1;
    __syncthreads();

    const int sw4 = (ql & 7) << 4;
    for (int s = 0; s < NSTEP; s++) {
        // issue stages needed by step s+1
        {
            const int sn = s + 1;
            int lastN;
            if (sn < L) lastN = sn;
            else if (sn < NSTEP - 1) lastN = L + 2 * (sn - L) + 1;
            else if (sn == NSTEP - 1) lastN = Hn - 1;
            else lastN = -1;
            while (nIss <= lastN) { STAGE(nIss); nIss++; }
        }

        if (s == L && pr == 1) {
            // light tile done: emit, reset, switch to heavy Q
            WRITE_OUT(q0l);
            st.o0 = ZERO16; st.o1 = ZERO16; st.lD = ZERO16;
#pragma unroll
            for (int ks = 0; ks < 4; ks++)
                bq[ks] = *reinterpret_cast<const short8*>(
                    &base2[(size_t)(q0h + ql) * QKW + h * 64 + ks * 16 + hi8 * 8]);
        }

        if (s < L) {
            const int tile = s;
            const char* kbase = (const char*)&Ks[tile & 3][0][0];
            const char* vbase = (const char*)&Vt[tile & 3][0][0];
            const bool domask = (pr == 1) && (s == L - 1);
            attn_full_tile(kbase, vbase, bq, ones1, st, sw4, ql, hi8,
                           domask, tile * 64, q0p + ql);
        } else if (s < NSTEP - 1) {
            const int tile = L + 2 * (s - L) + pr;
            const char* kbase = (const char*)&Ks[tile & 3][0][0];
            const char* vbase = (const char*)&Vt[tile & 3][0][0];
            attn_full_tile(kbase, vbase, bq, ones1, st, sw4, ql, hi8,
                           false, 0, 0);
        } else {
            const int tile = Hn - 1;
            const char* kbase = (const char*)&Ks[tile & 3][0][0];
            const char* vbase = (const char*)&Vt[tile & 3][0][0];
            attn_half_tile(kbase, vbase, bq, ones1, st, sw4, ql, hi8,
                           pr, tile * 64, q0h + ql);
        }
        __syncthreads();
    }

    // merge pair-1 heavy partials into pair 0
    float* xf = (float*)&Ks[0][0][0];   // 16 KB scratch
    float* xl = (float*)&Vt[0][0][0];
    const int tid128 = (w & 1) * 64 + l;
    if (pr == 1) {
#pragma unroll
        for (int r = 0; r < 16; r++) {
            xf[r * 128 + tid128] = st.o0[r];
            xf[(16 + r) * 128 + tid128] = st.o1[r];
            xl[r * 128 + tid128] = st.lD[r];
        }
    }
    __syncthreads();
    if (pr == 0) {
#pragma unroll
        for (int r = 0; r < 16; r++) {
            st.o0[r] += xf[r * 128 + tid128];
            st.o1[r] += xf[(16 + r) * 128 + tid128];
            st.lD[r] += xl[r * 128 + tid128];
        }
        WRITE_OUT(q0h);
    }
#undef STAGE
#undef WRITE_OUT
}

extern "C" void kernel_launch(void* const* d_in, const int* in_sizes, int n_in,
                              void* d_out, int out_size, void* d_ws, size_t ws_size,
                              hipStream_t stream) {
    const float* x     = (const float*)d_in[0];   // [4096][1024]
    const float* Wqkv  = (const float*)d_in[1];   // [1024][3072]
    const float* Wproj = (const float*)d_in[2];   // [1024][1024]
    float* out = (float*)d_out;                    // [4096][1024] fp32

    unsigned short* xb     = (unsigned short*)d_ws;            // 4096*1024
    unsigned short* wqkvt  = xb + (size_t)MM * DD;             // 3072*1024
    unsigned short* wprojt = wqkvt + (size_t)N3 * DD;          // 1024*1024
    unsigned short* qkv2   = wprojt + (size_t)DD * DD;         // 4096*2048 (Q|K)
    unsigned short* vtg    = qkv2 + (size_t)MM * QKW;          // 1024*4096 (V^T)
    unsigned short* attout = vtg + (size_t)DD * MM;            // 4096*1024
    size_t need = ((size_t)MM * DD + (size_t)N3 * DD + (size_t)DD * DD +
                   (size_t)MM * QKW + (size_t)DD * MM + (size_t)MM * DD) * 2;
    if (ws_size < need) return;

    const float sc = 0.125f * 1.44269504088896f;   // 1/sqrt(64) * log2(e), folded into Q

    prep_kernel<<<5120, dim3(32, 8), 0, stream>>>(x, Wqkv, Wproj, xb, wqkvt, wprojt);

    gemm256_qkv<<<dim3(12, 16), 512, 0, stream>>>(xb, wqkvt, qkv2, vtg, sc);

    attn_kernel<<<dim3(HH, 16, BB), 256, 0, stream>>>(qkv2, vtg, attout);

    gemm_proj<<<dim3(16, 32), 256, 0, stream>>>(attout, wprojt, out);
}